// Round 1
// baseline (7135.033 us; speedup 1.0000x reference)
//
#include <hip/hip_runtime.h>

#define N_ENTS 50000
#define R2 500
#define H 256
#define TSTEPS 4
#define NE 200000
#define NM 200000
#define NL 2
#define SLOPE 0.22916666666666666f

typedef __attribute__((ext_vector_type(8))) short short8;
typedef __attribute__((ext_vector_type(4))) short short4v;
typedef __attribute__((ext_vector_type(4))) float f32x4;

static __device__ __forceinline__ float b2f(short s) {
  unsigned u = ((unsigned)(unsigned short)s) << 16;
  return __builtin_bit_cast(float, u);
}
static __device__ __forceinline__ short f2b(float f) {
  unsigned u = __builtin_bit_cast(unsigned, f);
  u = (u + 0x7FFFu + ((u >> 16) & 1u)) >> 16;
  return (short)(unsigned short)u;
}

// ---------------- GEMM: C[M x Ncols] = A[M x K](bf16) * Bt[Ncols x K](bf16)^T ----
// EPI 0: Cf = acc (+Cadd)(+bias)            (f32 out, ldc)
// EPI 1: Obf = bf16(rrelu(acc))             (ldo)
// EPI 2: l2norm(rrelu(acc)) -> Cf (f32) and Obf (bf16)
template<int EPI>
__global__ __launch_bounds__(256)
void gemm_k(const short* __restrict__ A, int lda,
            const short* __restrict__ Bt, int ldb,
            int M, int K,
            float* __restrict__ Cf, int ldc,
            const float* __restrict__ Cadd,
            const float* __restrict__ bias,
            short* __restrict__ Obf, int ldo)
{
  __shared__ short bt[256 * 72];
  const int tid = threadIdx.x;
  const int w = tid >> 6;
  const int lane = tid & 63;
  const int fr = lane & 15;
  const int fq = lane >> 4;
  const int col0 = blockIdx.y << 8;
  const int rowbase = blockIdx.x * 64 + w * 16;
  const int arow = min(rowbase + fr, M - 1);
  const long abase = (long)arow * lda + fq * 8;

  f32x4 acc[16];
#pragma unroll
  for (int i = 0; i < 16; ++i) { acc[i][0] = 0.f; acc[i][1] = 0.f; acc[i][2] = 0.f; acc[i][3] = 0.f; }

  for (int kc = 0; kc < K; kc += 64) {
    __syncthreads();
    {
      const short* g = Bt + (long)(col0 + tid) * ldb + kc;
      short* l = &bt[tid * 72];
#pragma unroll
      for (int i = 0; i < 8; ++i)
        *(short8*)(l + i * 8) = *(const short8*)(g + i * 8);
    }
    __syncthreads();
#pragma unroll
    for (int ks = 0; ks < 2; ++ks) {
      short8 a = *(const short8*)(A + abase + kc + ks * 32);
#pragma unroll
      for (int ct = 0; ct < 16; ++ct) {
        short8 b = *(const short8*)&bt[(ct * 16 + fr) * 72 + ks * 32 + fq * 8];
        acc[ct] = __builtin_amdgcn_mfma_f32_16x16x32_bf16(a, b, acc[ct], 0, 0, 0);
      }
    }
  }

  const int crow = rowbase + fq * 4;
  if (EPI == 0) {
#pragma unroll
    for (int ct = 0; ct < 16; ++ct) {
      const int gcol = col0 + ct * 16 + fr;
#pragma unroll
      for (int j = 0; j < 4; ++j) {
        const int r = crow + j;
        if (r < M) {
          float v = acc[ct][j];
          if (Cadd) v += Cadd[(long)r * ldc + gcol];
          if (bias) v += bias[gcol];
          Cf[(long)r * ldc + gcol] = v;
        }
      }
    }
  } else {
    float ss[4];
#pragma unroll
    for (int j = 0; j < 4; ++j) ss[j] = 0.f;
#pragma unroll
    for (int ct = 0; ct < 16; ++ct) {
#pragma unroll
      for (int j = 0; j < 4; ++j) {
        float v = acc[ct][j];
        v = v >= 0.f ? v : v * SLOPE;
        acc[ct][j] = v;
        ss[j] += v * v;
      }
    }
    if (EPI == 2) {
#pragma unroll
      for (int j = 0; j < 4; ++j) {
        float s = ss[j];
        s += __shfl_xor(s, 1, 64);
        s += __shfl_xor(s, 2, 64);
        s += __shfl_xor(s, 4, 64);
        s += __shfl_xor(s, 8, 64);
        ss[j] = 1.f / fmaxf(sqrtf(s), 1e-12f);
      }
    }
#pragma unroll
    for (int ct = 0; ct < 16; ++ct) {
      const int gcol = ct * 16 + fr;   // EPI 1/2 used only with gridDim.y == 1
#pragma unroll
      for (int j = 0; j < 4; ++j) {
        const int r = crow + j;
        if (r < M) {
          float v = acc[ct][j];
          if (EPI == 2) {
            v *= ss[j];
            Cf[(long)r * ldc + gcol] = v;
          }
          Obf[(long)r * ldo + gcol] = f2b(v);
        }
      }
    }
  }
}

// ---------------- init: h = l2norm(dynamic_emb) -> bf16 into Acat halfB ----------
__global__ __launch_bounds__(256)
void l2init_k(const float* __restrict__ de, short* __restrict__ hb)
{
  const int w = threadIdx.x >> 6, lane = threadIdx.x & 63;
  const int row = blockIdx.x * 4 + w;
  f32x4 v = *(const f32x4*)&de[(long)row * H + lane * 4];
  float s = v[0]*v[0] + v[1]*v[1] + v[2]*v[2] + v[3]*v[3];
  s += __shfl_xor(s, 1, 64);  s += __shfl_xor(s, 2, 64);
  s += __shfl_xor(s, 4, 64);  s += __shfl_xor(s, 8, 64);
  s += __shfl_xor(s, 16, 64); s += __shfl_xor(s, 32, 64);
  float sc = 1.f / fmaxf(sqrtf(s), 1e-12f);
  short4v o;
  o[0] = f2b(v[0]*sc); o[1] = f2b(v[1]*sc); o[2] = f2b(v[2]*sc); o[3] = f2b(v[3]*sc);
  *(short4v*)&hb[(long)row * 512 + lane * 4] = o;
}

// ---------------- weight prep ----------------------------------------------------
__global__ void castcopy_k(const float* __restrict__ in, short* __restrict__ out, long n)
{
  long i = (long)blockIdx.x * 256 + threadIdx.x;
  if (i < n) out[i] = f2b(in[i]);
}

__global__ void wcat_k(const float* __restrict__ wn, const float* __restrict__ lw,
                       short* __restrict__ wc)
{
  long i = (long)blockIdx.x * 256 + threadIdx.x;  // over NL*256*512, layout [l][j][k]
  if (i >= (long)NL * 256 * 512) return;
  int l = (int)(i / (256 * 512));
  int rem = (int)(i % (256 * 512));
  int j = rem / 512;
  int k = rem % 512;
  float v = (k < 256) ? wn[(long)l * 65536 + k * 256 + j]
                      : lw[(long)l * 65536 + (k - 256) * 256 + j];
  wc[i] = f2b(v);
}

__global__ void h0init_k(const float* __restrict__ er, float* __restrict__ h0,
                         short* __restrict__ h0b)
{
  long i = (long)blockIdx.x * 256 + threadIdx.x;
  if (i < (long)R2 * H) { float v = er[i]; h0[i] = v; h0b[i] = f2b(v); }
}

// ---------------- r2e CSR build + segment mean -----------------------------------
__global__ __launch_bounds__(256)
void hist_k(const int* __restrict__ rel, unsigned* __restrict__ cnt, int m)
{
  __shared__ unsigned lh[R2];
  for (int i = threadIdx.x; i < R2; i += 256) lh[i] = 0;
  __syncthreads();
  for (long i = (long)blockIdx.x * 256 + threadIdx.x; i < m; i += (long)gridDim.x * 256)
    atomicAdd(&lh[rel[i]], 1u);
  __syncthreads();
  for (int i = threadIdx.x; i < R2; i += 256)
    if (lh[i]) atomicAdd(&cnt[i], lh[i]);
}

__global__ void prefix_k(const unsigned* __restrict__ cnt, unsigned* __restrict__ off)
{
  __shared__ unsigned c[R2];
  for (int i = threadIdx.x; i < R2; i += 256) c[i] = cnt[i];
  __syncthreads();
  if (threadIdx.x == 0) {
    unsigned run = 0;
    for (int i = 0; i < R2; ++i) { off[i] = run; run += c[i]; }
    off[R2] = run;
  }
}

__global__ __launch_bounds__(256)
void scatter_k(const int* __restrict__ rel, const int* __restrict__ ent,
               const unsigned* __restrict__ off, unsigned* __restrict__ cur,
               int* __restrict__ se, int m)
{
  for (long i = (long)blockIdx.x * 256 + threadIdx.x; i < m; i += (long)gridDim.x * 256) {
    int r = rel[i];
    unsigned p = atomicAdd(&cur[r], 1u);
    se[off[r] + p] = ent[i];
  }
}

__global__ __launch_bounds__(256)
void segmean_k(const unsigned* __restrict__ off, const int* __restrict__ se,
               const short* __restrict__ hb, short* __restrict__ x_inb)
{
  const int r = blockIdx.x;
  const int tid = threadIdx.x;
  const unsigned b = off[r], e2 = off[r + 1];
  float a0 = 0.f, a1 = 0.f, a2 = 0.f, a3 = 0.f;
  unsigned i = b;
  for (; i + 4 <= e2; i += 4) {
    int e0 = se[i], eA = se[i+1], eB = se[i+2], eC = se[i+3];
    a0 += b2f(hb[(long)e0 * 512 + tid]);
    a1 += b2f(hb[(long)eA * 512 + tid]);
    a2 += b2f(hb[(long)eB * 512 + tid]);
    a3 += b2f(hb[(long)eC * 512 + tid]);
  }
  for (; i < e2; ++i) a0 += b2f(hb[(long)se[i] * 512 + tid]);
  float acc = (a0 + a1) + (a2 + a3);
  float c = fmaxf((float)(e2 - b), 1.f);
  x_inb[(long)r * H + tid] = f2b(acc / c);
}

// ---------------- GRU gates ------------------------------------------------------
__global__ __launch_bounds__(256)
void gate_k(const float* __restrict__ gx, const float* __restrict__ gh,
            float* __restrict__ h0, short* __restrict__ h0b, float* __restrict__ relout)
{
  __shared__ float red[4];
  const int r = blockIdx.x, c = threadIdx.x;
  const long b = (long)r * 768;
  float xr = gx[b + c], xz = gx[b + 256 + c], xn = gx[b + 512 + c];
  float hr = gh[b + c], hz = gh[b + 256 + c], hn = gh[b + 512 + c];
  float rr = 1.f / (1.f + expf(-(xr + hr)));
  float z  = 1.f / (1.f + expf(-(xz + hz)));
  float nn = tanhf(xn + rr * hn);
  float v = (1.f - z) * nn + z * h0[(long)r * H + c];
  float s = v * v;
  s += __shfl_xor(s, 1, 64);  s += __shfl_xor(s, 2, 64);
  s += __shfl_xor(s, 4, 64);  s += __shfl_xor(s, 8, 64);
  s += __shfl_xor(s, 16, 64); s += __shfl_xor(s, 32, 64);
  const int w = c >> 6;
  if ((c & 63) == 0) red[w] = s;
  __syncthreads();
  float tot = (red[0] + red[1]) + (red[2] + red[3]);
  float sc = 1.f / fmaxf(sqrtf(tot), 1e-12f);
  v *= sc;
  h0[(long)r * H + c] = v;
  h0b[(long)r * H + c] = f2b(v);
  relout[(long)r * H + c] = v;
}

// ---------------- degree / norm / zero-list --------------------------------------
__global__ __launch_bounds__(256)
void deg_k(const int* __restrict__ dst, unsigned* __restrict__ deg, int e)
{
  for (long i = (long)blockIdx.x * 256 + threadIdx.x; i < e; i += (long)gridDim.x * 256)
    atomicAdd(&deg[dst[i]], 1u);
}

__global__ __launch_bounds__(256)
void norm_k(const unsigned* __restrict__ deg, float* __restrict__ nrm,
            unsigned* __restrict__ zl, unsigned* __restrict__ nz)
{
  int i = blockIdx.x * 256 + threadIdx.x;
  if (i < N_ENTS) {
    unsigned d = deg[i];
    nrm[i] = 1.f / fmaxf((float)d, 1.f);
    if (d == 0u) { unsigned p = atomicAdd(nz, 1u); zl[p] = i; }
  }
}

// ---------------- edge aggregation (atomics) -------------------------------------
__global__ __launch_bounds__(256)
void edge_agg_k(const int* __restrict__ src, const int* __restrict__ dst,
                const int* __restrict__ et, const short* __restrict__ hb,
                const short* __restrict__ h0b, float* __restrict__ pre)
{
  const int w = threadIdx.x >> 6, lane = threadIdx.x & 63;
  const int e = blockIdx.x * 4 + w;
  const int s = src[e], d = dst[e], r = et[e];
  short4v hv = *(const short4v*)&hb[(long)s * 512 + lane * 4];
  short4v rv = *(const short4v*)&h0b[(long)r * H + lane * 4];
  float* p = &pre[(long)d * H + lane * 4];
  atomicAdd(p + 0, b2f(hv[0]) + b2f(rv[0]));
  atomicAdd(p + 1, b2f(hv[1]) + b2f(rv[1]));
  atomicAdd(p + 2, b2f(hv[2]) + b2f(rv[2]));
  atomicAdd(p + 3, b2f(hv[3]) + b2f(rv[3]));
}

// ---------------- pre*norm -> bf16 halfA, re-zero pre ----------------------------
__global__ __launch_bounds__(256)
void conv_k(float* __restrict__ pre, const float* __restrict__ nrm, short* __restrict__ ah)
{
  long i4 = ((long)blockIdx.x * 256 + threadIdx.x) * 4;
  int row = (int)(i4 >> 8);
  float nv = nrm[row];
  f32x4 v = *(f32x4*)&pre[i4];
  short4v o;
  o[0] = f2b(v[0] * nv); o[1] = f2b(v[1] * nv);
  o[2] = f2b(v[2] * nv); o[3] = f2b(v[3] * nv);
  *(short4v*)&ah[(long)row * 512 + (int)(i4 & 255)] = o;
  f32x4 z; z[0] = 0.f; z[1] = 0.f; z[2] = 0.f; z[3] = 0.f;
  *(f32x4*)&pre[i4] = z;
}

// ---------------- deg==0 fixup: row = rrelu(hc @ evolve_w) (+l2norm if final) ----
template<int FINAL>
__global__ __launch_bounds__(256)
void fixup_k(const unsigned* __restrict__ nz, const unsigned* __restrict__ zl,
             const short* __restrict__ hbc, const short* __restrict__ evb,
             short* __restrict__ hbn, float* __restrict__ outF)
{
  __shared__ float x[H];
  __shared__ float red[4];
  const unsigned n = *nz;
  for (unsigned zi = blockIdx.x; zi < n; zi += gridDim.x) {
    const int row = zl[zi];
    __syncthreads();
    x[threadIdx.x] = b2f(hbc[(long)row * 512 + threadIdx.x]);
    __syncthreads();
    float acc = 0.f;
#pragma unroll 4
    for (int k = 0; k < H; ++k) acc += x[k] * b2f(evb[k * H + threadIdx.x]);
    float v = acc >= 0.f ? acc : acc * SLOPE;
    if (FINAL) {
      float s = v * v;
      s += __shfl_xor(s, 1, 64);  s += __shfl_xor(s, 2, 64);
      s += __shfl_xor(s, 4, 64);  s += __shfl_xor(s, 8, 64);
      s += __shfl_xor(s, 16, 64); s += __shfl_xor(s, 32, 64);
      const int w = threadIdx.x >> 6;
      if ((threadIdx.x & 63) == 0) red[w] = s;
      __syncthreads();
      float tot = (red[0] + red[1]) + (red[2] + red[3]);
      float sc = 1.f / fmaxf(sqrtf(tot), 1e-12f);
      v *= sc;
      outF[(long)row * H + threadIdx.x] = v;
    }
    hbn[(long)row * 512 + threadIdx.x] = f2b(v);
  }
}

// =================================================================================
extern "C" void kernel_launch(void* const* d_in, const int* in_sizes, int n_in,
                              void* d_out, int out_size, void* d_ws, size_t ws_size,
                              hipStream_t stream)
{
  (void)in_sizes; (void)n_in; (void)out_size; (void)ws_size;
  const int* src = (const int*)d_in[0];
  const int* dst = (const int*)d_in[1];
  const int* ety = (const int*)d_in[2];
  const int* r2e_ent = (const int*)d_in[3];
  const int* r2e_rel = (const int*)d_in[4];
  const float* dyn = (const float*)d_in[5];
  const float* erel = (const float*)d_in[6];
  const float* wn = (const float*)d_in[7];
  const float* lw = (const float*)d_in[8];
  const float* ew = (const float*)d_in[9];
  const float* wih = (const float*)d_in[10];
  const float* whh = (const float*)d_in[11];
  const float* bih = (const float*)d_in[12];
  const float* bhh = (const float*)d_in[13];

  float* out = (float*)d_out;
  float* hist = out;
  float* rels = out + (long)TSTEPS * N_ENTS * H;

  char* p = (char*)d_ws;
  auto alloc = [&](size_t n) { char* r = p; p += (n + 255) & ~(size_t)255; return r; };
  float*    pre    = (float*)alloc((size_t)N_ENTS * H * 4);
  short*    AcatA  = (short*)alloc((size_t)N_ENTS * 512 * 2);
  short*    AcatB  = (short*)alloc((size_t)N_ENTS * 512 * 2);
  unsigned* deg    = (unsigned*)alloc((size_t)N_ENTS * 4);
  float*    nrm    = (float*)alloc((size_t)N_ENTS * 4);
  unsigned* zl     = (unsigned*)alloc((size_t)N_ENTS * 4);
  unsigned* nz     = (unsigned*)alloc(256);
  unsigned* cnt    = (unsigned*)alloc(R2 * 4);
  unsigned* off    = (unsigned*)alloc((R2 + 1) * 4);
  unsigned* cur    = (unsigned*)alloc(R2 * 4);
  int*      se     = (int*)alloc((size_t)NM * 4);
  short*    x_inb  = (short*)alloc((size_t)R2 * H * 2);
  float*    gxbase = (float*)alloc((size_t)R2 * 768 * 4);
  float*    gx     = (float*)alloc((size_t)R2 * 768 * 4);
  float*    gh     = (float*)alloc((size_t)R2 * 768 * 4);
  float*    h0     = (float*)alloc((size_t)R2 * H * 4);
  short*    h0b    = (short*)alloc((size_t)R2 * H * 2);
  short*    erelb  = (short*)alloc((size_t)R2 * H * 2);
  short*    wcatb  = (short*)alloc((size_t)NL * 256 * 512 * 2);
  short*    evb    = (short*)alloc((size_t)NL * H * H * 2);
  short*    wihb   = (short*)alloc((size_t)768 * 512 * 2);
  short*    whhb   = (short*)alloc((size_t)768 * 256 * 2);

  hipMemsetAsync(pre, 0, (size_t)N_ENTS * H * 4, stream);

  wcat_k<<<(NL * 256 * 512 + 255) / 256, 256, 0, stream>>>(wn, lw, wcatb);
  castcopy_k<<<(NL * H * H + 255) / 256, 256, 0, stream>>>(ew, evb, (long)NL * H * H);
  castcopy_k<<<(768 * 512 + 255) / 256, 256, 0, stream>>>(wih, wihb, 768 * 512);
  castcopy_k<<<(768 * 256 + 255) / 256, 256, 0, stream>>>(whh, whhb, 768 * 256);
  castcopy_k<<<(R2 * H + 255) / 256, 256, 0, stream>>>(erel, erelb, (long)R2 * H);
  h0init_k<<<(R2 * H + 255) / 256, 256, 0, stream>>>(erel, h0, h0b);
  l2init_k<<<N_ENTS / 4, 256, 0, stream>>>(dyn, AcatA + 256);

  // gx_base = emb_rel @ W_ih[:, :256]^T + b_ih   (step-invariant)
  gemm_k<0><<<dim3(8, 3), 256, 0, stream>>>(erelb, 256, wihb, 512, R2, 256,
                                            gxbase, 768, nullptr, bih, nullptr, 0);

  short* Acur = AcatA;
  short* Anxt = AcatB;

  for (int t = 0; t < TSTEPS; ++t) {
    const int* src_t = src + (long)t * NE;
    const int* dst_t = dst + (long)t * NE;
    const int* ety_t = ety + (long)t * NE;
    const int* re_t  = r2e_ent + (long)t * NM;
    const int* rr_t  = r2e_rel + (long)t * NM;
    float* hist_t = hist + (long)t * N_ENTS * H;
    float* rels_t = rels + (long)t * R2 * H;

    hipMemsetAsync(cnt, 0, R2 * 4, stream);
    hipMemsetAsync(cur, 0, R2 * 4, stream);
    hipMemsetAsync(deg, 0, (size_t)N_ENTS * 4, stream);
    hipMemsetAsync(nz, 0, 4, stream);

    // relation mean via CSR
    hist_k<<<256, 256, 0, stream>>>(rr_t, cnt, NM);
    prefix_k<<<1, 256, 0, stream>>>(cnt, off);
    scatter_k<<<256, 256, 0, stream>>>(rr_t, re_t, off, cur, se, NM);
    segmean_k<<<R2, 256, 0, stream>>>(off, se, Acur + 256, x_inb);

    // GRU
    gemm_k<0><<<dim3(8, 3), 256, 0, stream>>>(x_inb, 256, wihb + 256, 512, R2, 256,
                                              gx, 768, gxbase, nullptr, nullptr, 0);
    gemm_k<0><<<dim3(8, 3), 256, 0, stream>>>(h0b, 256, whhb, 256, R2, 256,
                                              gh, 768, nullptr, bhh, nullptr, 0);
    gate_k<<<R2, 256, 0, stream>>>(gx, gh, h0, h0b, rels_t);

    // degree / norm / zero-degree list
    deg_k<<<512, 256, 0, stream>>>(dst_t, deg, NE);
    norm_k<<<(N_ENTS + 255) / 256, 256, 0, stream>>>(deg, nrm, zl, nz);

    for (int l = 0; l < NL; ++l) {
      edge_agg_k<<<NE / 4, 256, 0, stream>>>(src_t, dst_t, ety_t, Acur + 256, h0b, pre);
      conv_k<<<N_ENTS / 4, 256, 0, stream>>>(pre, nrm, Acur);
      if (l == NL - 1) {
        gemm_k<2><<<dim3(782, 1), 256, 0, stream>>>(Acur, 512, wcatb + (long)l * 256 * 512, 512,
                                                    N_ENTS, 512, hist_t, 256, nullptr, nullptr,
                                                    Anxt + 256, 512);
        fixup_k<1><<<512, 256, 0, stream>>>(nz, zl, Acur + 256, evb + (long)l * H * H,
                                            Anxt + 256, hist_t);
      } else {
        gemm_k<1><<<dim3(782, 1), 256, 0, stream>>>(Acur, 512, wcatb + (long)l * 256 * 512, 512,
                                                    N_ENTS, 512, nullptr, 0, nullptr, nullptr,
                                                    Anxt + 256, 512);
        fixup_k<0><<<512, 256, 0, stream>>>(nz, zl, Acur + 256, evb + (long)l * H * H,
                                            Anxt + 256, nullptr);
      }
      short* tmp = Acur; Acur = Anxt; Anxt = tmp;
    }
  }
}

// Round 2
// 2024.514 us; speedup vs baseline: 3.5243x; 3.5243x over previous
//
#include <hip/hip_runtime.h>

#define N_ENTS 50000
#define R2 500
#define H 256
#define TSTEPS 4
#define NE 200000
#define NM 200000
#define NL 2
#define SLOPE 0.22916666666666666f
#define SCAN_NB ((N_ENTS + 255) / 256)   // 196

typedef __attribute__((ext_vector_type(8))) short short8;
typedef __attribute__((ext_vector_type(4))) short short4v;
typedef __attribute__((ext_vector_type(4))) float f32x4;

static __device__ __forceinline__ float b2f(short s) {
  unsigned u = ((unsigned)(unsigned short)s) << 16;
  return __builtin_bit_cast(float, u);
}
static __device__ __forceinline__ short f2b(float f) {
  unsigned u = __builtin_bit_cast(unsigned, f);
  u = (u + 0x7FFFu + ((u >> 16) & 1u)) >> 16;
  return (short)(unsigned short)u;
}

// ---------------- GEMM: C[M x Ncols] = A[M x K](bf16) * Bt[Ncols x K](bf16)^T ----
// EPI 0: Cf = acc (+Cadd)(+bias)            (f32 out, ldc)
// EPI 1: Obf = bf16(rrelu(acc))             (ldo)
// EPI 2: l2norm(rrelu(acc)) -> Cf (f32) and Obf (bf16)
template<int EPI>
__global__ __launch_bounds__(256)
void gemm_k(const short* __restrict__ A, int lda,
            const short* __restrict__ Bt, int ldb,
            int M, int K,
            float* __restrict__ Cf, int ldc,
            const float* __restrict__ Cadd,
            const float* __restrict__ bias,
            short* __restrict__ Obf, int ldo)
{
  __shared__ short bt[256 * 72];
  const int tid = threadIdx.x;
  const int w = tid >> 6;
  const int lane = tid & 63;
  const int fr = lane & 15;
  const int fq = lane >> 4;
  const int col0 = blockIdx.y << 8;
  const int rowbase = blockIdx.x * 64 + w * 16;
  const int arow = min(rowbase + fr, M - 1);
  const long abase = (long)arow * lda + fq * 8;

  f32x4 acc[16];
#pragma unroll
  for (int i = 0; i < 16; ++i) { acc[i][0] = 0.f; acc[i][1] = 0.f; acc[i][2] = 0.f; acc[i][3] = 0.f; }

  for (int kc = 0; kc < K; kc += 64) {
    __syncthreads();
    {
      const short* g = Bt + (long)(col0 + tid) * ldb + kc;
      short* l = &bt[tid * 72];
#pragma unroll
      for (int i = 0; i < 8; ++i)
        *(short8*)(l + i * 8) = *(const short8*)(g + i * 8);
    }
    __syncthreads();
#pragma unroll
    for (int ks = 0; ks < 2; ++ks) {
      short8 a = *(const short8*)(A + abase + kc + ks * 32);
#pragma unroll
      for (int ct = 0; ct < 16; ++ct) {
        short8 b = *(const short8*)&bt[(ct * 16 + fr) * 72 + ks * 32 + fq * 8];
        acc[ct] = __builtin_amdgcn_mfma_f32_16x16x32_bf16(a, b, acc[ct], 0, 0, 0);
      }
    }
  }

  const int crow = rowbase + fq * 4;
  if (EPI == 0) {
#pragma unroll
    for (int ct = 0; ct < 16; ++ct) {
      const int gcol = col0 + ct * 16 + fr;
#pragma unroll
      for (int j = 0; j < 4; ++j) {
        const int r = crow + j;
        if (r < M) {
          float v = acc[ct][j];
          if (Cadd) v += Cadd[(long)r * ldc + gcol];
          if (bias) v += bias[gcol];
          Cf[(long)r * ldc + gcol] = v;
        }
      }
    }
  } else {
    float ss[4];
#pragma unroll
    for (int j = 0; j < 4; ++j) ss[j] = 0.f;
#pragma unroll
    for (int ct = 0; ct < 16; ++ct) {
#pragma unroll
      for (int j = 0; j < 4; ++j) {
        float v = acc[ct][j];
        v = v >= 0.f ? v : v * SLOPE;
        acc[ct][j] = v;
        ss[j] += v * v;
      }
    }
    if (EPI == 2) {
#pragma unroll
      for (int j = 0; j < 4; ++j) {
        float s = ss[j];
        s += __shfl_xor(s, 1, 64);
        s += __shfl_xor(s, 2, 64);
        s += __shfl_xor(s, 4, 64);
        s += __shfl_xor(s, 8, 64);
        ss[j] = 1.f / fmaxf(sqrtf(s), 1e-12f);
      }
    }
#pragma unroll
    for (int ct = 0; ct < 16; ++ct) {
      const int gcol = ct * 16 + fr;   // EPI 1/2 used only with gridDim.y == 1
#pragma unroll
      for (int j = 0; j < 4; ++j) {
        const int r = crow + j;
        if (r < M) {
          float v = acc[ct][j];
          if (EPI == 2) {
            v *= ss[j];
            Cf[(long)r * ldc + gcol] = v;
          }
          Obf[(long)r * ldo + gcol] = f2b(v);
        }
      }
    }
  }
}

// ---------------- init: h = l2norm(dynamic_emb) -> bf16 into Acat halfB ----------
__global__ __launch_bounds__(256)
void l2init_k(const float* __restrict__ de, short* __restrict__ hb)
{
  const int w = threadIdx.x >> 6, lane = threadIdx.x & 63;
  const int row = blockIdx.x * 4 + w;
  f32x4 v = *(const f32x4*)&de[(long)row * H + lane * 4];
  float s = v[0]*v[0] + v[1]*v[1] + v[2]*v[2] + v[3]*v[3];
  s += __shfl_xor(s, 1, 64);  s += __shfl_xor(s, 2, 64);
  s += __shfl_xor(s, 4, 64);  s += __shfl_xor(s, 8, 64);
  s += __shfl_xor(s, 16, 64); s += __shfl_xor(s, 32, 64);
  float sc = 1.f / fmaxf(sqrtf(s), 1e-12f);
  short4v o;
  o[0] = f2b(v[0]*sc); o[1] = f2b(v[1]*sc); o[2] = f2b(v[2]*sc); o[3] = f2b(v[3]*sc);
  *(short4v*)&hb[(long)row * 512 + lane * 4] = o;
}

// ---------------- weight prep ----------------------------------------------------
__global__ void castcopy_k(const float* __restrict__ in, short* __restrict__ out, long n)
{
  long i = (long)blockIdx.x * 256 + threadIdx.x;
  if (i < n) out[i] = f2b(in[i]);
}

__global__ void wcat_k(const float* __restrict__ wn, const float* __restrict__ lw,
                       short* __restrict__ wc)
{
  long i = (long)blockIdx.x * 256 + threadIdx.x;  // over NL*256*512, layout [l][j][k]
  if (i >= (long)NL * 256 * 512) return;
  int l = (int)(i / (256 * 512));
  int rem = (int)(i % (256 * 512));
  int j = rem / 512;
  int k = rem % 512;
  float v = (k < 256) ? wn[(long)l * 65536 + k * 256 + j]
                      : lw[(long)l * 65536 + (k - 256) * 256 + j];
  wc[i] = f2b(v);
}

__global__ void h0init_k(const float* __restrict__ er, float* __restrict__ h0,
                         short* __restrict__ h0b)
{
  long i = (long)blockIdx.x * 256 + threadIdx.x;
  if (i < (long)R2 * H) { float v = er[i]; h0[i] = v; h0b[i] = f2b(v); }
}

// ---------------- r2e CSR build + segment mean -----------------------------------
__global__ __launch_bounds__(256)
void hist_k(const int* __restrict__ rel, unsigned* __restrict__ cnt, int m)
{
  __shared__ unsigned lh[R2];
  for (int i = threadIdx.x; i < R2; i += 256) lh[i] = 0;
  __syncthreads();
  for (long i = (long)blockIdx.x * 256 + threadIdx.x; i < m; i += (long)gridDim.x * 256)
    atomicAdd(&lh[rel[i]], 1u);
  __syncthreads();
  for (int i = threadIdx.x; i < R2; i += 256)
    if (lh[i]) atomicAdd(&cnt[i], lh[i]);
}

__global__ void prefix_k(const unsigned* __restrict__ cnt, unsigned* __restrict__ off)
{
  __shared__ unsigned c[R2];
  for (int i = threadIdx.x; i < R2; i += 256) c[i] = cnt[i];
  __syncthreads();
  if (threadIdx.x == 0) {
    unsigned run = 0;
    for (int i = 0; i < R2; ++i) { off[i] = run; run += c[i]; }
    off[R2] = run;
  }
}

__global__ __launch_bounds__(256)
void scatter_k(const int* __restrict__ rel, const int* __restrict__ ent,
               const unsigned* __restrict__ off, unsigned* __restrict__ cur,
               int* __restrict__ se, int m)
{
  for (long i = (long)blockIdx.x * 256 + threadIdx.x; i < m; i += (long)gridDim.x * 256) {
    int r = rel[i];
    unsigned p = atomicAdd(&cur[r], 1u);
    se[off[r] + p] = ent[i];
  }
}

__global__ __launch_bounds__(256)
void segmean_k(const unsigned* __restrict__ off, const int* __restrict__ se,
               const short* __restrict__ hb, short* __restrict__ x_inb)
{
  const int r = blockIdx.x;
  const int tid = threadIdx.x;
  const unsigned b = off[r], e2 = off[r + 1];
  float a0 = 0.f, a1 = 0.f, a2 = 0.f, a3 = 0.f;
  unsigned i = b;
  for (; i + 4 <= e2; i += 4) {
    int e0 = se[i], eA = se[i+1], eB = se[i+2], eC = se[i+3];
    a0 += b2f(hb[(long)e0 * 512 + tid]);
    a1 += b2f(hb[(long)eA * 512 + tid]);
    a2 += b2f(hb[(long)eB * 512 + tid]);
    a3 += b2f(hb[(long)eC * 512 + tid]);
  }
  for (; i < e2; ++i) a0 += b2f(hb[(long)se[i] * 512 + tid]);
  float acc = (a0 + a1) + (a2 + a3);
  float c = fmaxf((float)(e2 - b), 1.f);
  x_inb[(long)r * H + tid] = f2b(acc / c);
}

// ---------------- GRU gates ------------------------------------------------------
__global__ __launch_bounds__(256)
void gate_k(const float* __restrict__ gx, const float* __restrict__ gh,
            float* __restrict__ h0, short* __restrict__ h0b, float* __restrict__ relout)
{
  __shared__ float red[4];
  const int r = blockIdx.x, c = threadIdx.x;
  const long b = (long)r * 768;
  float xr = gx[b + c], xz = gx[b + 256 + c], xn = gx[b + 512 + c];
  float hr = gh[b + c], hz = gh[b + 256 + c], hn = gh[b + 512 + c];
  float rr = 1.f / (1.f + expf(-(xr + hr)));
  float z  = 1.f / (1.f + expf(-(xz + hz)));
  float nn = tanhf(xn + rr * hn);
  float v = (1.f - z) * nn + z * h0[(long)r * H + c];
  float s = v * v;
  s += __shfl_xor(s, 1, 64);  s += __shfl_xor(s, 2, 64);
  s += __shfl_xor(s, 4, 64);  s += __shfl_xor(s, 8, 64);
  s += __shfl_xor(s, 16, 64); s += __shfl_xor(s, 32, 64);
  const int w = c >> 6;
  if ((c & 63) == 0) red[w] = s;
  __syncthreads();
  float tot = (red[0] + red[1]) + (red[2] + red[3]);
  float sc = 1.f / fmaxf(sqrtf(tot), 1e-12f);
  v *= sc;
  h0[(long)r * H + c] = v;
  h0b[(long)r * H + c] = f2b(v);
  relout[(long)r * H + c] = v;
}

// ---------------- dst-degree count ------------------------------------------------
__global__ __launch_bounds__(256)
void deg_k(const int* __restrict__ dst, unsigned* __restrict__ deg, int e)
{
  for (long i = (long)blockIdx.x * 256 + threadIdx.x; i < e; i += (long)gridDim.x * 256)
    atomicAdd(&deg[dst[i]], 1u);
}

// ---------------- 3-phase exclusive scan over deg[N_ENTS] -> offd -----------------
__global__ __launch_bounds__(256)
void scan1_k(const unsigned* __restrict__ deg, unsigned* __restrict__ offd,
             unsigned* __restrict__ bsum)
{
  __shared__ unsigned s[256];
  const int tid = threadIdx.x;
  const int i = blockIdx.x * 256 + tid;
  unsigned v = (i < N_ENTS) ? deg[i] : 0u;
  s[tid] = v;
  __syncthreads();
#pragma unroll
  for (int d = 1; d < 256; d <<= 1) {
    unsigned t = (tid >= d) ? s[tid - d] : 0u;
    __syncthreads();
    s[tid] += t;
    __syncthreads();
  }
  if (i < N_ENTS) offd[i] = s[tid] - v;            // block-local exclusive
  if (tid == 255) bsum[blockIdx.x] = s[255];
}

__global__ __launch_bounds__(256)
void scan2_k(unsigned* __restrict__ bsum)
{
  __shared__ unsigned s[256];
  const int tid = threadIdx.x;
  unsigned v = (tid < SCAN_NB) ? bsum[tid] : 0u;
  s[tid] = v;
  __syncthreads();
#pragma unroll
  for (int d = 1; d < 256; d <<= 1) {
    unsigned t = (tid >= d) ? s[tid - d] : 0u;
    __syncthreads();
    s[tid] += t;
    __syncthreads();
  }
  if (tid < SCAN_NB) bsum[tid] = s[tid] - v;       // exclusive block offsets
}

__global__ __launch_bounds__(256)
void scan3_k(unsigned* __restrict__ offd, const unsigned* __restrict__ bsum,
             const unsigned* __restrict__ deg,
             unsigned* __restrict__ zl, unsigned* __restrict__ nz)
{
  const int i = blockIdx.x * 256 + threadIdx.x;
  if (i < N_ENTS) {
    offd[i] += bsum[blockIdx.x];
    if (deg[i] == 0u) { unsigned p = atomicAdd(nz, 1u); zl[p] = i; }
  }
  if (i == 0) offd[N_ENTS] = NE;
}

// ---------------- scatter (src,etype) into dst-CSR --------------------------------
__global__ __launch_bounds__(256)
void scatter2_k(const int* __restrict__ src, const int* __restrict__ dst,
                const int* __restrict__ et, const unsigned* __restrict__ offd,
                unsigned* __restrict__ cur, int2* __restrict__ se2, int e)
{
  for (long i = (long)blockIdx.x * 256 + threadIdx.x; i < e; i += (long)gridDim.x * 256) {
    int d = dst[i];
    unsigned p = atomicAdd(&cur[d], 1u);
    se2[offd[d] + p] = make_int2(src[i], et[i]);
  }
}

// ---------------- CSR segmented aggregation: ah[row] = bf16(norm * sum) ----------
__global__ __launch_bounds__(256)
void agg_k(const int2* __restrict__ se2, const unsigned* __restrict__ offd,
           const short* __restrict__ hb, const short* __restrict__ h0b,
           short* __restrict__ ah)
{
  const int w = threadIdx.x >> 6, lane = threadIdx.x & 63;
  const int row = blockIdx.x * 4 + w;
  const unsigned b = offd[row], e2 = offd[row + 1];
  float a0 = 0.f, a1 = 0.f, a2 = 0.f, a3 = 0.f;
  for (unsigned i = b; i < e2; ++i) {
    int2 p = se2[i];
    short4v hv = *(const short4v*)&hb[(long)p.x * 512 + lane * 4];
    short4v rv = *(const short4v*)&h0b[(long)p.y * H + lane * 4];
    a0 += b2f(hv[0]) + b2f(rv[0]);
    a1 += b2f(hv[1]) + b2f(rv[1]);
    a2 += b2f(hv[2]) + b2f(rv[2]);
    a3 += b2f(hv[3]) + b2f(rv[3]);
  }
  const float nm = 1.f / fmaxf((float)(e2 - b), 1.f);
  short4v o;
  o[0] = f2b(a0 * nm); o[1] = f2b(a1 * nm); o[2] = f2b(a2 * nm); o[3] = f2b(a3 * nm);
  *(short4v*)&ah[(long)row * 512 + lane * 4] = o;
}

// ---------------- deg==0 fixup: row = rrelu(hc @ evolve_w) (+l2norm if final) ----
template<int FINAL>
__global__ __launch_bounds__(256)
void fixup_k(const unsigned* __restrict__ nz, const unsigned* __restrict__ zl,
             const short* __restrict__ hbc, const short* __restrict__ evb,
             short* __restrict__ hbn, float* __restrict__ outF)
{
  __shared__ float x[H];
  __shared__ float red[4];
  const unsigned n = *nz;
  for (unsigned zi = blockIdx.x; zi < n; zi += gridDim.x) {
    const int row = zl[zi];
    __syncthreads();
    x[threadIdx.x] = b2f(hbc[(long)row * 512 + threadIdx.x]);
    __syncthreads();
    float acc = 0.f;
#pragma unroll 4
    for (int k = 0; k < H; ++k) acc += x[k] * b2f(evb[k * H + threadIdx.x]);
    float v = acc >= 0.f ? acc : acc * SLOPE;
    if (FINAL) {
      float s = v * v;
      s += __shfl_xor(s, 1, 64);  s += __shfl_xor(s, 2, 64);
      s += __shfl_xor(s, 4, 64);  s += __shfl_xor(s, 8, 64);
      s += __shfl_xor(s, 16, 64); s += __shfl_xor(s, 32, 64);
      const int w = threadIdx.x >> 6;
      if ((threadIdx.x & 63) == 0) red[w] = s;
      __syncthreads();
      float tot = (red[0] + red[1]) + (red[2] + red[3]);
      float sc = 1.f / fmaxf(sqrtf(tot), 1e-12f);
      v *= sc;
      outF[(long)row * H + threadIdx.x] = v;
    }
    hbn[(long)row * 512 + threadIdx.x] = f2b(v);
  }
}

// =================================================================================
extern "C" void kernel_launch(void* const* d_in, const int* in_sizes, int n_in,
                              void* d_out, int out_size, void* d_ws, size_t ws_size,
                              hipStream_t stream)
{
  (void)in_sizes; (void)n_in; (void)out_size; (void)ws_size;
  const int* src = (const int*)d_in[0];
  const int* dst = (const int*)d_in[1];
  const int* ety = (const int*)d_in[2];
  const int* r2e_ent = (const int*)d_in[3];
  const int* r2e_rel = (const int*)d_in[4];
  const float* dyn = (const float*)d_in[5];
  const float* erel = (const float*)d_in[6];
  const float* wn = (const float*)d_in[7];
  const float* lw = (const float*)d_in[8];
  const float* ew = (const float*)d_in[9];
  const float* wih = (const float*)d_in[10];
  const float* whh = (const float*)d_in[11];
  const float* bih = (const float*)d_in[12];
  const float* bhh = (const float*)d_in[13];

  float* out = (float*)d_out;
  float* hist = out;
  float* rels = out + (long)TSTEPS * N_ENTS * H;

  char* p = (char*)d_ws;
  auto alloc = [&](size_t n) { char* r = p; p += (n + 255) & ~(size_t)255; return r; };
  short*    AcatA  = (short*)alloc((size_t)N_ENTS * 512 * 2);
  short*    AcatB  = (short*)alloc((size_t)N_ENTS * 512 * 2);
  unsigned* deg    = (unsigned*)alloc((size_t)N_ENTS * 4);
  unsigned* offd   = (unsigned*)alloc((size_t)(N_ENTS + 1) * 4);
  unsigned* curd   = (unsigned*)alloc((size_t)N_ENTS * 4);
  unsigned* bsum   = (unsigned*)alloc((size_t)SCAN_NB * 4);
  int2*     se2    = (int2*)alloc((size_t)NE * 8);
  unsigned* zl     = (unsigned*)alloc((size_t)N_ENTS * 4);
  unsigned* nz     = (unsigned*)alloc(256);
  unsigned* cnt    = (unsigned*)alloc(R2 * 4);
  unsigned* off    = (unsigned*)alloc((R2 + 1) * 4);
  unsigned* cur    = (unsigned*)alloc(R2 * 4);
  int*      se     = (int*)alloc((size_t)NM * 4);
  short*    x_inb  = (short*)alloc((size_t)R2 * H * 2);
  float*    gxbase = (float*)alloc((size_t)R2 * 768 * 4);
  float*    gx     = (float*)alloc((size_t)R2 * 768 * 4);
  float*    gh     = (float*)alloc((size_t)R2 * 768 * 4);
  float*    h0     = (float*)alloc((size_t)R2 * H * 4);
  short*    h0b    = (short*)alloc((size_t)R2 * H * 2);
  short*    erelb  = (short*)alloc((size_t)R2 * H * 2);
  short*    wcatb  = (short*)alloc((size_t)NL * 256 * 512 * 2);
  short*    evb    = (short*)alloc((size_t)NL * H * H * 2);
  short*    wihb   = (short*)alloc((size_t)768 * 512 * 2);
  short*    whhb   = (short*)alloc((size_t)768 * 256 * 2);

  wcat_k<<<(NL * 256 * 512 + 255) / 256, 256, 0, stream>>>(wn, lw, wcatb);
  castcopy_k<<<(NL * H * H + 255) / 256, 256, 0, stream>>>(ew, evb, (long)NL * H * H);
  castcopy_k<<<(768 * 512 + 255) / 256, 256, 0, stream>>>(wih, wihb, 768 * 512);
  castcopy_k<<<(768 * 256 + 255) / 256, 256, 0, stream>>>(whh, whhb, 768 * 256);
  castcopy_k<<<(R2 * H + 255) / 256, 256, 0, stream>>>(erel, erelb, (long)R2 * H);
  h0init_k<<<(R2 * H + 255) / 256, 256, 0, stream>>>(erel, h0, h0b);
  l2init_k<<<N_ENTS / 4, 256, 0, stream>>>(dyn, AcatA + 256);

  // gx_base = emb_rel @ W_ih[:, :256]^T + b_ih   (step-invariant)
  gemm_k<0><<<dim3(8, 3), 256, 0, stream>>>(erelb, 256, wihb, 512, R2, 256,
                                            gxbase, 768, nullptr, bih, nullptr, 0);

  short* Acur = AcatA;
  short* Anxt = AcatB;

  for (int t = 0; t < TSTEPS; ++t) {
    const int* src_t = src + (long)t * NE;
    const int* dst_t = dst + (long)t * NE;
    const int* ety_t = ety + (long)t * NE;
    const int* re_t  = r2e_ent + (long)t * NM;
    const int* rr_t  = r2e_rel + (long)t * NM;
    float* hist_t = hist + (long)t * N_ENTS * H;
    float* rels_t = rels + (long)t * R2 * H;

    hipMemsetAsync(cnt, 0, R2 * 4, stream);
    hipMemsetAsync(cur, 0, R2 * 4, stream);
    hipMemsetAsync(deg, 0, (size_t)N_ENTS * 4, stream);
    hipMemsetAsync(curd, 0, (size_t)N_ENTS * 4, stream);
    hipMemsetAsync(nz, 0, 4, stream);

    // relation mean via CSR
    hist_k<<<256, 256, 0, stream>>>(rr_t, cnt, NM);
    prefix_k<<<1, 256, 0, stream>>>(cnt, off);
    scatter_k<<<256, 256, 0, stream>>>(rr_t, re_t, off, cur, se, NM);
    segmean_k<<<R2, 256, 0, stream>>>(off, se, Acur + 256, x_inb);

    // GRU
    gemm_k<0><<<dim3(8, 3), 256, 0, stream>>>(x_inb, 256, wihb + 256, 512, R2, 256,
                                              gx, 768, gxbase, nullptr, nullptr, 0);
    gemm_k<0><<<dim3(8, 3), 256, 0, stream>>>(h0b, 256, whhb, 256, R2, 256,
                                              gh, 768, nullptr, bhh, nullptr, 0);
    gate_k<<<R2, 256, 0, stream>>>(gx, gh, h0, h0b, rels_t);

    // dst-CSR build: degree -> scan -> scatter; zero-list fused into scan add-back
    deg_k<<<512, 256, 0, stream>>>(dst_t, deg, NE);
    scan1_k<<<SCAN_NB, 256, 0, stream>>>(deg, offd, bsum);
    scan2_k<<<1, 256, 0, stream>>>(bsum);
    scan3_k<<<SCAN_NB, 256, 0, stream>>>(offd, bsum, deg, zl, nz);
    scatter2_k<<<512, 256, 0, stream>>>(src_t, dst_t, ety_t, offd, curd, se2, NE);

    for (int l = 0; l < NL; ++l) {
      agg_k<<<N_ENTS / 4, 256, 0, stream>>>(se2, offd, Acur + 256, h0b, Acur);
      if (l == NL - 1) {
        gemm_k<2><<<dim3(782, 1), 256, 0, stream>>>(Acur, 512, wcatb + (long)l * 256 * 512, 512,
                                                    N_ENTS, 512, hist_t, 256, nullptr, nullptr,
                                                    Anxt + 256, 512);
        fixup_k<1><<<512, 256, 0, stream>>>(nz, zl, Acur + 256, evb + (long)l * H * H,
                                            Anxt + 256, hist_t);
      } else {
        gemm_k<1><<<dim3(782, 1), 256, 0, stream>>>(Acur, 512, wcatb + (long)l * 256 * 512, 512,
                                                    N_ENTS, 512, nullptr, 0, nullptr, nullptr,
                                                    Anxt + 256, 512);
        fixup_k<0><<<512, 256, 0, stream>>>(nz, zl, Acur + 256, evb + (long)l * H * H,
                                            Anxt + 256, nullptr);
      }
      short* tmp = Acur; Acur = Anxt; Anxt = tmp;
    }
  }
}

// Round 3
// 1642.815 us; speedup vs baseline: 4.3432x; 1.2323x over previous
//
#include <hip/hip_runtime.h>

#define N_ENTS 50000
#define R2 500
#define H 256
#define TSTEPS 4
#define NE 200000
#define NM 200000
#define NL 2
#define SLOPE 0.22916666666666666f
#define SCAN_NB ((N_ENTS + 255) / 256)   // 196

typedef __attribute__((ext_vector_type(8))) short short8;
typedef __attribute__((ext_vector_type(4))) short short4v;
typedef __attribute__((ext_vector_type(4))) float f32x4;

static __device__ __forceinline__ float b2f(short s) {
  unsigned u = ((unsigned)(unsigned short)s) << 16;
  return __builtin_bit_cast(float, u);
}
static __device__ __forceinline__ short f2b(float f) {
  unsigned u = __builtin_bit_cast(unsigned, f);
  u = (u + 0x7FFFu + ((u >> 16) & 1u)) >> 16;
  return (short)(unsigned short)u;
}

static __device__ __forceinline__ void gload16(const short* g, short* l) {
  __builtin_amdgcn_global_load_lds(
      (const __attribute__((address_space(1))) void*)g,
      (__attribute__((address_space(3))) void*)l, 16, 0, 0);
}

// ---------------- big GEMM: C[M x 256] = A[M x K](bf16) * Bt[256 x K](bf16)^T ----
// m97 structure: 128x256 block, BK=64, 4 waves x (64 rows x 128 cols),
// global_load_lds staging with XOR slot-swizzle (slot ^= row&7) both sides.
// EPI 1: Obf = bf16(rrelu(acc))                      (ldo)
// EPI 2: l2norm(rrelu(acc)) -> Cf (f32, ldc) and Obf (bf16, ldo)
template<int EPI>
__global__ __launch_bounds__(256, 2)
void gemm_big(const short* __restrict__ A, int lda,
              const short* __restrict__ Bt, int ldb,
              int M, int K,
              float* __restrict__ Cf, int ldc,
              short* __restrict__ Obf, int ldo)
{
  __shared__ short As[128 * 64];
  __shared__ short Bs[256 * 64];
  const int tid = threadIdx.x;
  const int w = tid >> 6, lane = tid & 63;
  const int fr = lane & 15, fq = lane >> 4;
  const int rowh = w >> 1, colh = w & 1;
  const int blk0 = blockIdx.x * 128;
  const int l8 = lane >> 3, s7 = lane & 7;

  f32x4 acc[4][8];
#pragma unroll
  for (int m = 0; m < 4; ++m)
#pragma unroll
    for (int n = 0; n < 8; ++n) {
      acc[m][n][0] = 0.f; acc[m][n][1] = 0.f; acc[m][n][2] = 0.f; acc[m][n][3] = 0.f;
    }

  for (int kc = 0; kc < K; kc += 64) {
    __syncthreads();
#pragma unroll
    for (int i = 0; i < 4; ++i) {          // A tile: 128 rows x 64 k
      int row = w * 32 + i * 8 + l8;
      int grow = min(blk0 + row, M - 1);
      const short* g = A + (size_t)grow * lda + kc + ((s7 ^ (row & 7)) << 3);
      gload16(g, As + w * 2048 + i * 512);
    }
#pragma unroll
    for (int i = 0; i < 8; ++i) {          // B tile: 256 cols x 64 k
      int row = w * 64 + i * 8 + l8;
      const short* g = Bt + (size_t)row * ldb + kc + ((s7 ^ (row & 7)) << 3);
      gload16(g, Bs + w * 4096 + i * 512);
    }
    __syncthreads();
#pragma unroll
    for (int ks = 0; ks < 2; ++ks) {
      const int sl = ((((ks << 2) | fq) ^ s7) << 3);
      short8 a[4], b[8];
#pragma unroll
      for (int m = 0; m < 4; ++m)
        a[m] = *(const short8*)&As[(rowh * 64 + m * 16 + fr) * 64 + sl];
#pragma unroll
      for (int n = 0; n < 8; ++n)
        b[n] = *(const short8*)&Bs[(colh * 128 + n * 16 + fr) * 64 + sl];
#pragma unroll
      for (int m = 0; m < 4; ++m)
#pragma unroll
        for (int n = 0; n < 8; ++n)
          acc[m][n] = __builtin_amdgcn_mfma_f32_16x16x32_bf16(a[m], b[n], acc[m][n], 0, 0, 0);
    }
  }

  if (EPI == 1) {
#pragma unroll
    for (int m = 0; m < 4; ++m)
#pragma unroll
      for (int n = 0; n < 8; ++n) {
        const int col = colh * 128 + n * 16 + fr;
#pragma unroll
        for (int j = 0; j < 4; ++j) {
          const int r = blk0 + rowh * 64 + m * 16 + fq * 4 + j;
          if (r < M) {
            float v = acc[m][n][j];
            v = v >= 0.f ? v : v * SLOPE;
            Obf[(size_t)r * ldo + col] = f2b(v);
          }
        }
      }
  } else {
    float ss[4][4];
#pragma unroll
    for (int m = 0; m < 4; ++m)
#pragma unroll
      for (int j = 0; j < 4; ++j) ss[m][j] = 0.f;
#pragma unroll
    for (int m = 0; m < 4; ++m)
#pragma unroll
      for (int n = 0; n < 8; ++n)
#pragma unroll
        for (int j = 0; j < 4; ++j) {
          float v = acc[m][n][j];
          v = v >= 0.f ? v : v * SLOPE;
          acc[m][n][j] = v;
          ss[m][j] += v * v;
        }
#pragma unroll
    for (int m = 0; m < 4; ++m)
#pragma unroll
      for (int j = 0; j < 4; ++j) {
        float s = ss[m][j];
        s += __shfl_xor(s, 1, 64);
        s += __shfl_xor(s, 2, 64);
        s += __shfl_xor(s, 4, 64);
        s += __shfl_xor(s, 8, 64);
        ss[m][j] = s;                      // half-row (128-col) sum, all lanes
      }
    __syncthreads();                       // compute done; reuse Bs
    float* red = (float*)Bs;               // [0..255]: partials, [256..511]: inv
    if (colh == 0 && fr == 0) {
#pragma unroll
      for (int m = 0; m < 4; ++m)
#pragma unroll
        for (int j = 0; j < 4; ++j)
          red[rowh * 128 + m * 16 + fq * 4 + j] = ss[m][j];
    }
    __syncthreads();
    float inv[4][4];
    if (colh == 1) {
#pragma unroll
      for (int m = 0; m < 4; ++m)
#pragma unroll
        for (int j = 0; j < 4; ++j) {
          float tot = ss[m][j] + red[rowh * 128 + m * 16 + fq * 4 + j];
          inv[m][j] = 1.f / fmaxf(sqrtf(tot), 1e-12f);
        }
      if (fr == 0) {
#pragma unroll
        for (int m = 0; m < 4; ++m)
#pragma unroll
          for (int j = 0; j < 4; ++j)
            red[256 + rowh * 128 + m * 16 + fq * 4 + j] = inv[m][j];
      }
    }
    __syncthreads();
    if (colh == 0) {
#pragma unroll
      for (int m = 0; m < 4; ++m)
#pragma unroll
        for (int j = 0; j < 4; ++j)
          inv[m][j] = red[256 + rowh * 128 + m * 16 + fq * 4 + j];
    }
#pragma unroll
    for (int m = 0; m < 4; ++m)
#pragma unroll
      for (int n = 0; n < 8; ++n) {
        const int col = colh * 128 + n * 16 + fr;
#pragma unroll
        for (int j = 0; j < 4; ++j) {
          const int r = blk0 + rowh * 64 + m * 16 + fq * 4 + j;
          if (r < M) {
            float v = acc[m][n][j] * inv[m][j];
            Cf[(size_t)r * ldc + col] = v;
            Obf[(size_t)r * ldo + col] = f2b(v);
          }
        }
      }
  }
}

// ---------------- small GEMM (GRU): C = A * Bt^T (+Cadd)(+bias), f32 out ----------
__global__ __launch_bounds__(256)
void gemm_k(const short* __restrict__ A, int lda,
            const short* __restrict__ Bt, int ldb,
            int M, int K,
            float* __restrict__ Cf, int ldc,
            const float* __restrict__ Cadd,
            const float* __restrict__ bias)
{
  __shared__ short bt[256 * 72];
  const int tid = threadIdx.x;
  const int w = tid >> 6;
  const int lane = tid & 63;
  const int fr = lane & 15;
  const int fq = lane >> 4;
  const int col0 = blockIdx.y << 8;
  const int rowbase = blockIdx.x * 64 + w * 16;
  const int arow = min(rowbase + fr, M - 1);
  const long abase = (long)arow * lda + fq * 8;

  f32x4 acc[16];
#pragma unroll
  for (int i = 0; i < 16; ++i) { acc[i][0] = 0.f; acc[i][1] = 0.f; acc[i][2] = 0.f; acc[i][3] = 0.f; }

  for (int kc = 0; kc < K; kc += 64) {
    __syncthreads();
    {
      const short* g = Bt + (long)(col0 + tid) * ldb + kc;
      short* l = &bt[tid * 72];
#pragma unroll
      for (int i = 0; i < 8; ++i)
        *(short8*)(l + i * 8) = *(const short8*)(g + i * 8);
    }
    __syncthreads();
#pragma unroll
    for (int ks = 0; ks < 2; ++ks) {
      short8 a = *(const short8*)(A + abase + kc + ks * 32);
#pragma unroll
      for (int ct = 0; ct < 16; ++ct) {
        short8 b = *(const short8*)&bt[(ct * 16 + fr) * 72 + ks * 32 + fq * 8];
        acc[ct] = __builtin_amdgcn_mfma_f32_16x16x32_bf16(a, b, acc[ct], 0, 0, 0);
      }
    }
  }

  const int crow = rowbase + fq * 4;
#pragma unroll
  for (int ct = 0; ct < 16; ++ct) {
    const int gcol = col0 + ct * 16 + fr;
#pragma unroll
    for (int j = 0; j < 4; ++j) {
      const int r = crow + j;
      if (r < M) {
        float v = acc[ct][j];
        if (Cadd) v += Cadd[(long)r * ldc + gcol];
        if (bias) v += bias[gcol];
        Cf[(long)r * ldc + gcol] = v;
      }
    }
  }
}

// ---------------- init: h = l2norm(dynamic_emb) -> bf16 into Acat halfB ----------
__global__ __launch_bounds__(256)
void l2init_k(const float* __restrict__ de, short* __restrict__ hb)
{
  const int w = threadIdx.x >> 6, lane = threadIdx.x & 63;
  const int row = blockIdx.x * 4 + w;
  f32x4 v = *(const f32x4*)&de[(long)row * H + lane * 4];
  float s = v[0]*v[0] + v[1]*v[1] + v[2]*v[2] + v[3]*v[3];
  s += __shfl_xor(s, 1, 64);  s += __shfl_xor(s, 2, 64);
  s += __shfl_xor(s, 4, 64);  s += __shfl_xor(s, 8, 64);
  s += __shfl_xor(s, 16, 64); s += __shfl_xor(s, 32, 64);
  float sc = 1.f / fmaxf(sqrtf(s), 1e-12f);
  short4v o;
  o[0] = f2b(v[0]*sc); o[1] = f2b(v[1]*sc); o[2] = f2b(v[2]*sc); o[3] = f2b(v[3]*sc);
  *(short4v*)&hb[(long)row * 512 + lane * 4] = o;
}

// ---------------- weight prep ----------------------------------------------------
__global__ void castcopy_k(const float* __restrict__ in, short* __restrict__ out, long n)
{
  long i = (long)blockIdx.x * 256 + threadIdx.x;
  if (i < n) out[i] = f2b(in[i]);
}

__global__ void wcat_k(const float* __restrict__ wn, const float* __restrict__ lw,
                       short* __restrict__ wc)
{
  long i = (long)blockIdx.x * 256 + threadIdx.x;  // over NL*256*512, layout [l][j][k]
  if (i >= (long)NL * 256 * 512) return;
  int l = (int)(i / (256 * 512));
  int rem = (int)(i % (256 * 512));
  int j = rem / 512;
  int k = rem % 512;
  float v = (k < 256) ? wn[(long)l * 65536 + k * 256 + j]
                      : lw[(long)l * 65536 + (k - 256) * 256 + j];
  wc[i] = f2b(v);
}

__global__ void h0init_k(const float* __restrict__ er, float* __restrict__ h0,
                         short* __restrict__ h0b)
{
  long i = (long)blockIdx.x * 256 + threadIdx.x;
  if (i < (long)R2 * H) { float v = er[i]; h0[i] = v; h0b[i] = f2b(v); }
}

// ---------------- per-step zero of all counter buffers (replaces 5 memsets) ------
__global__ __launch_bounds__(256)
void zero_k(unsigned* __restrict__ deg, unsigned* __restrict__ curd,
            unsigned* __restrict__ cnt, unsigned* __restrict__ cur,
            unsigned* __restrict__ nz)
{
  int i = blockIdx.x * 256 + threadIdx.x;
  if (i < N_ENTS) { deg[i] = 0u; curd[i] = 0u; }
  if (i < R2) { cnt[i] = 0u; cur[i] = 0u; }
  if (i == 0) nz[0] = 0u;
}

// ---------------- r2e CSR build + segment mean -----------------------------------
__global__ __launch_bounds__(256)
void hist_k(const int* __restrict__ rel, unsigned* __restrict__ cnt, int m)
{
  __shared__ unsigned lh[R2];
  for (int i = threadIdx.x; i < R2; i += 256) lh[i] = 0;
  __syncthreads();
  for (long i = (long)blockIdx.x * 256 + threadIdx.x; i < m; i += (long)gridDim.x * 256)
    atomicAdd(&lh[rel[i]], 1u);
  __syncthreads();
  for (int i = threadIdx.x; i < R2; i += 256)
    if (lh[i]) atomicAdd(&cnt[i], lh[i]);
}

// parallel Hillis-Steele over 512 slots (2 elems/thread)
__global__ __launch_bounds__(256)
void prefix_k(const unsigned* __restrict__ cnt, unsigned* __restrict__ off)
{
  __shared__ unsigned s[512];
  const int t = threadIdx.x;
  s[t] = (t < R2) ? cnt[t] : 0u;
  s[t + 256] = (t + 256 < R2) ? cnt[t + 256] : 0u;
  __syncthreads();
#pragma unroll
  for (int d = 1; d < 512; d <<= 1) {
    unsigned v0 = (t >= d) ? s[t - d] : 0u;
    unsigned v1 = (t + 256 >= d) ? s[t + 256 - d] : 0u;
    __syncthreads();
    s[t] += v0; s[t + 256] += v1;
    __syncthreads();
  }
  if (t < R2) off[t] = (t == 0) ? 0u : s[t - 1];
  if (t + 256 < R2) off[t + 256] = s[t + 255];
  if (t == 0) off[R2] = s[R2 - 1];
}

__global__ __launch_bounds__(256)
void scatter_k(const int* __restrict__ rel, const int* __restrict__ ent,
               const unsigned* __restrict__ off, unsigned* __restrict__ cur,
               int* __restrict__ se, int m)
{
  for (long i = (long)blockIdx.x * 256 + threadIdx.x; i < m; i += (long)gridDim.x * 256) {
    int r = rel[i];
    unsigned p = atomicAdd(&cur[r], 1u);
    se[off[r] + p] = ent[i];
  }
}

__global__ __launch_bounds__(256)
void segmean_k(const unsigned* __restrict__ off, const int* __restrict__ se,
               const short* __restrict__ hb, short* __restrict__ x_inb)
{
  const int r = blockIdx.x;
  const int tid = threadIdx.x;
  const unsigned b = off[r], e2 = off[r + 1];
  float a0 = 0.f, a1 = 0.f, a2 = 0.f, a3 = 0.f;
  unsigned i = b;
  for (; i + 4 <= e2; i += 4) {
    int e0 = se[i], eA = se[i+1], eB = se[i+2], eC = se[i+3];
    a0 += b2f(hb[(long)e0 * 512 + tid]);
    a1 += b2f(hb[(long)eA * 512 + tid]);
    a2 += b2f(hb[(long)eB * 512 + tid]);
    a3 += b2f(hb[(long)eC * 512 + tid]);
  }
  for (; i < e2; ++i) a0 += b2f(hb[(long)se[i] * 512 + tid]);
  float acc = (a0 + a1) + (a2 + a3);
  float c = fmaxf((float)(e2 - b), 1.f);
  x_inb[(long)r * H + tid] = f2b(acc / c);
}

// ---------------- GRU gates ------------------------------------------------------
__global__ __launch_bounds__(256)
void gate_k(const float* __restrict__ gx, const float* __restrict__ gh,
            float* __restrict__ h0, short* __restrict__ h0b, float* __restrict__ relout)
{
  __shared__ float red[4];
  const int r = blockIdx.x, c = threadIdx.x;
  const long b = (long)r * 768;
  float xr = gx[b + c], xz = gx[b + 256 + c], xn = gx[b + 512 + c];
  float hr = gh[b + c], hz = gh[b + 256 + c], hn = gh[b + 512 + c];
  float rr = 1.f / (1.f + expf(-(xr + hr)));
  float z  = 1.f / (1.f + expf(-(xz + hz)));
  float nn = tanhf(xn + rr * hn);
  float v = (1.f - z) * nn + z * h0[(long)r * H + c];
  float s = v * v;
  s += __shfl_xor(s, 1, 64);  s += __shfl_xor(s, 2, 64);
  s += __shfl_xor(s, 4, 64);  s += __shfl_xor(s, 8, 64);
  s += __shfl_xor(s, 16, 64); s += __shfl_xor(s, 32, 64);
  const int w = c >> 6;
  if ((c & 63) == 0) red[w] = s;
  __syncthreads();
  float tot = (red[0] + red[1]) + (red[2] + red[3]);
  float sc = 1.f / fmaxf(sqrtf(tot), 1e-12f);
  v *= sc;
  h0[(long)r * H + c] = v;
  h0b[(long)r * H + c] = f2b(v);
  relout[(long)r * H + c] = v;
}

// ---------------- dst-degree count ------------------------------------------------
__global__ __launch_bounds__(256)
void deg_k(const int* __restrict__ dst, unsigned* __restrict__ deg, int e)
{
  for (long i = (long)blockIdx.x * 256 + threadIdx.x; i < e; i += (long)gridDim.x * 256)
    atomicAdd(&deg[dst[i]], 1u);
}

// ---------------- 3-phase exclusive scan over deg[N_ENTS] -> offd -----------------
__global__ __launch_bounds__(256)
void scan1_k(const unsigned* __restrict__ deg, unsigned* __restrict__ offd,
             unsigned* __restrict__ bsum)
{
  __shared__ unsigned s[256];
  const int tid = threadIdx.x;
  const int i = blockIdx.x * 256 + tid;
  unsigned v = (i < N_ENTS) ? deg[i] : 0u;
  s[tid] = v;
  __syncthreads();
#pragma unroll
  for (int d = 1; d < 256; d <<= 1) {
    unsigned t = (tid >= d) ? s[tid - d] : 0u;
    __syncthreads();
    s[tid] += t;
    __syncthreads();
  }
  if (i < N_ENTS) offd[i] = s[tid] - v;            // block-local exclusive
  if (tid == 255) bsum[blockIdx.x] = s[255];
}

__global__ __launch_bounds__(256)
void scan2_k(unsigned* __restrict__ bsum)
{
  __shared__ unsigned s[256];
  const int tid = threadIdx.x;
  unsigned v = (tid < SCAN_NB) ? bsum[tid] : 0u;
  s[tid] = v;
  __syncthreads();
#pragma unroll
  for (int d = 1; d < 256; d <<= 1) {
    unsigned t = (tid >= d) ? s[tid - d] : 0u;
    __syncthreads();
    s[tid] += t;
    __syncthreads();
  }
  if (tid < SCAN_NB) bsum[tid] = s[tid] - v;       // exclusive block offsets
}

__global__ __launch_bounds__(256)
void scan3_k(unsigned* __restrict__ offd, const unsigned* __restrict__ bsum,
             const unsigned* __restrict__ deg,
             unsigned* __restrict__ zl, unsigned* __restrict__ nz)
{
  const int i = blockIdx.x * 256 + threadIdx.x;
  if (i < N_ENTS) {
    offd[i] += bsum[blockIdx.x];
    if (deg[i] == 0u) { unsigned p = atomicAdd(nz, 1u); zl[p] = i; }
  }
  if (i == 0) offd[N_ENTS] = NE;
}

// ---------------- scatter (src,etype) into dst-CSR --------------------------------
__global__ __launch_bounds__(256)
void scatter2_k(const int* __restrict__ src, const int* __restrict__ dst,
                const int* __restrict__ et, const unsigned* __restrict__ offd,
                unsigned* __restrict__ cur, int2* __restrict__ se2, int e)
{
  for (long i = (long)blockIdx.x * 256 + threadIdx.x; i < e; i += (long)gridDim.x * 256) {
    int d = dst[i];
    unsigned p = atomicAdd(&cur[d], 1u);
    se2[offd[d] + p] = make_int2(src[i], et[i]);
  }
}

// ---------------- CSR segmented aggregation: ah[row] = bf16(norm * sum) ----------
__global__ __launch_bounds__(256)
void agg_k(const int2* __restrict__ se2, const unsigned* __restrict__ offd,
           const short* __restrict__ hb, const short* __restrict__ h0b,
           short* __restrict__ ah)
{
  const int w = threadIdx.x >> 6, lane = threadIdx.x & 63;
  const int row = blockIdx.x * 4 + w;
  const unsigned b = offd[row], e2 = offd[row + 1];
  float a0 = 0.f, a1 = 0.f, a2 = 0.f, a3 = 0.f;
  for (unsigned i = b; i < e2; ++i) {
    int2 p = se2[i];
    short4v hv = *(const short4v*)&hb[(long)p.x * 512 + lane * 4];
    short4v rv = *(const short4v*)&h0b[(long)p.y * H + lane * 4];
    a0 += b2f(hv[0]) + b2f(rv[0]);
    a1 += b2f(hv[1]) + b2f(rv[1]);
    a2 += b2f(hv[2]) + b2f(rv[2]);
    a3 += b2f(hv[3]) + b2f(rv[3]);
  }
  const float nm = 1.f / fmaxf((float)(e2 - b), 1.f);
  short4v o;
  o[0] = f2b(a0 * nm); o[1] = f2b(a1 * nm); o[2] = f2b(a2 * nm); o[3] = f2b(a3 * nm);
  *(short4v*)&ah[(long)row * 512 + lane * 4] = o;
}

// ---------------- deg==0 fixup: row = rrelu(hc @ evolve_w) (+l2norm if final) ----
template<int FINAL>
__global__ __launch_bounds__(256)
void fixup_k(const unsigned* __restrict__ nz, const unsigned* __restrict__ zl,
             const short* __restrict__ hbc, const short* __restrict__ evb,
             short* __restrict__ hbn, float* __restrict__ outF)
{
  __shared__ float x[H];
  __shared__ float red[4];
  const unsigned n = *nz;
  for (unsigned zi = blockIdx.x; zi < n; zi += gridDim.x) {
    const int row = zl[zi];
    __syncthreads();
    x[threadIdx.x] = b2f(hbc[(long)row * 512 + threadIdx.x]);
    __syncthreads();
    float acc = 0.f;
#pragma unroll 4
    for (int k = 0; k < H; ++k) acc += x[k] * b2f(evb[k * H + threadIdx.x]);
    float v = acc >= 0.f ? acc : acc * SLOPE;
    if (FINAL) {
      float s = v * v;
      s += __shfl_xor(s, 1, 64);  s += __shfl_xor(s, 2, 64);
      s += __shfl_xor(s, 4, 64);  s += __shfl_xor(s, 8, 64);
      s += __shfl_xor(s, 16, 64); s += __shfl_xor(s, 32, 64);
      const int w = threadIdx.x >> 6;
      if ((threadIdx.x & 63) == 0) red[w] = s;
      __syncthreads();
      float tot = (red[0] + red[1]) + (red[2] + red[3]);
      float sc = 1.f / fmaxf(sqrtf(tot), 1e-12f);
      v *= sc;
      outF[(long)row * H + threadIdx.x] = v;
    }
    hbn[(long)row * 512 + threadIdx.x] = f2b(v);
  }
}

// =================================================================================
extern "C" void kernel_launch(void* const* d_in, const int* in_sizes, int n_in,
                              void* d_out, int out_size, void* d_ws, size_t ws_size,
                              hipStream_t stream)
{
  (void)in_sizes; (void)n_in; (void)out_size; (void)ws_size;
  const int* src = (const int*)d_in[0];
  const int* dst = (const int*)d_in[1];
  const int* ety = (const int*)d_in[2];
  const int* r2e_ent = (const int*)d_in[3];
  const int* r2e_rel = (const int*)d_in[4];
  const float* dyn = (const float*)d_in[5];
  const float* erel = (const float*)d_in[6];
  const float* wn = (const float*)d_in[7];
  const float* lw = (const float*)d_in[8];
  const float* ew = (const float*)d_in[9];
  const float* wih = (const float*)d_in[10];
  const float* whh = (const float*)d_in[11];
  const float* bih = (const float*)d_in[12];
  const float* bhh = (const float*)d_in[13];

  float* out = (float*)d_out;
  float* hist = out;
  float* rels = out + (long)TSTEPS * N_ENTS * H;

  char* p = (char*)d_ws;
  auto alloc = [&](size_t n) { char* r = p; p += (n + 255) & ~(size_t)255; return r; };
  short*    AcatA  = (short*)alloc((size_t)N_ENTS * 512 * 2);
  short*    AcatB  = (short*)alloc((size_t)N_ENTS * 512 * 2);
  unsigned* deg    = (unsigned*)alloc((size_t)N_ENTS * 4);
  unsigned* offd   = (unsigned*)alloc((size_t)(N_ENTS + 1) * 4);
  unsigned* curd   = (unsigned*)alloc((size_t)N_ENTS * 4);
  unsigned* bsum   = (unsigned*)alloc((size_t)SCAN_NB * 4);
  int2*     se2    = (int2*)alloc((size_t)NE * 8);
  unsigned* zl     = (unsigned*)alloc((size_t)N_ENTS * 4);
  unsigned* nz     = (unsigned*)alloc(256);
  unsigned* cnt    = (unsigned*)alloc(R2 * 4);
  unsigned* off    = (unsigned*)alloc((R2 + 1) * 4);
  unsigned* cur    = (unsigned*)alloc(R2 * 4);
  int*      se     = (int*)alloc((size_t)NM * 4);
  short*    x_inb  = (short*)alloc((size_t)R2 * H * 2);
  float*    gxbase = (float*)alloc((size_t)R2 * 768 * 4);
  float*    gx     = (float*)alloc((size_t)R2 * 768 * 4);
  float*    gh     = (float*)alloc((size_t)R2 * 768 * 4);
  float*    h0     = (float*)alloc((size_t)R2 * H * 4);
  short*    h0b    = (short*)alloc((size_t)R2 * H * 2);
  short*    erelb  = (short*)alloc((size_t)R2 * H * 2);
  short*    wcatb  = (short*)alloc((size_t)NL * 256 * 512 * 2);
  short*    evb    = (short*)alloc((size_t)NL * H * H * 2);
  short*    wihb   = (short*)alloc((size_t)768 * 512 * 2);
  short*    whhb   = (short*)alloc((size_t)768 * 256 * 2);

  wcat_k<<<(NL * 256 * 512 + 255) / 256, 256, 0, stream>>>(wn, lw, wcatb);
  castcopy_k<<<(NL * H * H + 255) / 256, 256, 0, stream>>>(ew, evb, (long)NL * H * H);
  castcopy_k<<<(768 * 512 + 255) / 256, 256, 0, stream>>>(wih, wihb, 768 * 512);
  castcopy_k<<<(768 * 256 + 255) / 256, 256, 0, stream>>>(whh, whhb, 768 * 256);
  castcopy_k<<<(R2 * H + 255) / 256, 256, 0, stream>>>(erel, erelb, (long)R2 * H);
  h0init_k<<<(R2 * H + 255) / 256, 256, 0, stream>>>(erel, h0, h0b);
  l2init_k<<<N_ENTS / 4, 256, 0, stream>>>(dyn, AcatA + 256);

  // gx_base = emb_rel @ W_ih[:, :256]^T + b_ih   (step-invariant)
  gemm_k<<<dim3(8, 3), 256, 0, stream>>>(erelb, 256, wihb, 512, R2, 256,
                                         gxbase, 768, nullptr, bih);

  short* Acur = AcatA;
  short* Anxt = AcatB;

  for (int t = 0; t < TSTEPS; ++t) {
    const int* src_t = src + (long)t * NE;
    const int* dst_t = dst + (long)t * NE;
    const int* ety_t = ety + (long)t * NE;
    const int* re_t  = r2e_ent + (long)t * NM;
    const int* rr_t  = r2e_rel + (long)t * NM;
    float* hist_t = hist + (long)t * N_ENTS * H;
    float* rels_t = rels + (long)t * R2 * H;

    zero_k<<<SCAN_NB, 256, 0, stream>>>(deg, curd, cnt, cur, nz);

    // relation mean via CSR
    hist_k<<<256, 256, 0, stream>>>(rr_t, cnt, NM);
    prefix_k<<<1, 256, 0, stream>>>(cnt, off);
    scatter_k<<<256, 256, 0, stream>>>(rr_t, re_t, off, cur, se, NM);
    segmean_k<<<R2, 256, 0, stream>>>(off, se, Acur + 256, x_inb);

    // GRU
    gemm_k<<<dim3(8, 3), 256, 0, stream>>>(x_inb, 256, wihb + 256, 512, R2, 256,
                                           gx, 768, gxbase, nullptr);
    gemm_k<<<dim3(8, 3), 256, 0, stream>>>(h0b, 256, whhb, 256, R2, 256,
                                           gh, 768, nullptr, bhh);
    gate_k<<<R2, 256, 0, stream>>>(gx, gh, h0, h0b, rels_t);

    // dst-CSR build: degree -> scan -> scatter; zero-list fused into scan add-back
    deg_k<<<512, 256, 0, stream>>>(dst_t, deg, NE);
    scan1_k<<<SCAN_NB, 256, 0, stream>>>(deg, offd, bsum);
    scan2_k<<<1, 256, 0, stream>>>(bsum);
    scan3_k<<<SCAN_NB, 256, 0, stream>>>(offd, bsum, deg, zl, nz);
    scatter2_k<<<512, 256, 0, stream>>>(src_t, dst_t, ety_t, offd, curd, se2, NE);

    for (int l = 0; l < NL; ++l) {
      agg_k<<<N_ENTS / 4, 256, 0, stream>>>(se2, offd, Acur + 256, h0b, Acur);
      if (l == NL - 1) {
        gemm_big<2><<<391, 256, 0, stream>>>(Acur, 512, wcatb + (long)l * 256 * 512, 512,
                                             N_ENTS, 512, hist_t, 256, Anxt + 256, 512);
        fixup_k<1><<<512, 256, 0, stream>>>(nz, zl, Acur + 256, evb + (long)l * H * H,
                                            Anxt + 256, hist_t);
      } else {
        gemm_big<1><<<391, 256, 0, stream>>>(Acur, 512, wcatb + (long)l * 256 * 512, 512,
                                             N_ENTS, 512, nullptr, 0, Anxt + 256, 512);
        fixup_k<0><<<512, 256, 0, stream>>>(nz, zl, Acur + 256, evb + (long)l * H * H,
                                            Anxt + 256, nullptr);
      }
      short* tmp = Acur; Acur = Anxt; Anxt = tmp;
    }
  }
}

// Round 4
// 1319.271 us; speedup vs baseline: 5.4083x; 1.2452x over previous
//
#include <hip/hip_runtime.h>

#define N_ENTS 50000
#define R2 500
#define H 256
#define TSTEPS 4
#define NE 200000
#define NM 200000
#define NL 2
#define SLOPE 0.22916666666666666f
#define SCAN_NB ((N_ENTS + 255) / 256)   // 196

typedef __attribute__((ext_vector_type(8))) short short8;
typedef __attribute__((ext_vector_type(4))) short short4v;
typedef __attribute__((ext_vector_type(4))) float f32x4;

static __device__ __forceinline__ float b2f(short s) {
  unsigned u = ((unsigned)(unsigned short)s) << 16;
  return __builtin_bit_cast(float, u);
}
static __device__ __forceinline__ short f2b(float f) {
  unsigned u = __builtin_bit_cast(unsigned, f);
  u = (u + 0x7FFFu + ((u >> 16) & 1u)) >> 16;
  return (short)(unsigned short)u;
}

static __device__ __forceinline__ void gload16(const short* g, short* l) {
  __builtin_amdgcn_global_load_lds(
      (const __attribute__((address_space(1))) void*)g,
      (__attribute__((address_space(3))) void*)l, 16, 0, 0);
}

// ---------------- big GEMM: C[M x 256] = A[M x K](bf16) * Bt[256 x K](bf16)^T ----
// 128x256 block, BK=64, 4 waves x (64 rows x 128 cols), global_load_lds staging
// with XOR slot-swizzle (slot ^= row&7) on both source and read sides.
// EPI 1: Obf = bf16(rrelu(acc))                      (ldo)
// EPI 2: l2norm(rrelu(acc)) -> Cf (f32, ldc) and Obf (bf16, ldo)
template<int EPI>
__global__ __launch_bounds__(256, 2)
void gemm_big(const short* __restrict__ A, int lda,
              const short* __restrict__ Bt, int ldb,
              int M, int K,
              float* __restrict__ Cf, int ldc,
              short* __restrict__ Obf, int ldo)
{
  __shared__ short As[128 * 64];
  __shared__ short Bs[256 * 64];
  const int tid = threadIdx.x;
  const int w = tid >> 6, lane = tid & 63;
  const int fr = lane & 15, fq = lane >> 4;
  const int rowh = w >> 1, colh = w & 1;
  const int blk0 = blockIdx.x * 128;
  const int l8 = lane >> 3, s7 = lane & 7;

  f32x4 acc[4][8];
#pragma unroll
  for (int m = 0; m < 4; ++m)
#pragma unroll
    for (int n = 0; n < 8; ++n) {
      acc[m][n][0] = 0.f; acc[m][n][1] = 0.f; acc[m][n][2] = 0.f; acc[m][n][3] = 0.f;
    }

  for (int kc = 0; kc < K; kc += 64) {
    __syncthreads();
#pragma unroll
    for (int i = 0; i < 4; ++i) {          // A tile: 128 rows x 64 k
      int row = w * 32 + i * 8 + l8;
      int grow = min(blk0 + row, M - 1);
      const short* g = A + (size_t)grow * lda + kc + ((s7 ^ (row & 7)) << 3);
      gload16(g, As + w * 2048 + i * 512);
    }
#pragma unroll
    for (int i = 0; i < 8; ++i) {          // B tile: 256 cols x 64 k
      int row = w * 64 + i * 8 + l8;
      const short* g = Bt + (size_t)row * ldb + kc + ((s7 ^ (row & 7)) << 3);
      gload16(g, Bs + w * 4096 + i * 512);
    }
    __syncthreads();
#pragma unroll
    for (int ks = 0; ks < 2; ++ks) {
      const int sl = ((((ks << 2) | fq) ^ s7) << 3);
      short8 a[4], b[8];
#pragma unroll
      for (int m = 0; m < 4; ++m)
        a[m] = *(const short8*)&As[(rowh * 64 + m * 16 + fr) * 64 + sl];
#pragma unroll
      for (int n = 0; n < 8; ++n)
        b[n] = *(const short8*)&Bs[(colh * 128 + n * 16 + fr) * 64 + sl];
#pragma unroll
      for (int m = 0; m < 4; ++m)
#pragma unroll
        for (int n = 0; n < 8; ++n)
          acc[m][n] = __builtin_amdgcn_mfma_f32_16x16x32_bf16(a[m], b[n], acc[m][n], 0, 0, 0);
    }
  }

  if (EPI == 1) {
#pragma unroll
    for (int m = 0; m < 4; ++m)
#pragma unroll
      for (int n = 0; n < 8; ++n) {
        const int col = colh * 128 + n * 16 + fr;
#pragma unroll
        for (int j = 0; j < 4; ++j) {
          const int r = blk0 + rowh * 64 + m * 16 + fq * 4 + j;
          if (r < M) {
            float v = acc[m][n][j];
            v = v >= 0.f ? v : v * SLOPE;
            Obf[(size_t)r * ldo + col] = f2b(v);
          }
        }
      }
  } else {
    float ss[4][4];
#pragma unroll
    for (int m = 0; m < 4; ++m)
#pragma unroll
      for (int j = 0; j < 4; ++j) ss[m][j] = 0.f;
#pragma unroll
    for (int m = 0; m < 4; ++m)
#pragma unroll
      for (int n = 0; n < 8; ++n)
#pragma unroll
        for (int j = 0; j < 4; ++j) {
          float v = acc[m][n][j];
          v = v >= 0.f ? v : v * SLOPE;
          acc[m][n][j] = v;
          ss[m][j] += v * v;
        }
#pragma unroll
    for (int m = 0; m < 4; ++m)
#pragma unroll
      for (int j = 0; j < 4; ++j) {
        float s = ss[m][j];
        s += __shfl_xor(s, 1, 64);
        s += __shfl_xor(s, 2, 64);
        s += __shfl_xor(s, 4, 64);
        s += __shfl_xor(s, 8, 64);
        ss[m][j] = s;                      // half-row (128-col) sum, all lanes
      }
    __syncthreads();                       // compute done; reuse Bs
    float* red = (float*)Bs;               // [0..255]: partials, [256..511]: inv
    if (colh == 0 && fr == 0) {
#pragma unroll
      for (int m = 0; m < 4; ++m)
#pragma unroll
        for (int j = 0; j < 4; ++j)
          red[rowh * 128 + m * 16 + fq * 4 + j] = ss[m][j];
    }
    __syncthreads();
    float inv[4][4];
    if (colh == 1) {
#pragma unroll
      for (int m = 0; m < 4; ++m)
#pragma unroll
        for (int j = 0; j < 4; ++j) {
          float tot = ss[m][j] + red[rowh * 128 + m * 16 + fq * 4 + j];
          inv[m][j] = 1.f / fmaxf(sqrtf(tot), 1e-12f);
        }
      if (fr == 0) {
#pragma unroll
        for (int m = 0; m < 4; ++m)
#pragma unroll
          for (int j = 0; j < 4; ++j)
            red[256 + rowh * 128 + m * 16 + fq * 4 + j] = inv[m][j];
      }
    }
    __syncthreads();
    if (colh == 0) {
#pragma unroll
      for (int m = 0; m < 4; ++m)
#pragma unroll
        for (int j = 0; j < 4; ++j)
          inv[m][j] = red[256 + rowh * 128 + m * 16 + fq * 4 + j];
    }
#pragma unroll
    for (int m = 0; m < 4; ++m)
#pragma unroll
      for (int n = 0; n < 8; ++n) {
        const int col = colh * 128 + n * 16 + fr;
#pragma unroll
        for (int j = 0; j < 4; ++j) {
          const int r = blk0 + rowh * 64 + m * 16 + fq * 4 + j;
          if (r < M) {
            float v = acc[m][n][j] * inv[m][j];
            Cf[(size_t)r * ldc + col] = v;
            Obf[(size_t)r * ldo + col] = f2b(v);
          }
        }
      }
  }
}

// ---------------- small GEMM (init only): C = A * Bt^T (+bias), f32 out ----------
__global__ __launch_bounds__(256)
void gemm_k(const short* __restrict__ A, int lda,
            const short* __restrict__ Bt, int ldb,
            int M, int K,
            float* __restrict__ Cf, int ldc,
            const float* __restrict__ bias)
{
  __shared__ short bt[256 * 72];
  const int tid = threadIdx.x;
  const int w = tid >> 6;
  const int lane = tid & 63;
  const int fr = lane & 15;
  const int fq = lane >> 4;
  const int col0 = blockIdx.y << 8;
  const int rowbase = blockIdx.x * 64 + w * 16;
  const int arow = min(rowbase + fr, M - 1);
  const long abase = (long)arow * lda + fq * 8;

  f32x4 acc[16];
#pragma unroll
  for (int i = 0; i < 16; ++i) { acc[i][0] = 0.f; acc[i][1] = 0.f; acc[i][2] = 0.f; acc[i][3] = 0.f; }

  for (int kc = 0; kc < K; kc += 64) {
    __syncthreads();
    {
      const short* g = Bt + (long)(col0 + tid) * ldb + kc;
      short* l = &bt[tid * 72];
#pragma unroll
      for (int i = 0; i < 8; ++i)
        *(short8*)(l + i * 8) = *(const short8*)(g + i * 8);
    }
    __syncthreads();
#pragma unroll
    for (int ks = 0; ks < 2; ++ks) {
      short8 a = *(const short8*)(A + abase + kc + ks * 32);
#pragma unroll
      for (int ct = 0; ct < 16; ++ct) {
        short8 b = *(const short8*)&bt[(ct * 16 + fr) * 72 + ks * 32 + fq * 8];
        acc[ct] = __builtin_amdgcn_mfma_f32_16x16x32_bf16(a, b, acc[ct], 0, 0, 0);
      }
    }
  }

  const int crow = rowbase + fq * 4;
#pragma unroll
  for (int ct = 0; ct < 16; ++ct) {
    const int gcol = col0 + ct * 16 + fr;
#pragma unroll
    for (int j = 0; j < 4; ++j) {
      const int r = crow + j;
      if (r < M) {
        float v = acc[ct][j];
        if (bias) v += bias[gcol];
        Cf[(long)r * ldc + gcol] = v;
      }
    }
  }
}

// ---------------- fused GRU GEMMs: z=0 -> gx, z=1 -> gh ---------------------------
__global__ __launch_bounds__(256)
void gru2_k(const short* __restrict__ x_inb, const short* __restrict__ h0b,
            const short* __restrict__ wihb, const short* __restrict__ whhb,
            const float* __restrict__ gxbase, const float* __restrict__ bhh,
            float* __restrict__ gx, float* __restrict__ gh)
{
  const short* A;  const short* Bt;  int ldb;
  float* Cf;  const float* Cadd;  const float* bias;
  if (blockIdx.z == 0) { A = x_inb; Bt = wihb + 256; ldb = 512; Cf = gx; Cadd = gxbase; bias = nullptr; }
  else                 { A = h0b;   Bt = whhb;       ldb = 256; Cf = gh; Cadd = nullptr; bias = bhh; }

  __shared__ short bt[256 * 72];
  const int tid = threadIdx.x;
  const int w = tid >> 6;
  const int lane = tid & 63;
  const int fr = lane & 15;
  const int fq = lane >> 4;
  const int col0 = blockIdx.y << 8;
  const int rowbase = blockIdx.x * 64 + w * 16;
  const int arow = min(rowbase + fr, R2 - 1);
  const long abase = (long)arow * 256 + fq * 8;

  f32x4 acc[16];
#pragma unroll
  for (int i = 0; i < 16; ++i) { acc[i][0] = 0.f; acc[i][1] = 0.f; acc[i][2] = 0.f; acc[i][3] = 0.f; }

  for (int kc = 0; kc < 256; kc += 64) {
    __syncthreads();
    {
      const short* g = Bt + (long)(col0 + tid) * ldb + kc;
      short* l = &bt[tid * 72];
#pragma unroll
      for (int i = 0; i < 8; ++i)
        *(short8*)(l + i * 8) = *(const short8*)(g + i * 8);
    }
    __syncthreads();
#pragma unroll
    for (int ks = 0; ks < 2; ++ks) {
      short8 a = *(const short8*)(A + abase + kc + ks * 32);
#pragma unroll
      for (int ct = 0; ct < 16; ++ct) {
        short8 b = *(const short8*)&bt[(ct * 16 + fr) * 72 + ks * 32 + fq * 8];
        acc[ct] = __builtin_amdgcn_mfma_f32_16x16x32_bf16(a, b, acc[ct], 0, 0, 0);
      }
    }
  }

  const int crow = rowbase + fq * 4;
#pragma unroll
  for (int ct = 0; ct < 16; ++ct) {
    const int gcol = col0 + ct * 16 + fr;
#pragma unroll
    for (int j = 0; j < 4; ++j) {
      const int r = crow + j;
      if (r < R2) {
        float v = acc[ct][j];
        if (Cadd) v += Cadd[(long)r * 768 + gcol];
        if (bias) v += bias[gcol];
        Cf[(long)r * 768 + gcol] = v;
      }
    }
  }
}

// ---------------- init: h = l2norm(dynamic_emb) -> bf16 into Acat halfB ----------
__global__ __launch_bounds__(256)
void l2init_k(const float* __restrict__ de, short* __restrict__ hb)
{
  const int w = threadIdx.x >> 6, lane = threadIdx.x & 63;
  const int row = blockIdx.x * 4 + w;
  f32x4 v = *(const f32x4*)&de[(long)row * H + lane * 4];
  float s = v[0]*v[0] + v[1]*v[1] + v[2]*v[2] + v[3]*v[3];
  s += __shfl_xor(s, 1, 64);  s += __shfl_xor(s, 2, 64);
  s += __shfl_xor(s, 4, 64);  s += __shfl_xor(s, 8, 64);
  s += __shfl_xor(s, 16, 64); s += __shfl_xor(s, 32, 64);
  float sc = 1.f / fmaxf(sqrtf(s), 1e-12f);
  short4v o;
  o[0] = f2b(v[0]*sc); o[1] = f2b(v[1]*sc); o[2] = f2b(v[2]*sc); o[3] = f2b(v[3]*sc);
  *(short4v*)&hb[(long)row * 512 + lane * 4] = o;
}

// ---------------- weight prep ----------------------------------------------------
__global__ void castcopy_k(const float* __restrict__ in, short* __restrict__ out, long n)
{
  long i = (long)blockIdx.x * 256 + threadIdx.x;
  if (i < n) out[i] = f2b(in[i]);
}

__global__ void wcat_k(const float* __restrict__ wn, const float* __restrict__ lw,
                       short* __restrict__ wc)
{
  long i = (long)blockIdx.x * 256 + threadIdx.x;  // over NL*256*512, layout [l][j][k]
  if (i >= (long)NL * 256 * 512) return;
  int l = (int)(i / (256 * 512));
  int rem = (int)(i % (256 * 512));
  int j = rem / 512;
  int k = rem % 512;
  float v = (k < 256) ? wn[(long)l * 65536 + k * 256 + j]
                      : lw[(long)l * 65536 + (k - 256) * 256 + j];
  wc[i] = f2b(v);
}

// transpose evolve_w: evt[l][c][k] = ew[l][k][c]
__global__ void wtr_k(const float* __restrict__ ew, short* __restrict__ evt)
{
  long i = (long)blockIdx.x * 256 + threadIdx.x;
  if (i >= (long)NL * 65536) return;
  int l = (int)(i >> 16);
  int rem = (int)(i & 65535);
  int c = rem >> 8, k = rem & 255;
  evt[i] = f2b(ew[(long)l * 65536 + k * 256 + c]);
}

__global__ void h0init_k(const float* __restrict__ er, float* __restrict__ h0,
                         short* __restrict__ h0b)
{
  long i = (long)blockIdx.x * 256 + threadIdx.x;
  if (i < (long)R2 * H) { float v = er[i]; h0[i] = v; h0b[i] = f2b(v); }
}

// ---------------- per-step zero of counter buffers --------------------------------
__global__ __launch_bounds__(256)
void zero_k(unsigned* __restrict__ deg, unsigned* __restrict__ curd,
            unsigned* __restrict__ cnt, unsigned* __restrict__ cur,
            unsigned* __restrict__ nz)
{
  int i = blockIdx.x * 256 + threadIdx.x;
  if (i < N_ENTS) { deg[i] = 0u; curd[i] = 0u; }
  if (i < R2) { cnt[i] = 0u; cur[i] = 0u; }
  if (i == 0) nz[0] = 0u;
}

// ---------------- fused counting: rel histogram (LDS) + dst degree (global) ------
__global__ __launch_bounds__(256)
void count_k(const int* __restrict__ rel, const int* __restrict__ dstv,
             unsigned* __restrict__ cnt, unsigned* __restrict__ deg)
{
  __shared__ unsigned lh[R2];
  for (int i = threadIdx.x; i < R2; i += 256) lh[i] = 0;
  __syncthreads();
  for (long i = (long)blockIdx.x * 256 + threadIdx.x; i < NM; i += (long)gridDim.x * 256)
    atomicAdd(&lh[rel[i]], 1u);
  for (long i = (long)blockIdx.x * 256 + threadIdx.x; i < NE; i += (long)gridDim.x * 256)
    atomicAdd(&deg[dstv[i]], 1u);
  __syncthreads();
  for (int i = threadIdx.x; i < R2; i += 256)
    if (lh[i]) atomicAdd(&cnt[i], lh[i]);
}

// parallel Hillis-Steele over 512 slots (2 elems/thread)
__global__ __launch_bounds__(256)
void prefix_k(const unsigned* __restrict__ cnt, unsigned* __restrict__ off)
{
  __shared__ unsigned s[512];
  const int t = threadIdx.x;
  s[t] = (t < R2) ? cnt[t] : 0u;
  s[t + 256] = (t + 256 < R2) ? cnt[t + 256] : 0u;
  __syncthreads();
#pragma unroll
  for (int d = 1; d < 512; d <<= 1) {
    unsigned v0 = (t >= d) ? s[t - d] : 0u;
    unsigned v1 = (t + 256 >= d) ? s[t + 256 - d] : 0u;
    __syncthreads();
    s[t] += v0; s[t + 256] += v1;
    __syncthreads();
  }
  if (t < R2) off[t] = (t == 0) ? 0u : s[t - 1];
  if (t + 256 < R2) off[t + 256] = s[t + 255];
  if (t == 0) off[R2] = s[R2 - 1];
}

// ---------------- 3-phase exclusive scan over deg[N_ENTS] -> offd -----------------
__global__ __launch_bounds__(256)
void scan1_k(const unsigned* __restrict__ deg, unsigned* __restrict__ offd,
             unsigned* __restrict__ bsum)
{
  __shared__ unsigned s[256];
  const int tid = threadIdx.x;
  const int i = blockIdx.x * 256 + tid;
  unsigned v = (i < N_ENTS) ? deg[i] : 0u;
  s[tid] = v;
  __syncthreads();
#pragma unroll
  for (int d = 1; d < 256; d <<= 1) {
    unsigned t = (tid >= d) ? s[tid - d] : 0u;
    __syncthreads();
    s[tid] += t;
    __syncthreads();
  }
  if (i < N_ENTS) offd[i] = s[tid] - v;            // block-local exclusive
  if (tid == 255) bsum[blockIdx.x] = s[255];
}

__global__ __launch_bounds__(256)
void scan2_k(unsigned* __restrict__ bsum)
{
  __shared__ unsigned s[256];
  const int tid = threadIdx.x;
  unsigned v = (tid < SCAN_NB) ? bsum[tid] : 0u;
  s[tid] = v;
  __syncthreads();
#pragma unroll
  for (int d = 1; d < 256; d <<= 1) {
    unsigned t = (tid >= d) ? s[tid - d] : 0u;
    __syncthreads();
    s[tid] += t;
    __syncthreads();
  }
  if (tid < SCAN_NB) bsum[tid] = s[tid] - v;       // exclusive block offsets
}

__global__ __launch_bounds__(256)
void scan3_k(unsigned* __restrict__ offd, const unsigned* __restrict__ bsum,
             const unsigned* __restrict__ deg,
             unsigned* __restrict__ zl, unsigned* __restrict__ nz)
{
  const int i = blockIdx.x * 256 + threadIdx.x;
  if (i < N_ENTS) {
    offd[i] += bsum[blockIdx.x];
    if (deg[i] == 0u) { unsigned p = atomicAdd(nz, 1u); zl[p] = i; }
  }
  if (i == 0) offd[N_ENTS] = NE;
}

// ---------------- fused scatter: rel-CSR (ent) + dst-CSR (src,etype) --------------
__global__ __launch_bounds__(256)
void scatterB_k(const int* __restrict__ rel, const int* __restrict__ ent,
                const unsigned* __restrict__ off, unsigned* __restrict__ cur,
                int* __restrict__ se,
                const int* __restrict__ srcv, const int* __restrict__ dstv,
                const int* __restrict__ etv, const unsigned* __restrict__ offd,
                unsigned* __restrict__ curd,
                int* __restrict__ seS, int* __restrict__ seT)
{
  if (blockIdx.x < 256) {
    for (long i = (long)blockIdx.x * 256 + threadIdx.x; i < NM; i += 256l * 256) {
      int r = rel[i];
      unsigned p = atomicAdd(&cur[r], 1u);
      se[off[r] + p] = ent[i];
    }
  } else {
    for (long i = (long)(blockIdx.x - 256) * 256 + threadIdx.x; i < NE; i += 512l * 256) {
      int d = dstv[i];
      unsigned p = atomicAdd(&curd[d], 1u);
      unsigned q = offd[d] + p;
      seS[q] = srcv[i];
      seT[q] = etv[i];
    }
  }
}

// ---------------- segment-mean, split x4: partials then finalize ------------------
__global__ __launch_bounds__(256)
void segpart_k(const unsigned* __restrict__ off, const int* __restrict__ se,
               const short* __restrict__ hb, float* __restrict__ xinf)
{
  const int r = blockIdx.x >> 2, s = blockIdx.x & 3;
  const int tid = threadIdx.x;
  const unsigned b = off[r], e = off[r + 1], len = e - b;
  const unsigned lo = b + ((len * s) >> 2), hi = b + ((len * (s + 1)) >> 2);
  float a0 = 0.f, a1 = 0.f, a2 = 0.f, a3 = 0.f;
  unsigned i = lo;
  for (; i + 4 <= hi; i += 4) {
    a0 += b2f(hb[(long)se[i]     * 512 + tid]);
    a1 += b2f(hb[(long)se[i + 1] * 512 + tid]);
    a2 += b2f(hb[(long)se[i + 2] * 512 + tid]);
    a3 += b2f(hb[(long)se[i + 3] * 512 + tid]);
  }
  for (; i < hi; ++i) a0 += b2f(hb[(long)se[i] * 512 + tid]);
  xinf[((long)s * R2 + r) * 256 + tid] = (a0 + a1) + (a2 + a3);
}

__global__ __launch_bounds__(256)
void segfin_k(const float* __restrict__ xinf, const unsigned* __restrict__ cnt,
              short* __restrict__ x_inb)
{
  const int r = blockIdx.x, tid = threadIdx.x;
  float v = xinf[(long)r * 256 + tid] + xinf[((long)R2 + r) * 256 + tid]
          + xinf[((long)2 * R2 + r) * 256 + tid] + xinf[((long)3 * R2 + r) * 256 + tid];
  v /= fmaxf((float)cnt[r], 1.f);
  x_inb[(long)r * 256 + tid] = f2b(v);
}

// ---------------- GRU gates ------------------------------------------------------
__global__ __launch_bounds__(256)
void gate_k(const float* __restrict__ gx, const float* __restrict__ gh,
            float* __restrict__ h0, short* __restrict__ h0b, float* __restrict__ relout)
{
  __shared__ float red[4];
  const int r = blockIdx.x, c = threadIdx.x;
  const long b = (long)r * 768;
  float xr = gx[b + c], xz = gx[b + 256 + c], xn = gx[b + 512 + c];
  float hr = gh[b + c], hz = gh[b + 256 + c], hn = gh[b + 512 + c];
  float rr = 1.f / (1.f + expf(-(xr + hr)));
  float z  = 1.f / (1.f + expf(-(xz + hz)));
  float nn = tanhf(xn + rr * hn);
  float v = (1.f - z) * nn + z * h0[(long)r * H + c];
  float s = v * v;
  s += __shfl_xor(s, 1, 64);  s += __shfl_xor(s, 2, 64);
  s += __shfl_xor(s, 4, 64);  s += __shfl_xor(s, 8, 64);
  s += __shfl_xor(s, 16, 64); s += __shfl_xor(s, 32, 64);
  const int w = c >> 6;
  if ((c & 63) == 0) red[w] = s;
  __syncthreads();
  float tot = (red[0] + red[1]) + (red[2] + red[3]);
  float sc = 1.f / fmaxf(sqrtf(tot), 1e-12f);
  v *= sc;
  h0[(long)r * H + c] = v;
  h0b[(long)r * H + c] = f2b(v);
  relout[(long)r * H + c] = v;
}

// ---------------- layer-0 aggregation: also emits rsum[dst] = sum h0b[etype] ------
__global__ __launch_bounds__(256)
void agg_first_k(const int* __restrict__ seS, const int* __restrict__ seT,
                 const unsigned* __restrict__ offd,
                 const short* __restrict__ hb, const short* __restrict__ h0b,
                 short* __restrict__ rsum, short* __restrict__ acat)
{
  const int w = threadIdx.x >> 6, lane = threadIdx.x & 63;
  const int row = blockIdx.x * 4 + w;
  const unsigned b = offd[row], e2 = offd[row + 1];
  float h0_ = 0.f, h1_ = 0.f, h2_ = 0.f, h3_ = 0.f;
  float r0_ = 0.f, r1_ = 0.f, r2_ = 0.f, r3_ = 0.f;
  unsigned i = b;
  for (; i + 2 <= e2; i += 2) {
    int s0 = seS[i], s1 = seS[i + 1], t0 = seT[i], t1 = seT[i + 1];
    short4v ha = *(const short4v*)&hb[(long)s0 * 512 + lane * 4];
    short4v hc = *(const short4v*)&hb[(long)s1 * 512 + lane * 4];
    short4v ra = *(const short4v*)&h0b[(long)t0 * 256 + lane * 4];
    short4v rc = *(const short4v*)&h0b[(long)t1 * 256 + lane * 4];
    h0_ += b2f(ha[0]) + b2f(hc[0]);  h1_ += b2f(ha[1]) + b2f(hc[1]);
    h2_ += b2f(ha[2]) + b2f(hc[2]);  h3_ += b2f(ha[3]) + b2f(hc[3]);
    r0_ += b2f(ra[0]) + b2f(rc[0]);  r1_ += b2f(ra[1]) + b2f(rc[1]);
    r2_ += b2f(ra[2]) + b2f(rc[2]);  r3_ += b2f(ra[3]) + b2f(rc[3]);
  }
  if (i < e2) {
    int s0 = seS[i], t0 = seT[i];
    short4v ha = *(const short4v*)&hb[(long)s0 * 512 + lane * 4];
    short4v ra = *(const short4v*)&h0b[(long)t0 * 256 + lane * 4];
    h0_ += b2f(ha[0]); h1_ += b2f(ha[1]); h2_ += b2f(ha[2]); h3_ += b2f(ha[3]);
    r0_ += b2f(ra[0]); r1_ += b2f(ra[1]); r2_ += b2f(ra[2]); r3_ += b2f(ra[3]);
  }
  const float nm = 1.f / fmaxf((float)(e2 - b), 1.f);
  short4v rs, o;
  rs[0] = f2b(r0_); rs[1] = f2b(r1_); rs[2] = f2b(r2_); rs[3] = f2b(r3_);
  o[0] = f2b((h0_ + r0_) * nm); o[1] = f2b((h1_ + r1_) * nm);
  o[2] = f2b((h2_ + r2_) * nm); o[3] = f2b((h3_ + r3_) * nm);
  *(short4v*)&rsum[(long)row * 256 + lane * 4] = rs;
  *(short4v*)&acat[(long)row * 512 + lane * 4] = o;
}

// ---------------- layer-1 aggregation: reuses rsum --------------------------------
__global__ __launch_bounds__(256)
void agg_second_k(const int* __restrict__ seS, const unsigned* __restrict__ offd,
                  const short* __restrict__ hb, const short* __restrict__ rsum,
                  short* __restrict__ acat)
{
  const int w = threadIdx.x >> 6, lane = threadIdx.x & 63;
  const int row = blockIdx.x * 4 + w;
  const unsigned b = offd[row], e2 = offd[row + 1];
  short4v rv = *(const short4v*)&rsum[(long)row * 256 + lane * 4];
  float a0 = b2f(rv[0]), a1 = b2f(rv[1]), a2 = b2f(rv[2]), a3 = b2f(rv[3]);
  unsigned i = b;
  for (; i + 4 <= e2; i += 4) {
    int s0 = seS[i], s1 = seS[i + 1], s2 = seS[i + 2], s3 = seS[i + 3];
    short4v p0 = *(const short4v*)&hb[(long)s0 * 512 + lane * 4];
    short4v p1 = *(const short4v*)&hb[(long)s1 * 512 + lane * 4];
    short4v p2 = *(const short4v*)&hb[(long)s2 * 512 + lane * 4];
    short4v p3 = *(const short4v*)&hb[(long)s3 * 512 + lane * 4];
    a0 += b2f(p0[0]) + b2f(p1[0]) + b2f(p2[0]) + b2f(p3[0]);
    a1 += b2f(p0[1]) + b2f(p1[1]) + b2f(p2[1]) + b2f(p3[1]);
    a2 += b2f(p0[2]) + b2f(p1[2]) + b2f(p2[2]) + b2f(p3[2]);
    a3 += b2f(p0[3]) + b2f(p1[3]) + b2f(p2[3]) + b2f(p3[3]);
  }
  for (; i < e2; ++i) {
    short4v p0 = *(const short4v*)&hb[(long)seS[i] * 512 + lane * 4];
    a0 += b2f(p0[0]); a1 += b2f(p0[1]); a2 += b2f(p0[2]); a3 += b2f(p0[3]);
  }
  const float nm = 1.f / fmaxf((float)(e2 - b), 1.f);
  short4v o;
  o[0] = f2b(a0 * nm); o[1] = f2b(a1 * nm); o[2] = f2b(a2 * nm); o[3] = f2b(a3 * nm);
  *(short4v*)&acat[(long)row * 512 + lane * 4] = o;
}

// ---------------- deg==0 fixup: row = rrelu(hc @ evolve_w) (+l2norm if final) ----
// evt is transposed: evt[c][k], read as short8 (8 k's per load)
template<int FINAL>
__global__ __launch_bounds__(256)
void fixup_k(const unsigned* __restrict__ nz, const unsigned* __restrict__ zl,
             const short* __restrict__ hbc, const short* __restrict__ evt,
             short* __restrict__ hbn, float* __restrict__ outF)
{
  __shared__ float x[H];
  __shared__ float red[4];
  const unsigned n = *nz;
  const short* wrow = evt + (long)threadIdx.x * 256;
  for (unsigned zi = blockIdx.x; zi < n; zi += gridDim.x) {
    const int row = zl[zi];
    __syncthreads();
    x[threadIdx.x] = b2f(hbc[(long)row * 512 + threadIdx.x]);
    __syncthreads();
    float acc = 0.f;
#pragma unroll
    for (int k0 = 0; k0 < H; k0 += 8) {
      short8 wv = *(const short8*)&wrow[k0];
      acc += x[k0]     * b2f(wv[0]) + x[k0 + 1] * b2f(wv[1])
           + x[k0 + 2] * b2f(wv[2]) + x[k0 + 3] * b2f(wv[3])
           + x[k0 + 4] * b2f(wv[4]) + x[k0 + 5] * b2f(wv[5])
           + x[k0 + 6] * b2f(wv[6]) + x[k0 + 7] * b2f(wv[7]);
    }
    float v = acc >= 0.f ? acc : acc * SLOPE;
    if (FINAL) {
      float s = v * v;
      s += __shfl_xor(s, 1, 64);  s += __shfl_xor(s, 2, 64);
      s += __shfl_xor(s, 4, 64);  s += __shfl_xor(s, 8, 64);
      s += __shfl_xor(s, 16, 64); s += __shfl_xor(s, 32, 64);
      const int w = threadIdx.x >> 6;
      if ((threadIdx.x & 63) == 0) red[w] = s;
      __syncthreads();
      float tot = (red[0] + red[1]) + (red[2] + red[3]);
      float sc = 1.f / fmaxf(sqrtf(tot), 1e-12f);
      v *= sc;
      outF[(long)row * H + threadIdx.x] = v;
    }
    hbn[(long)row * 512 + threadIdx.x] = f2b(v);
  }
}

// =================================================================================
extern "C" void kernel_launch(void* const* d_in, const int* in_sizes, int n_in,
                              void* d_out, int out_size, void* d_ws, size_t ws_size,
                              hipStream_t stream)
{
  (void)in_sizes; (void)n_in; (void)out_size; (void)ws_size;
  const int* src = (const int*)d_in[0];
  const int* dst = (const int*)d_in[1];
  const int* ety = (const int*)d_in[2];
  const int* r2e_ent = (const int*)d_in[3];
  const int* r2e_rel = (const int*)d_in[4];
  const float* dyn = (const float*)d_in[5];
  const float* erel = (const float*)d_in[6];
  const float* wn = (const float*)d_in[7];
  const float* lw = (const float*)d_in[8];
  const float* ew = (const float*)d_in[9];
  const float* wih = (const float*)d_in[10];
  const float* whh = (const float*)d_in[11];
  const float* bih = (const float*)d_in[12];
  const float* bhh = (const float*)d_in[13];

  float* out = (float*)d_out;
  float* hist = out;
  float* rels = out + (long)TSTEPS * N_ENTS * H;

  char* p = (char*)d_ws;
  auto alloc = [&](size_t n) { char* r = p; p += (n + 255) & ~(size_t)255; return r; };
  short*    AcatA  = (short*)alloc((size_t)N_ENTS * 512 * 2);
  short*    AcatB  = (short*)alloc((size_t)N_ENTS * 512 * 2);
  short*    rsum   = (short*)alloc((size_t)N_ENTS * 256 * 2);
  unsigned* deg    = (unsigned*)alloc((size_t)N_ENTS * 4);
  unsigned* offd   = (unsigned*)alloc((size_t)(N_ENTS + 1) * 4);
  unsigned* curd   = (unsigned*)alloc((size_t)N_ENTS * 4);
  unsigned* bsum   = (unsigned*)alloc((size_t)SCAN_NB * 4);
  int*      seS    = (int*)alloc((size_t)NE * 4);
  int*      seT    = (int*)alloc((size_t)NE * 4);
  unsigned* zl     = (unsigned*)alloc((size_t)N_ENTS * 4);
  unsigned* nz     = (unsigned*)alloc(256);
  unsigned* cnt    = (unsigned*)alloc(R2 * 4);
  unsigned* off    = (unsigned*)alloc((R2 + 1) * 4);
  unsigned* cur    = (unsigned*)alloc(R2 * 4);
  int*      se     = (int*)alloc((size_t)NM * 4);
  float*    xinf   = (float*)alloc((size_t)4 * R2 * 256 * 4);
  short*    x_inb  = (short*)alloc((size_t)R2 * H * 2);
  float*    gxbase = (float*)alloc((size_t)R2 * 768 * 4);
  float*    gx     = (float*)alloc((size_t)R2 * 768 * 4);
  float*    gh     = (float*)alloc((size_t)R2 * 768 * 4);
  float*    h0     = (float*)alloc((size_t)R2 * H * 4);
  short*    h0b    = (short*)alloc((size_t)R2 * H * 2);
  short*    erelb  = (short*)alloc((size_t)R2 * H * 2);
  short*    wcatb  = (short*)alloc((size_t)NL * 256 * 512 * 2);
  short*    evt    = (short*)alloc((size_t)NL * H * H * 2);
  short*    wihb   = (short*)alloc((size_t)768 * 512 * 2);
  short*    whhb   = (short*)alloc((size_t)768 * 256 * 2);

  wcat_k<<<(NL * 256 * 512 + 255) / 256, 256, 0, stream>>>(wn, lw, wcatb);
  wtr_k<<<(NL * 65536 + 255) / 256, 256, 0, stream>>>(ew, evt);
  castcopy_k<<<(768 * 512 + 255) / 256, 256, 0, stream>>>(wih, wihb, 768 * 512);
  castcopy_k<<<(768 * 256 + 255) / 256, 256, 0, stream>>>(whh, whhb, 768 * 256);
  castcopy_k<<<(R2 * H + 255) / 256, 256, 0, stream>>>(erel, erelb, (long)R2 * H);
  h0init_k<<<(R2 * H + 255) / 256, 256, 0, stream>>>(erel, h0, h0b);
  l2init_k<<<N_ENTS / 4, 256, 0, stream>>>(dyn, AcatA + 256);

  // gx_base = emb_rel @ W_ih[:, :256]^T + b_ih   (step-invariant)
  gemm_k<<<dim3(8, 3), 256, 0, stream>>>(erelb, 256, wihb, 512, R2, 256,
                                         gxbase, 768, bih);

  short* Acur = AcatA;
  short* Anxt = AcatB;

  for (int t = 0; t < TSTEPS; ++t) {
    const int* src_t = src + (long)t * NE;
    const int* dst_t = dst + (long)t * NE;
    const int* ety_t = ety + (long)t * NE;
    const int* re_t  = r2e_ent + (long)t * NM;
    const int* rr_t  = r2e_rel + (long)t * NM;
    float* hist_t = hist + (long)t * N_ENTS * H;
    float* rels_t = rels + (long)t * R2 * H;

    zero_k<<<SCAN_NB, 256, 0, stream>>>(deg, curd, cnt, cur, nz);
    count_k<<<512, 256, 0, stream>>>(rr_t, dst_t, cnt, deg);
    prefix_k<<<1, 256, 0, stream>>>(cnt, off);
    scan1_k<<<SCAN_NB, 256, 0, stream>>>(deg, offd, bsum);
    scan2_k<<<1, 256, 0, stream>>>(bsum);
    scan3_k<<<SCAN_NB, 256, 0, stream>>>(offd, bsum, deg, zl, nz);
    scatterB_k<<<768, 256, 0, stream>>>(rr_t, re_t, off, cur, se,
                                        src_t, dst_t, ety_t, offd, curd, seS, seT);

    // relation mean (split x4) + GRU
    segpart_k<<<R2 * 4, 256, 0, stream>>>(off, se, Acur + 256, xinf);
    segfin_k<<<R2, 256, 0, stream>>>(xinf, cnt, x_inb);
    gru2_k<<<dim3(8, 3, 2), 256, 0, stream>>>(x_inb, h0b, wihb, whhb, gxbase, bhh, gx, gh);
    gate_k<<<R2, 256, 0, stream>>>(gx, gh, h0, h0b, rels_t);

    // layer 0
    agg_first_k<<<N_ENTS / 4, 256, 0, stream>>>(seS, seT, offd, Acur + 256, h0b, rsum, Acur);
    gemm_big<1><<<391, 256, 0, stream>>>(Acur, 512, wcatb, 512,
                                         N_ENTS, 512, nullptr, 0, Anxt + 256, 512);
    fixup_k<0><<<512, 256, 0, stream>>>(nz, zl, Acur + 256, evt, Anxt + 256, nullptr);
    { short* tmp = Acur; Acur = Anxt; Anxt = tmp; }

    // layer 1
    agg_second_k<<<N_ENTS / 4, 256, 0, stream>>>(seS, offd, Acur + 256, rsum, Acur);
    gemm_big<2><<<391, 256, 0, stream>>>(Acur, 512, wcatb + 256 * 512, 512,
                                         N_ENTS, 512, hist_t, 256, Anxt + 256, 512);
    fixup_k<1><<<512, 256, 0, stream>>>(nz, zl, Acur + 256, evt + (long)H * H,
                                        Anxt + 256, hist_t);
    { short* tmp = Acur; Acur = Anxt; Anxt = tmp; }
  }
}

// Round 5
// 1304.951 us; speedup vs baseline: 5.4677x; 1.0110x over previous
//
#include <hip/hip_runtime.h>

#define N_ENTS 50000
#define R2 500
#define H 256
#define TSTEPS 4
#define NE 200000
#define NM 200000
#define NL 2
#define SLOPE 0.22916666666666666f
#define SCAN_NB ((N_ENTS + 255) / 256)   // 196

typedef __attribute__((ext_vector_type(8))) short short8;
typedef __attribute__((ext_vector_type(4))) short short4v;
typedef __attribute__((ext_vector_type(4))) float f32x4;

static __device__ __forceinline__ float b2f(short s) {
  unsigned u = ((unsigned)(unsigned short)s) << 16;
  return __builtin_bit_cast(float, u);
}
static __device__ __forceinline__ short f2b(float f) {
  unsigned u = __builtin_bit_cast(unsigned, f);
  u = (u + 0x7FFFu + ((u >> 16) & 1u)) >> 16;
  return (short)(unsigned short)u;
}

static __device__ __forceinline__ void gload16(const short* g, short* l) {
  __builtin_amdgcn_global_load_lds(
      (const __attribute__((address_space(1))) void*)g,
      (__attribute__((address_space(3))) void*)l, 16, 0, 0);
}

// ---------------- big GEMM: C[M x 256] = A[M x K](bf16) * Bt[256 x K](bf16)^T ----
// 128x256 block, BK=64, 4 waves x (64 rows x 128 cols), global_load_lds staging
// with XOR slot-swizzle (slot ^= row&7) on both source and read sides.
// EPI 1: Obf = bf16(rrelu(acc))                      (ldo)
// EPI 2: l2norm(rrelu(acc)) -> Cf (f32, ldc) and Obf (bf16, ldo)
template<int EPI>
__global__ __launch_bounds__(256, 2)
void gemm_big(const short* __restrict__ A, int lda,
              const short* __restrict__ Bt, int ldb,
              int M, int K,
              float* __restrict__ Cf, int ldc,
              short* __restrict__ Obf, int ldo)
{
  __shared__ short As[128 * 64];
  __shared__ short Bs[256 * 64];
  const int tid = threadIdx.x;
  const int w = tid >> 6, lane = tid & 63;
  const int fr = lane & 15, fq = lane >> 4;
  const int rowh = w >> 1, colh = w & 1;
  const int blk0 = blockIdx.x * 128;
  const int l8 = lane >> 3, s7 = lane & 7;

  f32x4 acc[4][8];
#pragma unroll
  for (int m = 0; m < 4; ++m)
#pragma unroll
    for (int n = 0; n < 8; ++n) {
      acc[m][n][0] = 0.f; acc[m][n][1] = 0.f; acc[m][n][2] = 0.f; acc[m][n][3] = 0.f;
    }

  for (int kc = 0; kc < K; kc += 64) {
    __syncthreads();
#pragma unroll
    for (int i = 0; i < 4; ++i) {          // A tile: 128 rows x 64 k
      int row = w * 32 + i * 8 + l8;
      int grow = min(blk0 + row, M - 1);
      const short* g = A + (size_t)grow * lda + kc + ((s7 ^ (row & 7)) << 3);
      gload16(g, As + w * 2048 + i * 512);
    }
#pragma unroll
    for (int i = 0; i < 8; ++i) {          // B tile: 256 cols x 64 k
      int row = w * 64 + i * 8 + l8;
      const short* g = Bt + (size_t)row * ldb + kc + ((s7 ^ (row & 7)) << 3);
      gload16(g, Bs + w * 4096 + i * 512);
    }
    __syncthreads();
#pragma unroll
    for (int ks = 0; ks < 2; ++ks) {
      const int sl = ((((ks << 2) | fq) ^ s7) << 3);
      short8 a[4], b[8];
#pragma unroll
      for (int m = 0; m < 4; ++m)
        a[m] = *(const short8*)&As[(rowh * 64 + m * 16 + fr) * 64 + sl];
#pragma unroll
      for (int n = 0; n < 8; ++n)
        b[n] = *(const short8*)&Bs[(colh * 128 + n * 16 + fr) * 64 + sl];
#pragma unroll
      for (int m = 0; m < 4; ++m)
#pragma unroll
        for (int n = 0; n < 8; ++n)
          acc[m][n] = __builtin_amdgcn_mfma_f32_16x16x32_bf16(a[m], b[n], acc[m][n], 0, 0, 0);
    }
  }

  if (EPI == 1) {
#pragma unroll
    for (int m = 0; m < 4; ++m)
#pragma unroll
      for (int n = 0; n < 8; ++n) {
        const int col = colh * 128 + n * 16 + fr;
#pragma unroll
        for (int j = 0; j < 4; ++j) {
          const int r = blk0 + rowh * 64 + m * 16 + fq * 4 + j;
          if (r < M) {
            float v = acc[m][n][j];
            v = v >= 0.f ? v : v * SLOPE;
            Obf[(size_t)r * ldo + col] = f2b(v);
          }
        }
      }
  } else {
    float ss[4][4];
#pragma unroll
    for (int m = 0; m < 4; ++m)
#pragma unroll
      for (int j = 0; j < 4; ++j) ss[m][j] = 0.f;
#pragma unroll
    for (int m = 0; m < 4; ++m)
#pragma unroll
      for (int n = 0; n < 8; ++n)
#pragma unroll
        for (int j = 0; j < 4; ++j) {
          float v = acc[m][n][j];
          v = v >= 0.f ? v : v * SLOPE;
          acc[m][n][j] = v;
          ss[m][j] += v * v;
        }
#pragma unroll
    for (int m = 0; m < 4; ++m)
#pragma unroll
      for (int j = 0; j < 4; ++j) {
        float s = ss[m][j];
        s += __shfl_xor(s, 1, 64);
        s += __shfl_xor(s, 2, 64);
        s += __shfl_xor(s, 4, 64);
        s += __shfl_xor(s, 8, 64);
        ss[m][j] = s;                      // half-row (128-col) sum, all lanes
      }
    __syncthreads();                       // compute done; reuse Bs
    float* red = (float*)Bs;               // [0..255]: partials, [256..511]: inv
    if (colh == 0 && fr == 0) {
#pragma unroll
      for (int m = 0; m < 4; ++m)
#pragma unroll
        for (int j = 0; j < 4; ++j)
          red[rowh * 128 + m * 16 + fq * 4 + j] = ss[m][j];
    }
    __syncthreads();
    float inv[4][4];
    if (colh == 1) {
#pragma unroll
      for (int m = 0; m < 4; ++m)
#pragma unroll
        for (int j = 0; j < 4; ++j) {
          float tot = ss[m][j] + red[rowh * 128 + m * 16 + fq * 4 + j];
          inv[m][j] = 1.f / fmaxf(sqrtf(tot), 1e-12f);
        }
      if (fr == 0) {
#pragma unroll
        for (int m = 0; m < 4; ++m)
#pragma unroll
          for (int j = 0; j < 4; ++j)
            red[256 + rowh * 128 + m * 16 + fq * 4 + j] = inv[m][j];
      }
    }
    __syncthreads();
    if (colh == 0) {
#pragma unroll
      for (int m = 0; m < 4; ++m)
#pragma unroll
        for (int j = 0; j < 4; ++j)
          inv[m][j] = red[256 + rowh * 128 + m * 16 + fq * 4 + j];
    }
#pragma unroll
    for (int m = 0; m < 4; ++m)
#pragma unroll
      for (int n = 0; n < 8; ++n) {
        const int col = colh * 128 + n * 16 + fr;
#pragma unroll
        for (int j = 0; j < 4; ++j) {
          const int r = blk0 + rowh * 64 + m * 16 + fq * 4 + j;
          if (r < M) {
            float v = acc[m][n][j] * inv[m][j];
            Cf[(size_t)r * ldc + col] = v;
            Obf[(size_t)r * ldo + col] = f2b(v);
          }
        }
      }
  }
}

// ---------------- small GEMM (init only): C = A * Bt^T (+bias), f32 out ----------
__global__ __launch_bounds__(256)
void gemm_k(const short* __restrict__ A, int lda,
            const short* __restrict__ Bt, int ldb,
            int M, int K,
            float* __restrict__ Cf, int ldc,
            const float* __restrict__ bias)
{
  __shared__ short bt[256 * 72];
  const int tid = threadIdx.x;
  const int w = tid >> 6;
  const int lane = tid & 63;
  const int fr = lane & 15;
  const int fq = lane >> 4;
  const int col0 = blockIdx.y << 8;
  const int rowbase = blockIdx.x * 64 + w * 16;
  const int arow = min(rowbase + fr, M - 1);
  const long abase = (long)arow * lda + fq * 8;

  f32x4 acc[16];
#pragma unroll
  for (int i = 0; i < 16; ++i) { acc[i][0] = 0.f; acc[i][1] = 0.f; acc[i][2] = 0.f; acc[i][3] = 0.f; }

  for (int kc = 0; kc < K; kc += 64) {
    __syncthreads();
    {
      const short* g = Bt + (long)(col0 + tid) * ldb + kc;
      short* l = &bt[tid * 72];
#pragma unroll
      for (int i = 0; i < 8; ++i)
        *(short8*)(l + i * 8) = *(const short8*)(g + i * 8);
    }
    __syncthreads();
#pragma unroll
    for (int ks = 0; ks < 2; ++ks) {
      short8 a = *(const short8*)(A + abase + kc + ks * 32);
#pragma unroll
      for (int ct = 0; ct < 16; ++ct) {
        short8 b = *(const short8*)&bt[(ct * 16 + fr) * 72 + ks * 32 + fq * 8];
        acc[ct] = __builtin_amdgcn_mfma_f32_16x16x32_bf16(a, b, acc[ct], 0, 0, 0);
      }
    }
  }

  const int crow = rowbase + fq * 4;
#pragma unroll
  for (int ct = 0; ct < 16; ++ct) {
    const int gcol = col0 + ct * 16 + fr;
#pragma unroll
    for (int j = 0; j < 4; ++j) {
      const int r = crow + j;
      if (r < M) {
        float v = acc[ct][j];
        if (bias) v += bias[gcol];
        Cf[(long)r * ldc + gcol] = v;
      }
    }
  }
}

// ---------------- fused GRU GEMMs: z=0 -> gx, z=1 -> gh ---------------------------
__global__ __launch_bounds__(256)
void gru2_k(const short* __restrict__ x_inb, const short* __restrict__ h0b,
            const short* __restrict__ wihb, const short* __restrict__ whhb,
            const float* __restrict__ gxbase, const float* __restrict__ bhh,
            float* __restrict__ gx, float* __restrict__ gh)
{
  const short* A;  const short* Bt;  int ldb;
  float* Cf;  const float* Cadd;  const float* bias;
  if (blockIdx.z == 0) { A = x_inb; Bt = wihb + 256; ldb = 512; Cf = gx; Cadd = gxbase; bias = nullptr; }
  else                 { A = h0b;   Bt = whhb;       ldb = 256; Cf = gh; Cadd = nullptr; bias = bhh; }

  __shared__ short bt[256 * 72];
  const int tid = threadIdx.x;
  const int w = tid >> 6;
  const int lane = tid & 63;
  const int fr = lane & 15;
  const int fq = lane >> 4;
  const int col0 = blockIdx.y << 8;
  const int rowbase = blockIdx.x * 64 + w * 16;
  const int arow = min(rowbase + fr, R2 - 1);
  const long abase = (long)arow * 256 + fq * 8;

  f32x4 acc[16];
#pragma unroll
  for (int i = 0; i < 16; ++i) { acc[i][0] = 0.f; acc[i][1] = 0.f; acc[i][2] = 0.f; acc[i][3] = 0.f; }

  for (int kc = 0; kc < 256; kc += 64) {
    __syncthreads();
    {
      const short* g = Bt + (long)(col0 + tid) * ldb + kc;
      short* l = &bt[tid * 72];
#pragma unroll
      for (int i = 0; i < 8; ++i)
        *(short8*)(l + i * 8) = *(const short8*)(g + i * 8);
    }
    __syncthreads();
#pragma unroll
    for (int ks = 0; ks < 2; ++ks) {
      short8 a = *(const short8*)(A + abase + kc + ks * 32);
#pragma unroll
      for (int ct = 0; ct < 16; ++ct) {
        short8 b = *(const short8*)&bt[(ct * 16 + fr) * 72 + ks * 32 + fq * 8];
        acc[ct] = __builtin_amdgcn_mfma_f32_16x16x32_bf16(a, b, acc[ct], 0, 0, 0);
      }
    }
  }

  const int crow = rowbase + fq * 4;
#pragma unroll
  for (int ct = 0; ct < 16; ++ct) {
    const int gcol = col0 + ct * 16 + fr;
#pragma unroll
    for (int j = 0; j < 4; ++j) {
      const int r = crow + j;
      if (r < R2) {
        float v = acc[ct][j];
        if (Cadd) v += Cadd[(long)r * 768 + gcol];
        if (bias) v += bias[gcol];
        Cf[(long)r * 768 + gcol] = v;
      }
    }
  }
}

// ---------------- init: h = l2norm(dynamic_emb) -> bf16 into Acat halfB ----------
__global__ __launch_bounds__(256)
void l2init_k(const float* __restrict__ de, short* __restrict__ hb)
{
  const int w = threadIdx.x >> 6, lane = threadIdx.x & 63;
  const int row = blockIdx.x * 4 + w;
  f32x4 v = *(const f32x4*)&de[(long)row * H + lane * 4];
  float s = v[0]*v[0] + v[1]*v[1] + v[2]*v[2] + v[3]*v[3];
  s += __shfl_xor(s, 1, 64);  s += __shfl_xor(s, 2, 64);
  s += __shfl_xor(s, 4, 64);  s += __shfl_xor(s, 8, 64);
  s += __shfl_xor(s, 16, 64); s += __shfl_xor(s, 32, 64);
  float sc = 1.f / fmaxf(sqrtf(s), 1e-12f);
  short4v o;
  o[0] = f2b(v[0]*sc); o[1] = f2b(v[1]*sc); o[2] = f2b(v[2]*sc); o[3] = f2b(v[3]*sc);
  *(short4v*)&hb[(long)row * 512 + lane * 4] = o;
}

// ---------------- merged weight prep ---------------------------------------------
// ranges: wcat (NL*256*512) | wtr (NL*65536) | wih (768*512) | whh (768*256) | erel (R2*H)
__global__ __launch_bounds__(256)
void prep_k(const float* __restrict__ wn, const float* __restrict__ lw,
            const float* __restrict__ ew, const float* __restrict__ wih,
            const float* __restrict__ whh, const float* __restrict__ erel,
            short* __restrict__ wcatb, short* __restrict__ evt,
            short* __restrict__ wihb, short* __restrict__ whhb,
            short* __restrict__ erelb, float* __restrict__ h0, short* __restrict__ h0b)
{
  long i = (long)blockIdx.x * 256 + threadIdx.x;
  if (i < (long)NL * 256 * 512) {
    int l = (int)(i / (256 * 512));
    int rem = (int)(i % (256 * 512));
    int j = rem / 512;
    int k = rem % 512;
    float v = (k < 256) ? wn[(long)l * 65536 + k * 256 + j]
                        : lw[(long)l * 65536 + (k - 256) * 256 + j];
    wcatb[i] = f2b(v);
    return;
  }
  i -= (long)NL * 256 * 512;
  if (i < (long)NL * 65536) {
    int l = (int)(i >> 16);
    int rem = (int)(i & 65535);
    int c = rem >> 8, k = rem & 255;
    evt[i] = f2b(ew[(long)l * 65536 + k * 256 + c]);
    return;
  }
  i -= (long)NL * 65536;
  if (i < 768 * 512) { wihb[i] = f2b(wih[i]); return; }
  i -= 768 * 512;
  if (i < 768 * 256) { whhb[i] = f2b(whh[i]); return; }
  i -= 768 * 256;
  if (i < (long)R2 * H) {
    float v = erel[i];
    erelb[i] = f2b(v); h0[i] = v; h0b[i] = f2b(v);
  }
}
#define PREP_N ((long)NL * 256 * 512 + (long)NL * 65536 + 768 * 512 + 768 * 256 + (long)R2 * H)

// ---------------- per-step zero of counter buffers --------------------------------
__global__ __launch_bounds__(256)
void zero_k(unsigned* __restrict__ deg, unsigned* __restrict__ curd,
            unsigned* __restrict__ cnt, unsigned* __restrict__ cur,
            unsigned* __restrict__ nz, unsigned* __restrict__ flags)
{
  int i = blockIdx.x * 256 + threadIdx.x;
  if (i < N_ENTS) { deg[i] = 0u; curd[i] = 0u; }
  if (i < R2) { cnt[i] = 0u; cur[i] = 0u; }
  if (i < SCAN_NB) flags[i] = 0u;
  if (i == 0) nz[0] = 0u;
}

// ---------------- fused counting: rel histogram (LDS) + dst degree (global) ------
__global__ __launch_bounds__(256)
void count_k(const int* __restrict__ rel, const int* __restrict__ dstv,
             unsigned* __restrict__ cnt, unsigned* __restrict__ deg)
{
  __shared__ unsigned lh[R2];
  for (int i = threadIdx.x; i < R2; i += 256) lh[i] = 0;
  __syncthreads();
  for (long i = (long)blockIdx.x * 256 + threadIdx.x; i < NM; i += (long)gridDim.x * 256)
    atomicAdd(&lh[rel[i]], 1u);
  for (long i = (long)blockIdx.x * 256 + threadIdx.x; i < NE; i += (long)gridDim.x * 256)
    atomicAdd(&deg[dstv[i]], 1u);
  __syncthreads();
  for (int i = threadIdx.x; i < R2; i += 256)
    if (lh[i]) atomicAdd(&cnt[i], lh[i]);
}

// ---------------- single-kernel scans: decoupled lookback (deg) + rel prefix ------
// blocks 0..SCAN_NB-1: exclusive scan of deg -> offd, zero-list; block SCAN_NB: rel prefix
__global__ __launch_bounds__(256)
void scanall_k(const unsigned* __restrict__ deg, unsigned* __restrict__ offd,
               unsigned* __restrict__ flags,
               unsigned* __restrict__ zl, unsigned* __restrict__ nz,
               const unsigned* __restrict__ cnt, unsigned* __restrict__ off)
{
  if (blockIdx.x == SCAN_NB) {           // rel-histogram prefix (512-slot HS)
    __shared__ unsigned sr[512];
    const int t = threadIdx.x;
    sr[t] = (t < R2) ? cnt[t] : 0u;
    sr[t + 256] = (t + 256 < R2) ? cnt[t + 256] : 0u;
    __syncthreads();
#pragma unroll
    for (int d = 1; d < 512; d <<= 1) {
      unsigned v0 = (t >= d) ? sr[t - d] : 0u;
      unsigned v1 = (t + 256 >= d) ? sr[t + 256 - d] : 0u;
      __syncthreads();
      sr[t] += v0; sr[t + 256] += v1;
      __syncthreads();
    }
    if (t < R2) off[t] = (t == 0) ? 0u : sr[t - 1];
    if (t + 256 < R2) off[t + 256] = sr[t + 255];
    if (t == 0) off[R2] = sr[R2 - 1];
    return;
  }
  __shared__ unsigned s[256];
  __shared__ unsigned sexc;
  const int tid = threadIdx.x;
  const int b = blockIdx.x;
  const int i = b * 256 + tid;
  unsigned v = (i < N_ENTS) ? deg[i] : 0u;
  s[tid] = v;
  __syncthreads();
#pragma unroll
  for (int d = 1; d < 256; d <<= 1) {
    unsigned t2 = (tid >= d) ? s[tid - d] : 0u;
    __syncthreads();
    s[tid] += t2;
    __syncthreads();
  }
  const unsigned total = s[255];
  if (tid == 0) {
    if (b == 0) {
      __threadfence();
      atomicExch(&flags[0], (2u << 30) | total);
      sexc = 0u;
    } else {
      __threadfence();
      atomicExch(&flags[b], (1u << 30) | total);
      unsigned exc = 0u;
      int j = b - 1;
      while (j >= 0) {
        unsigned f;
        do { f = atomicAdd(&flags[j], 0u); } while ((f >> 30) == 0u);
        exc += f & 0x3FFFFFFFu;
        if ((f >> 30) == 2u) break;
        --j;
      }
      __threadfence();
      atomicExch(&flags[b], (2u << 30) | (exc + total));
      sexc = exc;
    }
  }
  __syncthreads();
  const unsigned exc = sexc;
  if (i < N_ENTS) {
    offd[i] = exc + s[tid] - v;
    if (v == 0u) { unsigned p2 = atomicAdd(nz, 1u); zl[p2] = i; }
  }
  if (i == 0) offd[N_ENTS] = NE;
}

// ---------------- fused scatter: rel-CSR (ent) + dst-CSR (src,etype int2) ---------
__global__ __launch_bounds__(256)
void scatterB_k(const int* __restrict__ rel, const int* __restrict__ ent,
                const unsigned* __restrict__ off, unsigned* __restrict__ cur,
                int* __restrict__ se,
                const int* __restrict__ srcv, const int* __restrict__ dstv,
                const int* __restrict__ etv, const unsigned* __restrict__ offd,
                unsigned* __restrict__ curd, int2* __restrict__ se2)
{
  if (blockIdx.x < 256) {
    for (long i = (long)blockIdx.x * 256 + threadIdx.x; i < NM; i += 256l * 256) {
      int r = rel[i];
      unsigned p = atomicAdd(&cur[r], 1u);
      se[off[r] + p] = ent[i];
    }
  } else {
    for (long i = (long)(blockIdx.x - 256) * 256 + threadIdx.x; i < NE; i += 512l * 256) {
      int d = dstv[i];
      unsigned p = atomicAdd(&curd[d], 1u);
      se2[offd[d] + p] = make_int2(srcv[i], etv[i]);
    }
  }
}

// ---------------- segment-sum partials (x4 split), 16B/lane, 2 entries/wave -------
__global__ __launch_bounds__(256)
void segpart_k(const unsigned* __restrict__ off, const int* __restrict__ se,
               const short* __restrict__ hb, float* __restrict__ xinf)
{
  __shared__ float red[4][256];
  const int r = blockIdx.x >> 2, s = blockIdx.x & 3;
  const int w = threadIdx.x >> 6, lane = threadIdx.x & 63;
  const int half = lane >> 5, sl = lane & 31;
  const unsigned b = off[r], e = off[r + 1], len = e - b;
  const unsigned lo = b + ((len * s) >> 2), hi = b + ((len * (s + 1)) >> 2);
  float a[8];
#pragma unroll
  for (int j = 0; j < 8; ++j) a[j] = 0.f;
  unsigned i = lo + w * 2;
  for (; i + 10 <= hi; i += 16) {          // two pairs per wave per iter
    int e0 = se[i + half];
    int e1 = se[i + 8 + half];
    short8 h0v = *(const short8*)&hb[(long)e0 * 512 + sl * 8];
    short8 h1v = *(const short8*)&hb[(long)e1 * 512 + sl * 8];
#pragma unroll
    for (int j = 0; j < 8; ++j) a[j] += b2f(h0v[j]) + b2f(h1v[j]);
  }
  for (; i + 2 <= hi; i += 8) {
    int e0 = se[i + half];
    short8 hv = *(const short8*)&hb[(long)e0 * 512 + sl * 8];
#pragma unroll
    for (int j = 0; j < 8; ++j) a[j] += b2f(hv[j]);
  }
  if (i + half < hi) {
    int e0 = se[i + half];
    short8 hv = *(const short8*)&hb[(long)e0 * 512 + sl * 8];
#pragma unroll
    for (int j = 0; j < 8; ++j) a[j] += b2f(hv[j]);
  }
#pragma unroll
  for (int j = 0; j < 8; ++j) a[j] += __shfl_xor(a[j], 32, 64);
  if (half == 0) {
#pragma unroll
    for (int j = 0; j < 8; ++j) red[w][sl * 8 + j] = a[j];
  }
  __syncthreads();
  const int t = threadIdx.x;
  xinf[((long)s * R2 + r) * 256 + t] =
      (red[0][t] + red[1][t]) + (red[2][t] + red[3][t]);
}

__global__ __launch_bounds__(256)
void segfin_k(const float* __restrict__ xinf, const unsigned* __restrict__ cnt,
              short* __restrict__ x_inb)
{
  const int r = blockIdx.x, tid = threadIdx.x;
  float v = xinf[(long)r * 256 + tid] + xinf[((long)R2 + r) * 256 + tid]
          + xinf[((long)2 * R2 + r) * 256 + tid] + xinf[((long)3 * R2 + r) * 256 + tid];
  v /= fmaxf((float)cnt[r], 1.f);
  x_inb[(long)r * 256 + tid] = f2b(v);
}

// ---------------- GRU gates ------------------------------------------------------
__global__ __launch_bounds__(256)
void gate_k(const float* __restrict__ gx, const float* __restrict__ gh,
            float* __restrict__ h0, short* __restrict__ h0b, float* __restrict__ relout)
{
  __shared__ float red[4];
  const int r = blockIdx.x, c = threadIdx.x;
  const long b = (long)r * 768;
  float xr = gx[b + c], xz = gx[b + 256 + c], xn = gx[b + 512 + c];
  float hr = gh[b + c], hz = gh[b + 256 + c], hn = gh[b + 512 + c];
  float rr = 1.f / (1.f + expf(-(xr + hr)));
  float z  = 1.f / (1.f + expf(-(xz + hz)));
  float nn = tanhf(xn + rr * hn);
  float v = (1.f - z) * nn + z * h0[(long)r * H + c];
  float s = v * v;
  s += __shfl_xor(s, 1, 64);  s += __shfl_xor(s, 2, 64);
  s += __shfl_xor(s, 4, 64);  s += __shfl_xor(s, 8, 64);
  s += __shfl_xor(s, 16, 64); s += __shfl_xor(s, 32, 64);
  const int w = c >> 6;
  if ((c & 63) == 0) red[w] = s;
  __syncthreads();
  float tot = (red[0] + red[1]) + (red[2] + red[3]);
  float sc = 1.f / fmaxf(sqrtf(tot), 1e-12f);
  v *= sc;
  h0[(long)r * H + c] = v;
  h0b[(long)r * H + c] = f2b(v);
  relout[(long)r * H + c] = v;
}

// ---------------- layer-0 aggregation: 16B/lane, 2 edges/wave, emits rsum --------
__global__ __launch_bounds__(256)
void agg_first_k(const int2* __restrict__ se2, const unsigned* __restrict__ offd,
                 const short* __restrict__ hb, const short* __restrict__ h0b,
                 short* __restrict__ rsum, short* __restrict__ acat)
{
  const int w = threadIdx.x >> 6, lane = threadIdx.x & 63;
  const int half = lane >> 5, sl = lane & 31;
  const int row = blockIdx.x * 4 + w;
  const unsigned b = offd[row], e = offd[row + 1];
  float ha[8], ra[8];
#pragma unroll
  for (int j = 0; j < 8; ++j) { ha[j] = 0.f; ra[j] = 0.f; }
  unsigned i = b;
  for (; i + 4 <= e; i += 4) {
    int2 e0 = se2[i + half];
    int2 e1 = se2[i + 2 + half];
    short8 h0v = *(const short8*)&hb[(long)e0.x * 512 + sl * 8];
    short8 r0v = *(const short8*)&h0b[(long)e0.y * 256 + sl * 8];
    short8 h1v = *(const short8*)&hb[(long)e1.x * 512 + sl * 8];
    short8 r1v = *(const short8*)&h0b[(long)e1.y * 256 + sl * 8];
#pragma unroll
    for (int j = 0; j < 8; ++j) {
      ha[j] += b2f(h0v[j]) + b2f(h1v[j]);
      ra[j] += b2f(r0v[j]) + b2f(r1v[j]);
    }
  }
  for (; i < e; i += 2) {
    if (i + half < e) {
      int2 e0 = se2[i + half];
      short8 hv = *(const short8*)&hb[(long)e0.x * 512 + sl * 8];
      short8 rv = *(const short8*)&h0b[(long)e0.y * 256 + sl * 8];
#pragma unroll
      for (int j = 0; j < 8; ++j) { ha[j] += b2f(hv[j]); ra[j] += b2f(rv[j]); }
    }
  }
#pragma unroll
  for (int j = 0; j < 8; ++j) {
    ha[j] += __shfl_xor(ha[j], 32, 64);
    ra[j] += __shfl_xor(ra[j], 32, 64);
  }
  if (half == 0) {
    const float nm = 1.f / fmaxf((float)(e - b), 1.f);
    short8 rs, o;
#pragma unroll
    for (int j = 0; j < 8; ++j) {
      rs[j] = f2b(ra[j]);
      o[j] = f2b((ha[j] + ra[j]) * nm);
    }
    *(short8*)&rsum[(long)row * 256 + sl * 8] = rs;
    *(short8*)&acat[(long)row * 512 + sl * 8] = o;
  }
}

// ---------------- layer-1 aggregation: reuses rsum, 16B/lane, 2 edges/wave -------
__global__ __launch_bounds__(256)
void agg_second_k(const int2* __restrict__ se2, const unsigned* __restrict__ offd,
                  const short* __restrict__ hb, const short* __restrict__ rsum,
                  short* __restrict__ acat)
{
  const int w = threadIdx.x >> 6, lane = threadIdx.x & 63;
  const int half = lane >> 5, sl = lane & 31;
  const int row = blockIdx.x * 4 + w;
  const unsigned b = offd[row], e = offd[row + 1];
  float ha[8];
#pragma unroll
  for (int j = 0; j < 8; ++j) ha[j] = 0.f;
  unsigned i = b;
  for (; i + 4 <= e; i += 4) {
    int2 e0 = se2[i + half];
    int2 e1 = se2[i + 2 + half];
    short8 h0v = *(const short8*)&hb[(long)e0.x * 512 + sl * 8];
    short8 h1v = *(const short8*)&hb[(long)e1.x * 512 + sl * 8];
#pragma unroll
    for (int j = 0; j < 8; ++j) ha[j] += b2f(h0v[j]) + b2f(h1v[j]);
  }
  for (; i < e; i += 2) {
    if (i + half < e) {
      int2 e0 = se2[i + half];
      short8 hv = *(const short8*)&hb[(long)e0.x * 512 + sl * 8];
#pragma unroll
      for (int j = 0; j < 8; ++j) ha[j] += b2f(hv[j]);
    }
  }
#pragma unroll
  for (int j = 0; j < 8; ++j) ha[j] += __shfl_xor(ha[j], 32, 64);
  if (half == 0) {
    short8 rs = *(const short8*)&rsum[(long)row * 256 + sl * 8];
    const float nm = 1.f / fmaxf((float)(e - b), 1.f);
    short8 o;
#pragma unroll
    for (int j = 0; j < 8; ++j) o[j] = f2b((ha[j] + b2f(rs[j])) * nm);
    *(short8*)&acat[(long)row * 512 + sl * 8] = o;
  }
}

// ---------------- deg==0 fixup: row = rrelu(hc @ evolve_w) (+l2norm if final) ----
// evt is transposed: evt[c][k], read as short8 (8 k's per load)
template<int FINAL>
__global__ __launch_bounds__(256)
void fixup_k(const unsigned* __restrict__ nz, const unsigned* __restrict__ zl,
             const short* __restrict__ hbc, const short* __restrict__ evt,
             short* __restrict__ hbn, float* __restrict__ outF)
{
  __shared__ float x[H];
  __shared__ float red[4];
  const unsigned n = *nz;
  const short* wrow = evt + (long)threadIdx.x * 256;
  for (unsigned zi = blockIdx.x; zi < n; zi += gridDim.x) {
    const int row = zl[zi];
    __syncthreads();
    x[threadIdx.x] = b2f(hbc[(long)row * 512 + threadIdx.x]);
    __syncthreads();
    float acc = 0.f;
#pragma unroll
    for (int k0 = 0; k0 < H; k0 += 8) {
      short8 wv = *(const short8*)&wrow[k0];
      acc += x[k0]     * b2f(wv[0]) + x[k0 + 1] * b2f(wv[1])
           + x[k0 + 2] * b2f(wv[2]) + x[k0 + 3] * b2f(wv[3])
           + x[k0 + 4] * b2f(wv[4]) + x[k0 + 5] * b2f(wv[5])
           + x[k0 + 6] * b2f(wv[6]) + x[k0 + 7] * b2f(wv[7]);
    }
    float v = acc >= 0.f ? acc : acc * SLOPE;
    if (FINAL) {
      float s = v * v;
      s += __shfl_xor(s, 1, 64);  s += __shfl_xor(s, 2, 64);
      s += __shfl_xor(s, 4, 64);  s += __shfl_xor(s, 8, 64);
      s += __shfl_xor(s, 16, 64); s += __shfl_xor(s, 32, 64);
      const int w = threadIdx.x >> 6;
      if ((threadIdx.x & 63) == 0) red[w] = s;
      __syncthreads();
      float tot = (red[0] + red[1]) + (red[2] + red[3]);
      float sc = 1.f / fmaxf(sqrtf(tot), 1e-12f);
      v *= sc;
      outF[(long)row * H + threadIdx.x] = v;
    }
    hbn[(long)row * 512 + threadIdx.x] = f2b(v);
  }
}

// =================================================================================
extern "C" void kernel_launch(void* const* d_in, const int* in_sizes, int n_in,
                              void* d_out, int out_size, void* d_ws, size_t ws_size,
                              hipStream_t stream)
{
  (void)in_sizes; (void)n_in; (void)out_size; (void)ws_size;
  const int* src = (const int*)d_in[0];
  const int* dst = (const int*)d_in[1];
  const int* ety = (const int*)d_in[2];
  const int* r2e_ent = (const int*)d_in[3];
  const int* r2e_rel = (const int*)d_in[4];
  const float* dyn = (const float*)d_in[5];
  const float* erel = (const float*)d_in[6];
  const float* wn = (const float*)d_in[7];
  const float* lw = (const float*)d_in[8];
  const float* ew = (const float*)d_in[9];
  const float* wih = (const float*)d_in[10];
  const float* whh = (const float*)d_in[11];
  const float* bih = (const float*)d_in[12];
  const float* bhh = (const float*)d_in[13];

  float* out = (float*)d_out;
  float* hist = out;
  float* rels = out + (long)TSTEPS * N_ENTS * H;

  char* p = (char*)d_ws;
  auto alloc = [&](size_t n) { char* r = p; p += (n + 255) & ~(size_t)255; return r; };
  short*    AcatA  = (short*)alloc((size_t)N_ENTS * 512 * 2);
  short*    AcatB  = (short*)alloc((size_t)N_ENTS * 512 * 2);
  short*    rsum   = (short*)alloc((size_t)N_ENTS * 256 * 2);
  unsigned* deg    = (unsigned*)alloc((size_t)N_ENTS * 4);
  unsigned* offd   = (unsigned*)alloc((size_t)(N_ENTS + 1) * 4);
  unsigned* curd   = (unsigned*)alloc((size_t)N_ENTS * 4);
  unsigned* flags  = (unsigned*)alloc((size_t)SCAN_NB * 4);
  int2*     se2    = (int2*)alloc((size_t)NE * 8);
  unsigned* zl     = (unsigned*)alloc((size_t)N_ENTS * 4);
  unsigned* nz     = (unsigned*)alloc(256);
  unsigned* cnt    = (unsigned*)alloc(R2 * 4);
  unsigned* off    = (unsigned*)alloc((R2 + 1) * 4);
  unsigned* cur    = (unsigned*)alloc(R2 * 4);
  int*      se     = (int*)alloc((size_t)NM * 4);
  float*    xinf   = (float*)alloc((size_t)4 * R2 * 256 * 4);
  short*    x_inb  = (short*)alloc((size_t)R2 * H * 2);
  float*    gxbase = (float*)alloc((size_t)R2 * 768 * 4);
  float*    gx     = (float*)alloc((size_t)R2 * 768 * 4);
  float*    gh     = (float*)alloc((size_t)R2 * 768 * 4);
  float*    h0     = (float*)alloc((size_t)R2 * H * 4);
  short*    h0b    = (short*)alloc((size_t)R2 * H * 2);
  short*    erelb  = (short*)alloc((size_t)R2 * H * 2);
  short*    wcatb  = (short*)alloc((size_t)NL * 256 * 512 * 2);
  short*    evt    = (short*)alloc((size_t)NL * H * H * 2);
  short*    wihb   = (short*)alloc((size_t)768 * 512 * 2);
  short*    whhb   = (short*)alloc((size_t)768 * 256 * 2);

  prep_k<<<(int)((PREP_N + 255) / 256), 256, 0, stream>>>(
      wn, lw, ew, wih, whh, erel, wcatb, evt, wihb, whhb, erelb, h0, h0b);
  l2init_k<<<N_ENTS / 4, 256, 0, stream>>>(dyn, AcatA + 256);

  // gx_base = emb_rel @ W_ih[:, :256]^T + b_ih   (step-invariant)
  gemm_k<<<dim3(8, 3), 256, 0, stream>>>(erelb, 256, wihb, 512, R2, 256,
                                         gxbase, 768, bih);

  short* Acur = AcatA;
  short* Anxt = AcatB;

  for (int t = 0; t < TSTEPS; ++t) {
    const int* src_t = src + (long)t * NE;
    const int* dst_t = dst + (long)t * NE;
    const int* ety_t = ety + (long)t * NE;
    const int* re_t  = r2e_ent + (long)t * NM;
    const int* rr_t  = r2e_rel + (long)t * NM;
    float* hist_t = hist + (long)t * N_ENTS * H;
    float* rels_t = rels + (long)t * R2 * H;

    zero_k<<<SCAN_NB, 256, 0, stream>>>(deg, curd, cnt, cur, nz, flags);
    count_k<<<512, 256, 0, stream>>>(rr_t, dst_t, cnt, deg);
    scanall_k<<<SCAN_NB + 1, 256, 0, stream>>>(deg, offd, flags, zl, nz, cnt, off);
    scatterB_k<<<768, 256, 0, stream>>>(rr_t, re_t, off, cur, se,
                                        src_t, dst_t, ety_t, offd, curd, se2);

    // relation mean (split x4) + GRU
    segpart_k<<<R2 * 4, 256, 0, stream>>>(off, se, Acur + 256, xinf);
    segfin_k<<<R2, 256, 0, stream>>>(xinf, cnt, x_inb);
    gru2_k<<<dim3(8, 3, 2), 256, 0, stream>>>(x_inb, h0b, wihb, whhb, gxbase, bhh, gx, gh);
    gate_k<<<R2, 256, 0, stream>>>(gx, gh, h0, h0b, rels_t);

    // layer 0
    agg_first_k<<<N_ENTS / 4, 256, 0, stream>>>(se2, offd, Acur + 256, h0b, rsum, Acur);
    gemm_big<1><<<391, 256, 0, stream>>>(Acur, 512, wcatb, 512,
                                         N_ENTS, 512, nullptr, 0, Anxt + 256, 512);
    fixup_k<0><<<512, 256, 0, stream>>>(nz, zl, Acur + 256, evt, Anxt + 256, nullptr);
    { short* tmp = Acur; Acur = Anxt; Anxt = tmp; }

    // layer 1
    agg_second_k<<<N_ENTS / 4, 256, 0, stream>>>(se2, offd, Acur + 256, rsum, Acur);
    gemm_big<2><<<391, 256, 0, stream>>>(Acur, 512, wcatb + 256 * 512, 512,
                                         N_ENTS, 512, hist_t, 256, Anxt + 256, 512);
    fixup_k<1><<<512, 256, 0, stream>>>(nz, zl, Acur + 256, evt + (long)H * H,
                                        Anxt + 256, hist_t);
    { short* tmp = Acur; Acur = Anxt; Anxt = tmp; }
  }
}

// Round 6
// 1134.041 us; speedup vs baseline: 6.2917x; 1.1507x over previous
//
#include <hip/hip_runtime.h>

#define N_ENTS 50000
#define R2 500
#define H 256
#define TSTEPS 4
#define NE 200000
#define NM 200000
#define NL 2
#define SLOPE 0.22916666666666666f
#define SCAN_NB ((N_ENTS + 255) / 256)   // 196

typedef __attribute__((ext_vector_type(8))) short short8;
typedef __attribute__((ext_vector_type(4))) short short4v;
typedef __attribute__((ext_vector_type(4))) float f32x4;

static __device__ __forceinline__ float b2f(short s) {
  unsigned u = ((unsigned)(unsigned short)s) << 16;
  return __builtin_bit_cast(float, u);
}
static __device__ __forceinline__ short f2b(float f) {
  unsigned u = __builtin_bit_cast(unsigned, f);
  u = (u + 0x7FFFu + ((u >> 16) & 1u)) >> 16;
  return (short)(unsigned short)u;
}

static __device__ __forceinline__ void gload16(const short* g, short* l) {
  __builtin_amdgcn_global_load_lds(
      (const __attribute__((address_space(1))) void*)g,
      (__attribute__((address_space(3))) void*)l, 16, 0, 0);
}

// ---------------- big GEMM: C[M x 256] = A[M x K](bf16) * Bt[256 x K](bf16)^T ----
// 128x256 block, BK=64, 4 waves x (64 rows x 128 cols), global_load_lds staging
// with XOR slot-swizzle (slot ^= row&7) on both source and read sides.
// EPI 1: Obf = bf16(rrelu(acc))                      (ldo)
// EPI 2: l2norm(rrelu(acc)) -> Cf (f32, ldc) and (if Obf) Obf (bf16, ldo)
template<int EPI>
__global__ __launch_bounds__(256, 2)
void gemm_big(const short* __restrict__ A, int lda,
              const short* __restrict__ Bt, int ldb,
              int M, int K,
              float* __restrict__ Cf, int ldc,
              short* __restrict__ Obf, int ldo)
{
  __shared__ short As[128 * 64];
  __shared__ short Bs[256 * 64];
  const int tid = threadIdx.x;
  const int w = tid >> 6, lane = tid & 63;
  const int fr = lane & 15, fq = lane >> 4;
  const int rowh = w >> 1, colh = w & 1;
  const int blk0 = blockIdx.x * 128;
  const int l8 = lane >> 3, s7 = lane & 7;

  f32x4 acc[4][8];
#pragma unroll
  for (int m = 0; m < 4; ++m)
#pragma unroll
    for (int n = 0; n < 8; ++n) {
      acc[m][n][0] = 0.f; acc[m][n][1] = 0.f; acc[m][n][2] = 0.f; acc[m][n][3] = 0.f;
    }

  for (int kc = 0; kc < K; kc += 64) {
    __syncthreads();
#pragma unroll
    for (int i = 0; i < 4; ++i) {          // A tile: 128 rows x 64 k
      int row = w * 32 + i * 8 + l8;
      int grow = min(blk0 + row, M - 1);
      const short* g = A + (size_t)grow * lda + kc + ((s7 ^ (row & 7)) << 3);
      gload16(g, As + w * 2048 + i * 512);
    }
#pragma unroll
    for (int i = 0; i < 8; ++i) {          // B tile: 256 cols x 64 k
      int row = w * 64 + i * 8 + l8;
      const short* g = Bt + (size_t)row * ldb + kc + ((s7 ^ (row & 7)) << 3);
      gload16(g, Bs + w * 4096 + i * 512);
    }
    __syncthreads();
#pragma unroll
    for (int ks = 0; ks < 2; ++ks) {
      const int sl = ((((ks << 2) | fq) ^ s7) << 3);
      short8 a[4], b[8];
#pragma unroll
      for (int m = 0; m < 4; ++m)
        a[m] = *(const short8*)&As[(rowh * 64 + m * 16 + fr) * 64 + sl];
#pragma unroll
      for (int n = 0; n < 8; ++n)
        b[n] = *(const short8*)&Bs[(colh * 128 + n * 16 + fr) * 64 + sl];
#pragma unroll
      for (int m = 0; m < 4; ++m)
#pragma unroll
        for (int n = 0; n < 8; ++n)
          acc[m][n] = __builtin_amdgcn_mfma_f32_16x16x32_bf16(a[m], b[n], acc[m][n], 0, 0, 0);
    }
  }

  if (EPI == 1) {
#pragma unroll
    for (int m = 0; m < 4; ++m)
#pragma unroll
      for (int n = 0; n < 8; ++n) {
        const int col = colh * 128 + n * 16 + fr;
#pragma unroll
        for (int j = 0; j < 4; ++j) {
          const int r = blk0 + rowh * 64 + m * 16 + fq * 4 + j;
          if (r < M) {
            float v = acc[m][n][j];
            v = v >= 0.f ? v : v * SLOPE;
            Obf[(size_t)r * ldo + col] = f2b(v);
          }
        }
      }
  } else {
    float ss[4][4];
#pragma unroll
    for (int m = 0; m < 4; ++m)
#pragma unroll
      for (int j = 0; j < 4; ++j) ss[m][j] = 0.f;
#pragma unroll
    for (int m = 0; m < 4; ++m)
#pragma unroll
      for (int n = 0; n < 8; ++n)
#pragma unroll
        for (int j = 0; j < 4; ++j) {
          float v = acc[m][n][j];
          v = v >= 0.f ? v : v * SLOPE;
          acc[m][n][j] = v;
          ss[m][j] += v * v;
        }
#pragma unroll
    for (int m = 0; m < 4; ++m)
#pragma unroll
      for (int j = 0; j < 4; ++j) {
        float s = ss[m][j];
        s += __shfl_xor(s, 1, 64);
        s += __shfl_xor(s, 2, 64);
        s += __shfl_xor(s, 4, 64);
        s += __shfl_xor(s, 8, 64);
        ss[m][j] = s;                      // half-row (128-col) sum, all lanes
      }
    __syncthreads();                       // compute done; reuse Bs
    float* red = (float*)Bs;               // [0..255]: partials, [256..511]: inv
    if (colh == 0 && fr == 0) {
#pragma unroll
      for (int m = 0; m < 4; ++m)
#pragma unroll
        for (int j = 0; j < 4; ++j)
          red[rowh * 128 + m * 16 + fq * 4 + j] = ss[m][j];
    }
    __syncthreads();
    float inv[4][4];
    if (colh == 1) {
#pragma unroll
      for (int m = 0; m < 4; ++m)
#pragma unroll
        for (int j = 0; j < 4; ++j) {
          float tot = ss[m][j] + red[rowh * 128 + m * 16 + fq * 4 + j];
          inv[m][j] = 1.f / fmaxf(sqrtf(tot), 1e-12f);
        }
      if (fr == 0) {
#pragma unroll
        for (int m = 0; m < 4; ++m)
#pragma unroll
          for (int j = 0; j < 4; ++j)
            red[256 + rowh * 128 + m * 16 + fq * 4 + j] = inv[m][j];
      }
    }
    __syncthreads();
    if (colh == 0) {
#pragma unroll
      for (int m = 0; m < 4; ++m)
#pragma unroll
        for (int j = 0; j < 4; ++j)
          inv[m][j] = red[256 + rowh * 128 + m * 16 + fq * 4 + j];
    }
#pragma unroll
    for (int m = 0; m < 4; ++m)
#pragma unroll
      for (int n = 0; n < 8; ++n) {
        const int col = colh * 128 + n * 16 + fr;
#pragma unroll
        for (int j = 0; j < 4; ++j) {
          const int r = blk0 + rowh * 64 + m * 16 + fq * 4 + j;
          if (r < M) {
            float v = acc[m][n][j] * inv[m][j];
            Cf[(size_t)r * ldc + col] = v;
            if (Obf) Obf[(size_t)r * ldo + col] = f2b(v);
          }
        }
      }
  }
}

// ---------------- small GEMM (init only): C = A * Bt^T (+bias), f32 out ----------
__global__ __launch_bounds__(256)
void gemm_k(const short* __restrict__ A, int lda,
            const short* __restrict__ Bt, int ldb,
            int M, int K,
            float* __restrict__ Cf, int ldc,
            const float* __restrict__ bias)
{
  __shared__ short bt[256 * 72];
  const int tid = threadIdx.x;
  const int w = tid >> 6;
  const int lane = tid & 63;
  const int fr = lane & 15;
  const int fq = lane >> 4;
  const int col0 = blockIdx.y << 8;
  const int rowbase = blockIdx.x * 64 + w * 16;
  const int arow = min(rowbase + fr, M - 1);
  const long abase = (long)arow * lda + fq * 8;

  f32x4 acc[16];
#pragma unroll
  for (int i = 0; i < 16; ++i) { acc[i][0] = 0.f; acc[i][1] = 0.f; acc[i][2] = 0.f; acc[i][3] = 0.f; }

  for (int kc = 0; kc < K; kc += 64) {
    __syncthreads();
    {
      const short* g = Bt + (long)(col0 + tid) * ldb + kc;
      short* l = &bt[tid * 72];
#pragma unroll
      for (int i = 0; i < 8; ++i)
        *(short8*)(l + i * 8) = *(const short8*)(g + i * 8);
    }
    __syncthreads();
#pragma unroll
    for (int ks = 0; ks < 2; ++ks) {
      short8 a = *(const short8*)(A + abase + kc + ks * 32);
#pragma unroll
      for (int ct = 0; ct < 16; ++ct) {
        short8 b = *(const short8*)&bt[(ct * 16 + fr) * 72 + ks * 32 + fq * 8];
        acc[ct] = __builtin_amdgcn_mfma_f32_16x16x32_bf16(a, b, acc[ct], 0, 0, 0);
      }
    }
  }

  const int crow = rowbase + fq * 4;
#pragma unroll
  for (int ct = 0; ct < 16; ++ct) {
    const int gcol = col0 + ct * 16 + fr;
#pragma unroll
    for (int j = 0; j < 4; ++j) {
      const int r = crow + j;
      if (r < M) {
        float v = acc[ct][j];
        if (bias) v += bias[gcol];
        Cf[(long)r * ldc + gcol] = v;
      }
    }
  }
}

// ---------------- fused GRU GEMMs: z=0 -> gx, z=1 -> gh ---------------------------
__global__ __launch_bounds__(256)
void gru2_k(const short* __restrict__ x_inb, const short* __restrict__ h0b,
            const short* __restrict__ wihb, const short* __restrict__ whhb,
            const float* __restrict__ gxbase, const float* __restrict__ bhh,
            float* __restrict__ gx, float* __restrict__ gh)
{
  const short* A;  const short* Bt;  int ldb;
  float* Cf;  const float* Cadd;  const float* bias;
  if (blockIdx.z == 0) { A = x_inb; Bt = wihb + 256; ldb = 512; Cf = gx; Cadd = gxbase; bias = nullptr; }
  else                 { A = h0b;   Bt = whhb;       ldb = 256; Cf = gh; Cadd = nullptr; bias = bhh; }

  __shared__ short bt[256 * 72];
  const int tid = threadIdx.x;
  const int w = tid >> 6;
  const int lane = tid & 63;
  const int fr = lane & 15;
  const int fq = lane >> 4;
  const int col0 = blockIdx.y << 8;
  const int rowbase = blockIdx.x * 64 + w * 16;
  const int arow = min(rowbase + fr, R2 - 1);
  const long abase = (long)arow * 256 + fq * 8;

  f32x4 acc[16];
#pragma unroll
  for (int i = 0; i < 16; ++i) { acc[i][0] = 0.f; acc[i][1] = 0.f; acc[i][2] = 0.f; acc[i][3] = 0.f; }

  for (int kc = 0; kc < 256; kc += 64) {
    __syncthreads();
    {
      const short* g = Bt + (long)(col0 + tid) * ldb + kc;
      short* l = &bt[tid * 72];
#pragma unroll
      for (int i = 0; i < 8; ++i)
        *(short8*)(l + i * 8) = *(const short8*)(g + i * 8);
    }
    __syncthreads();
#pragma unroll
    for (int ks = 0; ks < 2; ++ks) {
      short8 a = *(const short8*)(A + abase + kc + ks * 32);
#pragma unroll
      for (int ct = 0; ct < 16; ++ct) {
        short8 b = *(const short8*)&bt[(ct * 16 + fr) * 72 + ks * 32 + fq * 8];
        acc[ct] = __builtin_amdgcn_mfma_f32_16x16x32_bf16(a, b, acc[ct], 0, 0, 0);
      }
    }
  }

  const int crow = rowbase + fq * 4;
#pragma unroll
  for (int ct = 0; ct < 16; ++ct) {
    const int gcol = col0 + ct * 16 + fr;
#pragma unroll
    for (int j = 0; j < 4; ++j) {
      const int r = crow + j;
      if (r < R2) {
        float v = acc[ct][j];
        if (Cadd) v += Cadd[(long)r * 768 + gcol];
        if (bias) v += bias[gcol];
        Cf[(long)r * 768 + gcol] = v;
      }
    }
  }
}

// ---------------- init: h = l2norm(dynamic_emb) -> bf16 into Acat halfB ----------
__global__ __launch_bounds__(256)
void l2init_k(const float* __restrict__ de, short* __restrict__ hb)
{
  const int w = threadIdx.x >> 6, lane = threadIdx.x & 63;
  const int row = blockIdx.x * 4 + w;
  f32x4 v = *(const f32x4*)&de[(long)row * H + lane * 4];
  float s = v[0]*v[0] + v[1]*v[1] + v[2]*v[2] + v[3]*v[3];
  s += __shfl_xor(s, 1, 64);  s += __shfl_xor(s, 2, 64);
  s += __shfl_xor(s, 4, 64);  s += __shfl_xor(s, 8, 64);
  s += __shfl_xor(s, 16, 64); s += __shfl_xor(s, 32, 64);
  float sc = 1.f / fmaxf(sqrtf(s), 1e-12f);
  short4v o;
  o[0] = f2b(v[0]*sc); o[1] = f2b(v[1]*sc); o[2] = f2b(v[2]*sc); o[3] = f2b(v[3]*sc);
  *(short4v*)&hb[(long)row * 512 + lane * 4] = o;
}

// ---------------- merged weight prep ---------------------------------------------
__global__ __launch_bounds__(256)
void prep_k(const float* __restrict__ wn, const float* __restrict__ lw,
            const float* __restrict__ ew, const float* __restrict__ wih,
            const float* __restrict__ whh, const float* __restrict__ erel,
            short* __restrict__ wcatb, short* __restrict__ evt,
            short* __restrict__ wihb, short* __restrict__ whhb,
            short* __restrict__ erelb, float* __restrict__ h0, short* __restrict__ h0b)
{
  long i = (long)blockIdx.x * 256 + threadIdx.x;
  if (i < (long)NL * 256 * 512) {
    int l = (int)(i / (256 * 512));
    int rem = (int)(i % (256 * 512));
    int j = rem / 512;
    int k = rem % 512;
    float v = (k < 256) ? wn[(long)l * 65536 + k * 256 + j]
                        : lw[(long)l * 65536 + (k - 256) * 256 + j];
    wcatb[i] = f2b(v);
    return;
  }
  i -= (long)NL * 256 * 512;
  if (i < (long)NL * 65536) {
    int l = (int)(i >> 16);
    int rem = (int)(i & 65535);
    int c = rem >> 8, k = rem & 255;
    evt[i] = f2b(ew[(long)l * 65536 + k * 256 + c]);
    return;
  }
  i -= (long)NL * 65536;
  if (i < 768 * 512) { wihb[i] = f2b(wih[i]); return; }
  i -= 768 * 512;
  if (i < 768 * 256) { whhb[i] = f2b(whh[i]); return; }
  i -= 768 * 256;
  if (i < (long)R2 * H) {
    float v = erel[i];
    erelb[i] = f2b(v); h0[i] = v; h0b[i] = f2b(v);
  }
}
#define PREP_N ((long)NL * 256 * 512 + (long)NL * 65536 + 768 * 512 + 768 * 256 + (long)R2 * H)

// ---------------- batched zero of all 4 steps' counters ---------------------------
__global__ __launch_bounds__(256)
void zero_all_k(unsigned* __restrict__ deg, unsigned* __restrict__ curd,
                unsigned* __restrict__ cnt, unsigned* __restrict__ cur,
                unsigned* __restrict__ nz, unsigned* __restrict__ flags)
{
  const int t = blockIdx.y;
  int i = blockIdx.x * 256 + threadIdx.x;
  if (i < N_ENTS) { deg[(long)t * N_ENTS + i] = 0u; curd[(long)t * N_ENTS + i] = 0u; }
  if (i < R2) { cnt[t * R2 + i] = 0u; cur[t * R2 + i] = 0u; }
  if (i < SCAN_NB) flags[t * SCAN_NB + i] = 0u;
  if (i == 0) nz[t] = 0u;
}

// ---------------- batched counting: rel histogram (LDS) + dst degree --------------
__global__ __launch_bounds__(256)
void count_all_k(const int* __restrict__ relA, const int* __restrict__ dstA,
                 unsigned* __restrict__ cntA, unsigned* __restrict__ degA)
{
  const int t = blockIdx.y;
  const int* rel = relA + (long)t * NM;
  const int* dstv = dstA + (long)t * NE;
  unsigned* cnt = cntA + t * R2;
  unsigned* deg = degA + (long)t * N_ENTS;
  __shared__ unsigned lh[R2];
  for (int i = threadIdx.x; i < R2; i += 256) lh[i] = 0;
  __syncthreads();
  for (long i = (long)blockIdx.x * 256 + threadIdx.x; i < NM; i += (long)gridDim.x * 256)
    atomicAdd(&lh[rel[i]], 1u);
  for (long i = (long)blockIdx.x * 256 + threadIdx.x; i < NE; i += (long)gridDim.x * 256)
    atomicAdd(&deg[dstv[i]], 1u);
  __syncthreads();
  for (int i = threadIdx.x; i < R2; i += 256)
    if (lh[i]) atomicAdd(&cnt[i], lh[i]);
}

// ---------------- batched scans: decoupled lookback (deg) + rel prefix ------------
__global__ __launch_bounds__(256)
void scan_all_k(const unsigned* __restrict__ degA, unsigned* __restrict__ offdA,
                unsigned* __restrict__ flagsA,
                unsigned* __restrict__ zlA, unsigned* __restrict__ nzA,
                const unsigned* __restrict__ cntA, unsigned* __restrict__ offA)
{
  const int t = blockIdx.y;
  if (blockIdx.x == SCAN_NB) {           // rel-histogram prefix (512-slot HS)
    const unsigned* cnt = cntA + t * R2;
    unsigned* off = offA + t * (R2 + 1);
    __shared__ unsigned sr[512];
    const int tt = threadIdx.x;
    sr[tt] = (tt < R2) ? cnt[tt] : 0u;
    sr[tt + 256] = (tt + 256 < R2) ? cnt[tt + 256] : 0u;
    __syncthreads();
#pragma unroll
    for (int d = 1; d < 512; d <<= 1) {
      unsigned v0 = (tt >= d) ? sr[tt - d] : 0u;
      unsigned v1 = (tt + 256 >= d) ? sr[tt + 256 - d] : 0u;
      __syncthreads();
      sr[tt] += v0; sr[tt + 256] += v1;
      __syncthreads();
    }
    if (tt < R2) off[tt] = (tt == 0) ? 0u : sr[tt - 1];
    if (tt + 256 < R2) off[tt + 256] = sr[tt + 255];
    if (tt == 0) off[R2] = sr[R2 - 1];
    return;
  }
  const unsigned* deg = degA + (long)t * N_ENTS;
  unsigned* offd = offdA + (long)t * (N_ENTS + 1);
  unsigned* flags = flagsA + t * SCAN_NB;
  unsigned* zl = zlA + (long)t * N_ENTS;
  unsigned* nz = nzA + t;
  __shared__ unsigned s[256];
  __shared__ unsigned sexc;
  const int tid = threadIdx.x;
  const int b = blockIdx.x;
  const int i = b * 256 + tid;
  unsigned v = (i < N_ENTS) ? deg[i] : 0u;
  s[tid] = v;
  __syncthreads();
#pragma unroll
  for (int d = 1; d < 256; d <<= 1) {
    unsigned t2 = (tid >= d) ? s[tid - d] : 0u;
    __syncthreads();
    s[tid] += t2;
    __syncthreads();
  }
  const unsigned total = s[255];
  if (tid == 0) {
    if (b == 0) {
      __threadfence();
      atomicExch(&flags[0], (2u << 30) | total);
      sexc = 0u;
    } else {
      __threadfence();
      atomicExch(&flags[b], (1u << 30) | total);
      unsigned exc = 0u;
      int j = b - 1;
      while (j >= 0) {
        unsigned f;
        do { f = atomicAdd(&flags[j], 0u); } while ((f >> 30) == 0u);
        exc += f & 0x3FFFFFFFu;
        if ((f >> 30) == 2u) break;
        --j;
      }
      __threadfence();
      atomicExch(&flags[b], (2u << 30) | (exc + total));
      sexc = exc;
    }
  }
  __syncthreads();
  const unsigned exc = sexc;
  if (i < N_ENTS) {
    offd[i] = exc + s[tid] - v;
    if (v == 0u) { unsigned p2 = atomicAdd(nz, 1u); zl[p2] = i; }
  }
  if (i == 0) offd[N_ENTS] = NE;
}

// ---------------- batched scatter: rel-CSR (ent) + dst-CSR (src,etype int2) ------
__global__ __launch_bounds__(256)
void scatter_all_k(const int* __restrict__ relA, const int* __restrict__ entA,
                   const unsigned* __restrict__ offA, unsigned* __restrict__ curA,
                   int* __restrict__ seA,
                   const int* __restrict__ srcA, const int* __restrict__ dstA,
                   const int* __restrict__ etA, const unsigned* __restrict__ offdA,
                   unsigned* __restrict__ curdA, int2* __restrict__ se2A)
{
  const int t = blockIdx.y;
  if (blockIdx.x < 256) {
    const int* rel = relA + (long)t * NM;
    const int* ent = entA + (long)t * NM;
    const unsigned* off = offA + t * (R2 + 1);
    unsigned* cur = curA + t * R2;
    int* se = seA + (long)t * NM;
    for (long i = (long)blockIdx.x * 256 + threadIdx.x; i < NM; i += 256l * 256) {
      int r = rel[i];
      unsigned p = atomicAdd(&cur[r], 1u);
      se[off[r] + p] = ent[i];
    }
  } else {
    const int* srcv = srcA + (long)t * NE;
    const int* dstv = dstA + (long)t * NE;
    const int* etv = etA + (long)t * NE;
    const unsigned* offd = offdA + (long)t * (N_ENTS + 1);
    unsigned* curd = curdA + (long)t * N_ENTS;
    int2* se2 = se2A + (long)t * NE;
    for (long i = (long)(blockIdx.x - 256) * 256 + threadIdx.x; i < NE; i += 512l * 256) {
      int d = dstv[i];
      unsigned p = atomicAdd(&curd[d], 1u);
      se2[offd[d] + p] = make_int2(srcv[i], etv[i]);
    }
  }
}

// ---------------- segment-sum partials (x4 split), 16B/lane, 2 entries/wave -------
__global__ __launch_bounds__(256)
void segpart_k(const unsigned* __restrict__ off, const int* __restrict__ se,
               const short* __restrict__ hb, float* __restrict__ xinf)
{
  __shared__ float red[4][256];
  const int r = blockIdx.x >> 2, s = blockIdx.x & 3;
  const int w = threadIdx.x >> 6, lane = threadIdx.x & 63;
  const int half = lane >> 5, sl = lane & 31;
  const unsigned b = off[r], e = off[r + 1], len = e - b;
  const unsigned lo = b + ((len * s) >> 2), hi = b + ((len * (s + 1)) >> 2);
  float a[8];
#pragma unroll
  for (int j = 0; j < 8; ++j) a[j] = 0.f;
  unsigned i = lo + w * 2;
  for (; i + 10 <= hi; i += 16) {          // two pairs per wave per iter
    int e0 = se[i + half];
    int e1 = se[i + 8 + half];
    short8 h0v = *(const short8*)&hb[(long)e0 * 512 + sl * 8];
    short8 h1v = *(const short8*)&hb[(long)e1 * 512 + sl * 8];
#pragma unroll
    for (int j = 0; j < 8; ++j) a[j] += b2f(h0v[j]) + b2f(h1v[j]);
  }
  for (; i + 2 <= hi; i += 8) {
    int e0 = se[i + half];
    short8 hv = *(const short8*)&hb[(long)e0 * 512 + sl * 8];
#pragma unroll
    for (int j = 0; j < 8; ++j) a[j] += b2f(hv[j]);
  }
  if (i + half < hi) {
    int e0 = se[i + half];
    short8 hv = *(const short8*)&hb[(long)e0 * 512 + sl * 8];
#pragma unroll
    for (int j = 0; j < 8; ++j) a[j] += b2f(hv[j]);
  }
#pragma unroll
  for (int j = 0; j < 8; ++j) a[j] += __shfl_xor(a[j], 32, 64);
  if (half == 0) {
#pragma unroll
    for (int j = 0; j < 8; ++j) red[w][sl * 8 + j] = a[j];
  }
  __syncthreads();
  const int t = threadIdx.x;
  xinf[((long)s * R2 + r) * 256 + t] =
      (red[0][t] + red[1][t]) + (red[2][t] + red[3][t]);
}

__global__ __launch_bounds__(256)
void segfin_k(const float* __restrict__ xinf, const unsigned* __restrict__ cnt,
              short* __restrict__ x_inb)
{
  const int r = blockIdx.x, tid = threadIdx.x;
  float v = xinf[(long)r * 256 + tid] + xinf[((long)R2 + r) * 256 + tid]
          + xinf[((long)2 * R2 + r) * 256 + tid] + xinf[((long)3 * R2 + r) * 256 + tid];
  v /= fmaxf((float)cnt[r], 1.f);
  x_inb[(long)r * 256 + tid] = f2b(v);
}

// ---------------- GRU gates ------------------------------------------------------
__global__ __launch_bounds__(256)
void gate_k(const float* __restrict__ gx, const float* __restrict__ gh,
            float* __restrict__ h0, short* __restrict__ h0b, float* __restrict__ relout)
{
  __shared__ float red[4];
  const int r = blockIdx.x, c = threadIdx.x;
  const long b = (long)r * 768;
  float xr = gx[b + c], xz = gx[b + 256 + c], xn = gx[b + 512 + c];
  float hr = gh[b + c], hz = gh[b + 256 + c], hn = gh[b + 512 + c];
  float rr = 1.f / (1.f + expf(-(xr + hr)));
  float z  = 1.f / (1.f + expf(-(xz + hz)));
  float nn = tanhf(xn + rr * hn);
  float v = (1.f - z) * nn + z * h0[(long)r * H + c];
  float s = v * v;
  s += __shfl_xor(s, 1, 64);  s += __shfl_xor(s, 2, 64);
  s += __shfl_xor(s, 4, 64);  s += __shfl_xor(s, 8, 64);
  s += __shfl_xor(s, 16, 64); s += __shfl_xor(s, 32, 64);
  const int w = c >> 6;
  if ((c & 63) == 0) red[w] = s;
  __syncthreads();
  float tot = (red[0] + red[1]) + (red[2] + red[3]);
  float sc = 1.f / fmaxf(sqrtf(tot), 1e-12f);
  v *= sc;
  h0[(long)r * H + c] = v;
  h0b[(long)r * H + c] = f2b(v);
  relout[(long)r * H + c] = v;
}

// ---------------- layer-0 aggregation: 16B/lane, 2 edges/wave, emits rsum --------
__global__ __launch_bounds__(256)
void agg_first_k(const int2* __restrict__ se2, const unsigned* __restrict__ offd,
                 const short* __restrict__ hb, const short* __restrict__ h0b,
                 short* __restrict__ rsum, short* __restrict__ acat)
{
  const int w = threadIdx.x >> 6, lane = threadIdx.x & 63;
  const int half = lane >> 5, sl = lane & 31;
  const int row = blockIdx.x * 4 + w;
  const unsigned b = offd[row], e = offd[row + 1];
  float ha[8], ra[8];
#pragma unroll
  for (int j = 0; j < 8; ++j) { ha[j] = 0.f; ra[j] = 0.f; }
  unsigned i = b;
  for (; i + 4 <= e; i += 4) {
    int2 e0 = se2[i + half];
    int2 e1 = se2[i + 2 + half];
    short8 h0v = *(const short8*)&hb[(long)e0.x * 512 + sl * 8];
    short8 r0v = *(const short8*)&h0b[(long)e0.y * 256 + sl * 8];
    short8 h1v = *(const short8*)&hb[(long)e1.x * 512 + sl * 8];
    short8 r1v = *(const short8*)&h0b[(long)e1.y * 256 + sl * 8];
#pragma unroll
    for (int j = 0; j < 8; ++j) {
      ha[j] += b2f(h0v[j]) + b2f(h1v[j]);
      ra[j] += b2f(r0v[j]) + b2f(r1v[j]);
    }
  }
  for (; i < e; i += 2) {
    if (i + half < e) {
      int2 e0 = se2[i + half];
      short8 hv = *(const short8*)&hb[(long)e0.x * 512 + sl * 8];
      short8 rv = *(const short8*)&h0b[(long)e0.y * 256 + sl * 8];
#pragma unroll
      for (int j = 0; j < 8; ++j) { ha[j] += b2f(hv[j]); ra[j] += b2f(rv[j]); }
    }
  }
#pragma unroll
  for (int j = 0; j < 8; ++j) {
    ha[j] += __shfl_xor(ha[j], 32, 64);
    ra[j] += __shfl_xor(ra[j], 32, 64);
  }
  if (half == 0) {
    const float nm = 1.f / fmaxf((float)(e - b), 1.f);
    short8 rs, o;
#pragma unroll
    for (int j = 0; j < 8; ++j) {
      rs[j] = f2b(ra[j]);
      o[j] = f2b((ha[j] + ra[j]) * nm);
    }
    *(short8*)&rsum[(long)row * 256 + sl * 8] = rs;
    *(short8*)&acat[(long)row * 512 + sl * 8] = o;
  }
}

// ---------------- layer-1 aggregation: reuses rsum, 16B/lane, 2 edges/wave -------
__global__ __launch_bounds__(256)
void agg_second_k(const int2* __restrict__ se2, const unsigned* __restrict__ offd,
                  const short* __restrict__ hb, const short* __restrict__ rsum,
                  short* __restrict__ acat)
{
  const int w = threadIdx.x >> 6, lane = threadIdx.x & 63;
  const int half = lane >> 5, sl = lane & 31;
  const int row = blockIdx.x * 4 + w;
  const unsigned b = offd[row], e = offd[row + 1];
  float ha[8];
#pragma unroll
  for (int j = 0; j < 8; ++j) ha[j] = 0.f;
  unsigned i = b;
  for (; i + 4 <= e; i += 4) {
    int2 e0 = se2[i + half];
    int2 e1 = se2[i + 2 + half];
    short8 h0v = *(const short8*)&hb[(long)e0.x * 512 + sl * 8];
    short8 h1v = *(const short8*)&hb[(long)e1.x * 512 + sl * 8];
#pragma unroll
    for (int j = 0; j < 8; ++j) ha[j] += b2f(h0v[j]) + b2f(h1v[j]);
  }
  for (; i < e; i += 2) {
    if (i + half < e) {
      int2 e0 = se2[i + half];
      short8 hv = *(const short8*)&hb[(long)e0.x * 512 + sl * 8];
#pragma unroll
      for (int j = 0; j < 8; ++j) ha[j] += b2f(hv[j]);
    }
  }
#pragma unroll
  for (int j = 0; j < 8; ++j) ha[j] += __shfl_xor(ha[j], 32, 64);
  if (half == 0) {
    short8 rs = *(const short8*)&rsum[(long)row * 256 + sl * 8];
    const float nm = 1.f / fmaxf((float)(e - b), 1.f);
    short8 o;
#pragma unroll
    for (int j = 0; j < 8; ++j) o[j] = f2b((ha[j] + b2f(rs[j])) * nm);
    *(short8*)&acat[(long)row * 512 + sl * 8] = o;
  }
}

// ---------------- deg==0 fixup: row = rrelu(hc @ evolve_w) (+l2norm if final) ----
template<int FINAL>
__global__ __launch_bounds__(256)
void fixup_k(const unsigned* __restrict__ nz, const unsigned* __restrict__ zl,
             const short* __restrict__ hbc, const short* __restrict__ evt,
             short* __restrict__ hbn, float* __restrict__ outF)
{
  __shared__ float x[H];
  __shared__ float red[4];
  const unsigned n = *nz;
  const short* wrow = evt + (long)threadIdx.x * 256;
  for (unsigned zi = blockIdx.x; zi < n; zi += gridDim.x) {
    const int row = zl[zi];
    __syncthreads();
    x[threadIdx.x] = b2f(hbc[(long)row * 512 + threadIdx.x]);
    __syncthreads();
    float acc = 0.f;
#pragma unroll
    for (int k0 = 0; k0 < H; k0 += 8) {
      short8 wv = *(const short8*)&wrow[k0];
      acc += x[k0]     * b2f(wv[0]) + x[k0 + 1] * b2f(wv[1])
           + x[k0 + 2] * b2f(wv[2]) + x[k0 + 3] * b2f(wv[3])
           + x[k0 + 4] * b2f(wv[4]) + x[k0 + 5] * b2f(wv[5])
           + x[k0 + 6] * b2f(wv[6]) + x[k0 + 7] * b2f(wv[7]);
    }
    float v = acc >= 0.f ? acc : acc * SLOPE;
    if (FINAL) {
      float s = v * v;
      s += __shfl_xor(s, 1, 64);  s += __shfl_xor(s, 2, 64);
      s += __shfl_xor(s, 4, 64);  s += __shfl_xor(s, 8, 64);
      s += __shfl_xor(s, 16, 64); s += __shfl_xor(s, 32, 64);
      const int w = threadIdx.x >> 6;
      if ((threadIdx.x & 63) == 0) red[w] = s;
      __syncthreads();
      float tot = (red[0] + red[1]) + (red[2] + red[3]);
      float sc = 1.f / fmaxf(sqrtf(tot), 1e-12f);
      v *= sc;
      outF[(long)row * H + threadIdx.x] = v;
    }
    if (hbn) hbn[(long)row * 512 + threadIdx.x] = f2b(v);
  }
}

// =================================================================================
extern "C" void kernel_launch(void* const* d_in, const int* in_sizes, int n_in,
                              void* d_out, int out_size, void* d_ws, size_t ws_size,
                              hipStream_t stream)
{
  (void)in_sizes; (void)n_in; (void)out_size; (void)ws_size;
  const int* src = (const int*)d_in[0];
  const int* dst = (const int*)d_in[1];
  const int* ety = (const int*)d_in[2];
  const int* r2e_ent = (const int*)d_in[3];
  const int* r2e_rel = (const int*)d_in[4];
  const float* dyn = (const float*)d_in[5];
  const float* erel = (const float*)d_in[6];
  const float* wn = (const float*)d_in[7];
  const float* lw = (const float*)d_in[8];
  const float* ew = (const float*)d_in[9];
  const float* wih = (const float*)d_in[10];
  const float* whh = (const float*)d_in[11];
  const float* bih = (const float*)d_in[12];
  const float* bhh = (const float*)d_in[13];

  float* out = (float*)d_out;
  float* hist = out;
  float* rels = out + (long)TSTEPS * N_ENTS * H;

  char* p = (char*)d_ws;
  auto alloc = [&](size_t n) { char* r = p; p += (n + 255) & ~(size_t)255; return r; };
  short*    AcatA  = (short*)alloc((size_t)N_ENTS * 512 * 2);
  short*    AcatB  = (short*)alloc((size_t)N_ENTS * 512 * 2);
  short*    rsum   = (short*)alloc((size_t)N_ENTS * 256 * 2);
  unsigned* deg    = (unsigned*)alloc((size_t)TSTEPS * N_ENTS * 4);
  unsigned* offd   = (unsigned*)alloc((size_t)TSTEPS * (N_ENTS + 1) * 4);
  unsigned* curd   = (unsigned*)alloc((size_t)TSTEPS * N_ENTS * 4);
  unsigned* flags  = (unsigned*)alloc((size_t)TSTEPS * SCAN_NB * 4);
  int2*     se2    = (int2*)alloc((size_t)TSTEPS * NE * 8);
  unsigned* zl     = (unsigned*)alloc((size_t)TSTEPS * N_ENTS * 4);
  unsigned* nz     = (unsigned*)alloc(256);
  unsigned* cnt    = (unsigned*)alloc((size_t)TSTEPS * R2 * 4);
  unsigned* off    = (unsigned*)alloc((size_t)TSTEPS * (R2 + 1) * 4);
  unsigned* cur    = (unsigned*)alloc((size_t)TSTEPS * R2 * 4);
  int*      se     = (int*)alloc((size_t)TSTEPS * NM * 4);
  float*    xinf   = (float*)alloc((size_t)4 * R2 * 256 * 4);
  short*    x_inb  = (short*)alloc((size_t)R2 * H * 2);
  float*    gxbase = (float*)alloc((size_t)R2 * 768 * 4);
  float*    gx     = (float*)alloc((size_t)R2 * 768 * 4);
  float*    gh     = (float*)alloc((size_t)R2 * 768 * 4);
  float*    h0     = (float*)alloc((size_t)R2 * H * 4);
  short*    h0b    = (short*)alloc((size_t)R2 * H * 2);
  short*    erelb  = (short*)alloc((size_t)R2 * H * 2);
  short*    wcatb  = (short*)alloc((size_t)NL * 256 * 512 * 2);
  short*    evt    = (short*)alloc((size_t)NL * H * H * 2);
  short*    wihb   = (short*)alloc((size_t)768 * 512 * 2);
  short*    whhb   = (short*)alloc((size_t)768 * 256 * 2);

  prep_k<<<(int)((PREP_N + 255) / 256), 256, 0, stream>>>(
      wn, lw, ew, wih, whh, erel, wcatb, evt, wihb, whhb, erelb, h0, h0b);
  l2init_k<<<N_ENTS / 4, 256, 0, stream>>>(dyn, AcatA + 256);

  // gx_base = emb_rel @ W_ih[:, :256]^T + b_ih   (step-invariant)
  gemm_k<<<dim3(8, 3), 256, 0, stream>>>(erelb, 256, wihb, 512, R2, 256,
                                         gxbase, 768, bih);

  // ---- batched CSR build for ALL steps (depends only on int inputs) -------------
  zero_all_k<<<dim3(SCAN_NB, TSTEPS), 256, 0, stream>>>(deg, curd, cnt, cur, nz, flags);
  count_all_k<<<dim3(512, TSTEPS), 256, 0, stream>>>(r2e_rel, dst, cnt, deg);
  scan_all_k<<<dim3(SCAN_NB + 1, TSTEPS), 256, 0, stream>>>(deg, offd, flags, zl, nz, cnt, off);
  scatter_all_k<<<dim3(768, TSTEPS), 256, 0, stream>>>(r2e_rel, r2e_ent, off, cur, se,
                                                       src, dst, ety, offd, curd, se2);

  short* Acur = AcatA;
  short* Anxt = AcatB;

  for (int t = 0; t < TSTEPS; ++t) {
    float* hist_t = hist + (long)t * N_ENTS * H;
    float* rels_t = rels + (long)t * R2 * H;
    const unsigned* off_t  = off + t * (R2 + 1);
    const int*      se_t   = se + (long)t * NM;
    const unsigned* offd_t = offd + (long)t * (N_ENTS + 1);
    const int2*     se2_t  = se2 + (long)t * NE;
    const unsigned* cnt_t  = cnt + t * R2;
    const unsigned* nz_t   = nz + t;
    const unsigned* zl_t   = zl + (long)t * N_ENTS;

    // relation mean (split x4) + GRU
    segpart_k<<<R2 * 4, 256, 0, stream>>>(off_t, se_t, Acur + 256, xinf);
    segfin_k<<<R2, 256, 0, stream>>>(xinf, cnt_t, x_inb);
    gru2_k<<<dim3(8, 3, 2), 256, 0, stream>>>(x_inb, h0b, wihb, whhb, gxbase, bhh, gx, gh);
    gate_k<<<R2, 256, 0, stream>>>(gx, gh, h0, h0b, rels_t);

    // layer 0
    agg_first_k<<<N_ENTS / 4, 256, 0, stream>>>(se2_t, offd_t, Acur + 256, h0b, rsum, Acur);
    gemm_big<1><<<391, 256, 0, stream>>>(Acur, 512, wcatb, 512,
                                         N_ENTS, 512, nullptr, 0, Anxt + 256, 512);
    fixup_k<0><<<512, 256, 0, stream>>>(nz_t, zl_t, Acur + 256, evt, Anxt + 256, nullptr);
    { short* tmp = Acur; Acur = Anxt; Anxt = tmp; }

    // layer 1
    agg_second_k<<<N_ENTS / 4, 256, 0, stream>>>(se2_t, offd_t, Acur + 256, rsum, Acur);
    const bool last = (t == TSTEPS - 1);
    gemm_big<2><<<391, 256, 0, stream>>>(Acur, 512, wcatb + 256 * 512, 512,
                                         N_ENTS, 512, hist_t, 256,
                                         last ? nullptr : (Anxt + 256), 512);
    fixup_k<1><<<512, 256, 0, stream>>>(nz_t, zl_t, Acur + 256, evt + (long)H * H,
                                        last ? nullptr : (Anxt + 256), hist_t);
    { short* tmp = Acur; Acur = Anxt; Anxt = tmp; }
  }
}

// Round 7
// 1022.355 us; speedup vs baseline: 6.9790x; 1.1092x over previous
//
#include <hip/hip_runtime.h>

#define N_ENTS 50000
#define R2 500
#define H 256
#define TSTEPS 4
#define NE 200000
#define NM 200000
#define NL 2
#define SLOPE 0.22916666666666666f
#define SCAN_NB ((N_ENTS + 255) / 256)   // 196
#define CPAD 16                           // one cache line per counter

typedef __attribute__((ext_vector_type(8))) short short8;
typedef __attribute__((ext_vector_type(4))) short short4v;
typedef __attribute__((ext_vector_type(4))) float f32x4;

static __device__ __forceinline__ float b2f(short s) {
  unsigned u = ((unsigned)(unsigned short)s) << 16;
  return __builtin_bit_cast(float, u);
}
static __device__ __forceinline__ short f2b(float f) {
  unsigned u = __builtin_bit_cast(unsigned, f);
  u = (u + 0x7FFFu + ((u >> 16) & 1u)) >> 16;
  return (short)(unsigned short)u;
}

static __device__ __forceinline__ void gload16(const short* g, short* l) {
  __builtin_amdgcn_global_load_lds(
      (const __attribute__((address_space(1))) void*)g,
      (__attribute__((address_space(3))) void*)l, 16, 0, 0);
}

// ---------------- big GEMM: C[M x 256] = A[M x K](bf16) * Bt[256 x K](bf16)^T ----
// 128x256 block, BK=64, 4 waves x (64 rows x 128 cols), global_load_lds staging
// with XOR slot-swizzle (slot ^= row&7) on both source and read sides.
// EPI 1: Obf = bf16(rrelu(acc))                      (ldo)
// EPI 2: l2norm(rrelu(acc)) -> Cf (f32, ldc) and (if Obf) Obf (bf16, ldo)
template<int EPI>
__global__ __launch_bounds__(256, 2)
void gemm_big(const short* __restrict__ A, int lda,
              const short* __restrict__ Bt, int ldb,
              int M, int K,
              float* __restrict__ Cf, int ldc,
              short* __restrict__ Obf, int ldo)
{
  __shared__ short As[128 * 64];
  __shared__ short Bs[256 * 64];
  const int tid = threadIdx.x;
  const int w = tid >> 6, lane = tid & 63;
  const int fr = lane & 15, fq = lane >> 4;
  const int rowh = w >> 1, colh = w & 1;
  const int blk0 = blockIdx.x * 128;
  const int l8 = lane >> 3, s7 = lane & 7;

  f32x4 acc[4][8];
#pragma unroll
  for (int m = 0; m < 4; ++m)
#pragma unroll
    for (int n = 0; n < 8; ++n) {
      acc[m][n][0] = 0.f; acc[m][n][1] = 0.f; acc[m][n][2] = 0.f; acc[m][n][3] = 0.f;
    }

  for (int kc = 0; kc < K; kc += 64) {
    __syncthreads();
#pragma unroll
    for (int i = 0; i < 4; ++i) {          // A tile: 128 rows x 64 k
      int row = w * 32 + i * 8 + l8;
      int grow = min(blk0 + row, M - 1);
      const short* g = A + (size_t)grow * lda + kc + ((s7 ^ (row & 7)) << 3);
      gload16(g, As + w * 2048 + i * 512);
    }
#pragma unroll
    for (int i = 0; i < 8; ++i) {          // B tile: 256 cols x 64 k
      int row = w * 64 + i * 8 + l8;
      const short* g = Bt + (size_t)row * ldb + kc + ((s7 ^ (row & 7)) << 3);
      gload16(g, Bs + w * 4096 + i * 512);
    }
    __syncthreads();
#pragma unroll
    for (int ks = 0; ks < 2; ++ks) {
      const int sl = ((((ks << 2) | fq) ^ s7) << 3);
      short8 a[4], b[8];
#pragma unroll
      for (int m = 0; m < 4; ++m)
        a[m] = *(const short8*)&As[(rowh * 64 + m * 16 + fr) * 64 + sl];
#pragma unroll
      for (int n = 0; n < 8; ++n)
        b[n] = *(const short8*)&Bs[(colh * 128 + n * 16 + fr) * 64 + sl];
#pragma unroll
      for (int m = 0; m < 4; ++m)
#pragma unroll
        for (int n = 0; n < 8; ++n)
          acc[m][n] = __builtin_amdgcn_mfma_f32_16x16x32_bf16(a[m], b[n], acc[m][n], 0, 0, 0);
    }
  }

  if (EPI == 1) {
#pragma unroll
    for (int m = 0; m < 4; ++m)
#pragma unroll
      for (int n = 0; n < 8; ++n) {
        const int col = colh * 128 + n * 16 + fr;
#pragma unroll
        for (int j = 0; j < 4; ++j) {
          const int r = blk0 + rowh * 64 + m * 16 + fq * 4 + j;
          if (r < M) {
            float v = acc[m][n][j];
            v = v >= 0.f ? v : v * SLOPE;
            Obf[(size_t)r * ldo + col] = f2b(v);
          }
        }
      }
  } else {
    float ss[4][4];
#pragma unroll
    for (int m = 0; m < 4; ++m)
#pragma unroll
      for (int j = 0; j < 4; ++j) ss[m][j] = 0.f;
#pragma unroll
    for (int m = 0; m < 4; ++m)
#pragma unroll
      for (int n = 0; n < 8; ++n)
#pragma unroll
        for (int j = 0; j < 4; ++j) {
          float v = acc[m][n][j];
          v = v >= 0.f ? v : v * SLOPE;
          acc[m][n][j] = v;
          ss[m][j] += v * v;
        }
#pragma unroll
    for (int m = 0; m < 4; ++m)
#pragma unroll
      for (int j = 0; j < 4; ++j) {
        float s = ss[m][j];
        s += __shfl_xor(s, 1, 64);
        s += __shfl_xor(s, 2, 64);
        s += __shfl_xor(s, 4, 64);
        s += __shfl_xor(s, 8, 64);
        ss[m][j] = s;                      // half-row (128-col) sum, all lanes
      }
    __syncthreads();                       // compute done; reuse Bs
    float* red = (float*)Bs;               // [0..255]: partials, [256..511]: inv
    if (colh == 0 && fr == 0) {
#pragma unroll
      for (int m = 0; m < 4; ++m)
#pragma unroll
        for (int j = 0; j < 4; ++j)
          red[rowh * 128 + m * 16 + fq * 4 + j] = ss[m][j];
    }
    __syncthreads();
    float inv[4][4];
    if (colh == 1) {
#pragma unroll
      for (int m = 0; m < 4; ++m)
#pragma unroll
        for (int j = 0; j < 4; ++j) {
          float tot = ss[m][j] + red[rowh * 128 + m * 16 + fq * 4 + j];
          inv[m][j] = 1.f / fmaxf(sqrtf(tot), 1e-12f);
        }
      if (fr == 0) {
#pragma unroll
        for (int m = 0; m < 4; ++m)
#pragma unroll
          for (int j = 0; j < 4; ++j)
            red[256 + rowh * 128 + m * 16 + fq * 4 + j] = inv[m][j];
      }
    }
    __syncthreads();
    if (colh == 0) {
#pragma unroll
      for (int m = 0; m < 4; ++m)
#pragma unroll
        for (int j = 0; j < 4; ++j)
          inv[m][j] = red[256 + rowh * 128 + m * 16 + fq * 4 + j];
    }
#pragma unroll
    for (int m = 0; m < 4; ++m)
#pragma unroll
      for (int n = 0; n < 8; ++n) {
        const int col = colh * 128 + n * 16 + fr;
#pragma unroll
        for (int j = 0; j < 4; ++j) {
          const int r = blk0 + rowh * 64 + m * 16 + fq * 4 + j;
          if (r < M) {
            float v = acc[m][n][j] * inv[m][j];
            Cf[(size_t)r * ldc + col] = v;
            if (Obf) Obf[(size_t)r * ldo + col] = f2b(v);
          }
        }
      }
  }
}

// ---------------- small GEMM (init only): C = A * Bt^T (+bias), f32 out ----------
__global__ __launch_bounds__(256)
void gemm_k(const short* __restrict__ A, int lda,
            const short* __restrict__ Bt, int ldb,
            int M, int K,
            float* __restrict__ Cf, int ldc,
            const float* __restrict__ bias)
{
  __shared__ short bt[256 * 72];
  const int tid = threadIdx.x;
  const int w = tid >> 6;
  const int lane = tid & 63;
  const int fr = lane & 15;
  const int fq = lane >> 4;
  const int col0 = blockIdx.y << 8;
  const int rowbase = blockIdx.x * 64 + w * 16;
  const int arow = min(rowbase + fr, M - 1);
  const long abase = (long)arow * lda + fq * 8;

  f32x4 acc[16];
#pragma unroll
  for (int i = 0; i < 16; ++i) { acc[i][0] = 0.f; acc[i][1] = 0.f; acc[i][2] = 0.f; acc[i][3] = 0.f; }

  for (int kc = 0; kc < K; kc += 64) {
    __syncthreads();
    {
      const short* g = Bt + (long)(col0 + tid) * ldb + kc;
      short* l = &bt[tid * 72];
#pragma unroll
      for (int i = 0; i < 8; ++i)
        *(short8*)(l + i * 8) = *(const short8*)(g + i * 8);
    }
    __syncthreads();
#pragma unroll
    for (int ks = 0; ks < 2; ++ks) {
      short8 a = *(const short8*)(A + abase + kc + ks * 32);
#pragma unroll
      for (int ct = 0; ct < 16; ++ct) {
        short8 b = *(const short8*)&bt[(ct * 16 + fr) * 72 + ks * 32 + fq * 8];
        acc[ct] = __builtin_amdgcn_mfma_f32_16x16x32_bf16(a, b, acc[ct], 0, 0, 0);
      }
    }
  }

  const int crow = rowbase + fq * 4;
#pragma unroll
  for (int ct = 0; ct < 16; ++ct) {
    const int gcol = col0 + ct * 16 + fr;
#pragma unroll
    for (int j = 0; j < 4; ++j) {
      const int r = crow + j;
      if (r < M) {
        float v = acc[ct][j];
        if (bias) v += bias[gcol];
        Cf[(long)r * ldc + gcol] = v;
      }
    }
  }
}

// ---------------- fused GRU GEMMs: z=0 -> gx, z=1 -> gh ---------------------------
__global__ __launch_bounds__(256)
void gru2_k(const short* __restrict__ x_inb, const short* __restrict__ h0b,
            const short* __restrict__ wihb, const short* __restrict__ whhb,
            const float* __restrict__ gxbase, const float* __restrict__ bhh,
            float* __restrict__ gx, float* __restrict__ gh)
{
  const short* A;  const short* Bt;  int ldb;
  float* Cf;  const float* Cadd;  const float* bias;
  if (blockIdx.z == 0) { A = x_inb; Bt = wihb + 256; ldb = 512; Cf = gx; Cadd = gxbase; bias = nullptr; }
  else                 { A = h0b;   Bt = whhb;       ldb = 256; Cf = gh; Cadd = nullptr; bias = bhh; }

  __shared__ short bt[256 * 72];
  const int tid = threadIdx.x;
  const int w = tid >> 6;
  const int lane = tid & 63;
  const int fr = lane & 15;
  const int fq = lane >> 4;
  const int col0 = blockIdx.y << 8;
  const int rowbase = blockIdx.x * 64 + w * 16;
  const int arow = min(rowbase + fr, R2 - 1);
  const long abase = (long)arow * 256 + fq * 8;

  f32x4 acc[16];
#pragma unroll
  for (int i = 0; i < 16; ++i) { acc[i][0] = 0.f; acc[i][1] = 0.f; acc[i][2] = 0.f; acc[i][3] = 0.f; }

  for (int kc = 0; kc < 256; kc += 64) {
    __syncthreads();
    {
      const short* g = Bt + (long)(col0 + tid) * ldb + kc;
      short* l = &bt[tid * 72];
#pragma unroll
      for (int i = 0; i < 8; ++i)
        *(short8*)(l + i * 8) = *(const short8*)(g + i * 8);
    }
    __syncthreads();
#pragma unroll
    for (int ks = 0; ks < 2; ++ks) {
      short8 a = *(const short8*)(A + abase + kc + ks * 32);
#pragma unroll
      for (int ct = 0; ct < 16; ++ct) {
        short8 b = *(const short8*)&bt[(ct * 16 + fr) * 72 + ks * 32 + fq * 8];
        acc[ct] = __builtin_amdgcn_mfma_f32_16x16x32_bf16(a, b, acc[ct], 0, 0, 0);
      }
    }
  }

  const int crow = rowbase + fq * 4;
#pragma unroll
  for (int ct = 0; ct < 16; ++ct) {
    const int gcol = col0 + ct * 16 + fr;
#pragma unroll
    for (int j = 0; j < 4; ++j) {
      const int r = crow + j;
      if (r < R2) {
        float v = acc[ct][j];
        if (Cadd) v += Cadd[(long)r * 768 + gcol];
        if (bias) v += bias[gcol];
        Cf[(long)r * 768 + gcol] = v;
      }
    }
  }
}

// ---------------- init: h = l2norm(dynamic_emb) -> bf16 into Acat halfB ----------
__global__ __launch_bounds__(256)
void l2init_k(const float* __restrict__ de, short* __restrict__ hb)
{
  const int w = threadIdx.x >> 6, lane = threadIdx.x & 63;
  const int row = blockIdx.x * 4 + w;
  f32x4 v = *(const f32x4*)&de[(long)row * H + lane * 4];
  float s = v[0]*v[0] + v[1]*v[1] + v[2]*v[2] + v[3]*v[3];
  s += __shfl_xor(s, 1, 64);  s += __shfl_xor(s, 2, 64);
  s += __shfl_xor(s, 4, 64);  s += __shfl_xor(s, 8, 64);
  s += __shfl_xor(s, 16, 64); s += __shfl_xor(s, 32, 64);
  float sc = 1.f / fmaxf(sqrtf(s), 1e-12f);
  short4v o;
  o[0] = f2b(v[0]*sc); o[1] = f2b(v[1]*sc); o[2] = f2b(v[2]*sc); o[3] = f2b(v[3]*sc);
  *(short4v*)&hb[(long)row * 512 + lane * 4] = o;
}

// ---------------- merged weight prep ---------------------------------------------
__global__ __launch_bounds__(256)
void prep_k(const float* __restrict__ wn, const float* __restrict__ lw,
            const float* __restrict__ ew, const float* __restrict__ wih,
            const float* __restrict__ whh, const float* __restrict__ erel,
            short* __restrict__ wcatb, short* __restrict__ evt,
            short* __restrict__ wihb, short* __restrict__ whhb,
            short* __restrict__ erelb, float* __restrict__ h0, short* __restrict__ h0b)
{
  long i = (long)blockIdx.x * 256 + threadIdx.x;
  if (i < (long)NL * 256 * 512) {
    int l = (int)(i / (256 * 512));
    int rem = (int)(i % (256 * 512));
    int j = rem / 512;
    int k = rem % 512;
    float v = (k < 256) ? wn[(long)l * 65536 + k * 256 + j]
                        : lw[(long)l * 65536 + (k - 256) * 256 + j];
    wcatb[i] = f2b(v);
    return;
  }
  i -= (long)NL * 256 * 512;
  if (i < (long)NL * 65536) {
    int l = (int)(i >> 16);
    int rem = (int)(i & 65535);
    int c = rem >> 8, k = rem & 255;
    evt[i] = f2b(ew[(long)l * 65536 + k * 256 + c]);
    return;
  }
  i -= (long)NL * 65536;
  if (i < 768 * 512) { wihb[i] = f2b(wih[i]); return; }
  i -= 768 * 512;
  if (i < 768 * 256) { whhb[i] = f2b(whh[i]); return; }
  i -= 768 * 256;
  if (i < (long)R2 * H) {
    float v = erel[i];
    erelb[i] = f2b(v); h0[i] = v; h0b[i] = f2b(v);
  }
}
#define PREP_N ((long)NL * 256 * 512 + (long)NL * 65536 + 768 * 512 + 768 * 256 + (long)R2 * H)

// ---------------- batched zero of all 4 steps' counters (padded) ------------------
__global__ __launch_bounds__(256)
void zero_all_k(unsigned* __restrict__ deg, unsigned* __restrict__ curd,
                unsigned* __restrict__ cnt, unsigned* __restrict__ cur,
                unsigned* __restrict__ nz, unsigned* __restrict__ flags)
{
  const int t = blockIdx.y;
  int i = blockIdx.x * 256 + threadIdx.x;
  if (i < N_ENTS) { deg[(long)t * N_ENTS + i] = 0u; curd[(long)t * N_ENTS + i] = 0u; }
  if (i < R2) { cnt[((long)t * R2 + i) * CPAD] = 0u; cur[((long)t * R2 + i) * CPAD] = 0u; }
  if (i < SCAN_NB) flags[t * SCAN_NB + i] = 0u;
  if (i == 0) nz[t * CPAD] = 0u;
}

// ---------------- batched counting: rel histogram (LDS) + dst degree --------------
__global__ __launch_bounds__(256)
void count_all_k(const int* __restrict__ relA, const int* __restrict__ dstA,
                 unsigned* __restrict__ cntA, unsigned* __restrict__ degA)
{
  const int t = blockIdx.y;
  const int* rel = relA + (long)t * NM;
  const int* dstv = dstA + (long)t * NE;
  unsigned* cnt = cntA + (long)t * R2 * CPAD;
  unsigned* deg = degA + (long)t * N_ENTS;
  __shared__ unsigned lh[R2];
  for (int i = threadIdx.x; i < R2; i += 256) lh[i] = 0;
  __syncthreads();
  for (long i = (long)blockIdx.x * 256 + threadIdx.x; i < NM; i += (long)gridDim.x * 256)
    atomicAdd(&lh[rel[i]], 1u);
  for (long i = (long)blockIdx.x * 256 + threadIdx.x; i < NE; i += (long)gridDim.x * 256)
    atomicAdd(&deg[dstv[i]], 1u);
  __syncthreads();
  for (int i = threadIdx.x; i < R2; i += 256)
    if (lh[i]) atomicAdd(&cnt[i * CPAD], lh[i]);
}

// ---------------- batched scans: decoupled lookback (deg) + rel prefix ------------
__global__ __launch_bounds__(256)
void scan_all_k(const unsigned* __restrict__ degA, unsigned* __restrict__ offdA,
                unsigned* __restrict__ flagsA,
                unsigned* __restrict__ zlA, unsigned* __restrict__ nzA,
                const unsigned* __restrict__ cntA, unsigned* __restrict__ offA)
{
  const int t = blockIdx.y;
  if (blockIdx.x == SCAN_NB) {           // rel-histogram prefix (512-slot HS)
    const unsigned* cnt = cntA + (long)t * R2 * CPAD;
    unsigned* off = offA + t * (R2 + 1);
    __shared__ unsigned sr[512];
    const int tt = threadIdx.x;
    sr[tt] = (tt < R2) ? cnt[tt * CPAD] : 0u;
    sr[tt + 256] = (tt + 256 < R2) ? cnt[(tt + 256) * CPAD] : 0u;
    __syncthreads();
#pragma unroll
    for (int d = 1; d < 512; d <<= 1) {
      unsigned v0 = (tt >= d) ? sr[tt - d] : 0u;
      unsigned v1 = (tt + 256 >= d) ? sr[tt + 256 - d] : 0u;
      __syncthreads();
      sr[tt] += v0; sr[tt + 256] += v1;
      __syncthreads();
    }
    if (tt < R2) off[tt] = (tt == 0) ? 0u : sr[tt - 1];
    if (tt + 256 < R2) off[tt + 256] = sr[tt + 255];
    if (tt == 0) off[R2] = sr[R2 - 1];
    return;
  }
  const unsigned* deg = degA + (long)t * N_ENTS;
  unsigned* offd = offdA + (long)t * (N_ENTS + 1);
  unsigned* flags = flagsA + t * SCAN_NB;
  unsigned* zl = zlA + (long)t * N_ENTS;
  unsigned* nz = nzA + t * CPAD;
  __shared__ unsigned s[256];
  __shared__ unsigned sexc;
  const int tid = threadIdx.x;
  const int b = blockIdx.x;
  const int i = b * 256 + tid;
  unsigned v = (i < N_ENTS) ? deg[i] : 0u;
  s[tid] = v;
  __syncthreads();
#pragma unroll
  for (int d = 1; d < 256; d <<= 1) {
    unsigned t2 = (tid >= d) ? s[tid - d] : 0u;
    __syncthreads();
    s[tid] += t2;
    __syncthreads();
  }
  const unsigned total = s[255];
  if (tid == 0) {
    if (b == 0) {
      __threadfence();
      atomicExch(&flags[0], (2u << 30) | total);
      sexc = 0u;
    } else {
      __threadfence();
      atomicExch(&flags[b], (1u << 30) | total);
      unsigned exc = 0u;
      int j = b - 1;
      while (j >= 0) {
        unsigned f;
        do { f = atomicAdd(&flags[j], 0u); } while ((f >> 30) == 0u);
        exc += f & 0x3FFFFFFFu;
        if ((f >> 30) == 2u) break;
        --j;
      }
      __threadfence();
      atomicExch(&flags[b], (2u << 30) | (exc + total));
      sexc = exc;
    }
  }
  __syncthreads();
  const unsigned exc = sexc;
  if (i < N_ENTS) {
    offd[i] = exc + s[tid] - v;
    if (v == 0u) { unsigned p2 = atomicAdd(nz, 1u); zl[p2] = i; }
  }
  if (i == 0) offd[N_ENTS] = NE;
}

// ---------------- batched scatter: rel-CSR (ent) + dst-CSR (src,etype int2) ------
__global__ __launch_bounds__(256)
void scatter_all_k(const int* __restrict__ relA, const int* __restrict__ entA,
                   const unsigned* __restrict__ offA, unsigned* __restrict__ curA,
                   int* __restrict__ seA,
                   const int* __restrict__ srcA, const int* __restrict__ dstA,
                   const int* __restrict__ etA, const unsigned* __restrict__ offdA,
                   unsigned* __restrict__ curdA, int2* __restrict__ se2A)
{
  const int t = blockIdx.y;
  if (blockIdx.x < 256) {
    const int* rel = relA + (long)t * NM;
    const int* ent = entA + (long)t * NM;
    const unsigned* off = offA + t * (R2 + 1);
    unsigned* cur = curA + (long)t * R2 * CPAD;
    int* se = seA + (long)t * NM;
    for (long i = (long)blockIdx.x * 256 + threadIdx.x; i < NM; i += 256l * 256) {
      int r = rel[i];
      unsigned p = atomicAdd(&cur[r * CPAD], 1u);
      se[off[r] + p] = ent[i];
    }
  } else {
    const int* srcv = srcA + (long)t * NE;
    const int* dstv = dstA + (long)t * NE;
    const int* etv = etA + (long)t * NE;
    const unsigned* offd = offdA + (long)t * (N_ENTS + 1);
    unsigned* curd = curdA + (long)t * N_ENTS;
    int2* se2 = se2A + (long)t * NE;
    for (long i = (long)(blockIdx.x - 256) * 256 + threadIdx.x; i < NE; i += 512l * 256) {
      int d = dstv[i];
      unsigned p = atomicAdd(&curd[d], 1u);
      se2[offd[d] + p] = make_int2(srcv[i], etv[i]);
    }
  }
}

// ---------------- segment-sum partials (x4 split), 16B/lane, 2 entries/wave -------
__global__ __launch_bounds__(256)
void segpart_k(const unsigned* __restrict__ off, const int* __restrict__ se,
               const short* __restrict__ hb, float* __restrict__ xinf)
{
  __shared__ float red[4][256];
  const int r = blockIdx.x >> 2, s = blockIdx.x & 3;
  const int w = threadIdx.x >> 6, lane = threadIdx.x & 63;
  const int half = lane >> 5, sl = lane & 31;
  const unsigned b = off[r], e = off[r + 1], len = e - b;
  const unsigned lo = b + ((len * s) >> 2), hi = b + ((len * (s + 1)) >> 2);
  float a[8];
#pragma unroll
  for (int j = 0; j < 8; ++j) a[j] = 0.f;
  unsigned i = lo + w * 2;
  for (; i + 10 <= hi; i += 16) {          // two pairs per wave per iter
    int e0 = se[i + half];
    int e1 = se[i + 8 + half];
    short8 h0v = *(const short8*)&hb[(long)e0 * 512 + sl * 8];
    short8 h1v = *(const short8*)&hb[(long)e1 * 512 + sl * 8];
#pragma unroll
    for (int j = 0; j < 8; ++j) a[j] += b2f(h0v[j]) + b2f(h1v[j]);
  }
  for (; i + 2 <= hi; i += 8) {
    int e0 = se[i + half];
    short8 hv = *(const short8*)&hb[(long)e0 * 512 + sl * 8];
#pragma unroll
    for (int j = 0; j < 8; ++j) a[j] += b2f(hv[j]);
  }
  if (i + half < hi) {
    int e0 = se[i + half];
    short8 hv = *(const short8*)&hb[(long)e0 * 512 + sl * 8];
#pragma unroll
    for (int j = 0; j < 8; ++j) a[j] += b2f(hv[j]);
  }
#pragma unroll
  for (int j = 0; j < 8; ++j) a[j] += __shfl_xor(a[j], 32, 64);
  if (half == 0) {
#pragma unroll
    for (int j = 0; j < 8; ++j) red[w][sl * 8 + j] = a[j];
  }
  __syncthreads();
  const int t = threadIdx.x;
  xinf[((long)s * R2 + r) * 256 + t] =
      (red[0][t] + red[1][t]) + (red[2][t] + red[3][t]);
}

__global__ __launch_bounds__(256)
void segfin_k(const float* __restrict__ xinf, const unsigned* __restrict__ cnt,
              short* __restrict__ x_inb)
{
  const int r = blockIdx.x, tid = threadIdx.x;
  float v = xinf[(long)r * 256 + tid] + xinf[((long)R2 + r) * 256 + tid]
          + xinf[((long)2 * R2 + r) * 256 + tid] + xinf[((long)3 * R2 + r) * 256 + tid];
  v /= fmaxf((float)cnt[r * CPAD], 1.f);
  x_inb[(long)r * 256 + tid] = f2b(v);
}

// ---------------- GRU gates ------------------------------------------------------
__global__ __launch_bounds__(256)
void gate_k(const float* __restrict__ gx, const float* __restrict__ gh,
            float* __restrict__ h0, short* __restrict__ h0b, float* __restrict__ relout)
{
  __shared__ float red[4];
  const int r = blockIdx.x, c = threadIdx.x;
  const long b = (long)r * 768;
  float xr = gx[b + c], xz = gx[b + 256 + c], xn = gx[b + 512 + c];
  float hr = gh[b + c], hz = gh[b + 256 + c], hn = gh[b + 512 + c];
  float rr = 1.f / (1.f + expf(-(xr + hr)));
  float z  = 1.f / (1.f + expf(-(xz + hz)));
  float nn = tanhf(xn + rr * hn);
  float v = (1.f - z) * nn + z * h0[(long)r * H + c];
  float s = v * v;
  s += __shfl_xor(s, 1, 64);  s += __shfl_xor(s, 2, 64);
  s += __shfl_xor(s, 4, 64);  s += __shfl_xor(s, 8, 64);
  s += __shfl_xor(s, 16, 64); s += __shfl_xor(s, 32, 64);
  const int w = c >> 6;
  if ((c & 63) == 0) red[w] = s;
  __syncthreads();
  float tot = (red[0] + red[1]) + (red[2] + red[3]);
  float sc = 1.f / fmaxf(sqrtf(tot), 1e-12f);
  v *= sc;
  h0[(long)r * H + c] = v;
  h0b[(long)r * H + c] = f2b(v);
  relout[(long)r * H + c] = v;
}

// ---------------- layer-0 aggregation: 16B/lane, 2 edges/wave, emits rsum --------
__global__ __launch_bounds__(256)
void agg_first_k(const int2* __restrict__ se2, const unsigned* __restrict__ offd,
                 const short* __restrict__ hb, const short* __restrict__ h0b,
                 short* __restrict__ rsum, short* __restrict__ acat)
{
  const int w = threadIdx.x >> 6, lane = threadIdx.x & 63;
  const int half = lane >> 5, sl = lane & 31;
  const int row = blockIdx.x * 4 + w;
  const unsigned b = offd[row], e = offd[row + 1];
  float ha[8], ra[8];
#pragma unroll
  for (int j = 0; j < 8; ++j) { ha[j] = 0.f; ra[j] = 0.f; }
  unsigned i = b;
  for (; i + 4 <= e; i += 4) {
    int2 e0 = se2[i + half];
    int2 e1 = se2[i + 2 + half];
    short8 h0v = *(const short8*)&hb[(long)e0.x * 512 + sl * 8];
    short8 r0v = *(const short8*)&h0b[(long)e0.y * 256 + sl * 8];
    short8 h1v = *(const short8*)&hb[(long)e1.x * 512 + sl * 8];
    short8 r1v = *(const short8*)&h0b[(long)e1.y * 256 + sl * 8];
#pragma unroll
    for (int j = 0; j < 8; ++j) {
      ha[j] += b2f(h0v[j]) + b2f(h1v[j]);
      ra[j] += b2f(r0v[j]) + b2f(r1v[j]);
    }
  }
  for (; i < e; i += 2) {
    if (i + half < e) {
      int2 e0 = se2[i + half];
      short8 hv = *(const short8*)&hb[(long)e0.x * 512 + sl * 8];
      short8 rv = *(const short8*)&h0b[(long)e0.y * 256 + sl * 8];
#pragma unroll
      for (int j = 0; j < 8; ++j) { ha[j] += b2f(hv[j]); ra[j] += b2f(rv[j]); }
    }
  }
#pragma unroll
  for (int j = 0; j < 8; ++j) {
    ha[j] += __shfl_xor(ha[j], 32, 64);
    ra[j] += __shfl_xor(ra[j], 32, 64);
  }
  if (half == 0) {
    const float nm = 1.f / fmaxf((float)(e - b), 1.f);
    short8 rs, o;
#pragma unroll
    for (int j = 0; j < 8; ++j) {
      rs[j] = f2b(ra[j]);
      o[j] = f2b((ha[j] + ra[j]) * nm);
    }
    *(short8*)&rsum[(long)row * 256 + sl * 8] = rs;
    *(short8*)&acat[(long)row * 512 + sl * 8] = o;
  }
}

// ---------------- layer-1 aggregation: reuses rsum, 16B/lane, 2 edges/wave -------
__global__ __launch_bounds__(256)
void agg_second_k(const int2* __restrict__ se2, const unsigned* __restrict__ offd,
                  const short* __restrict__ hb, const short* __restrict__ rsum,
                  short* __restrict__ acat)
{
  const int w = threadIdx.x >> 6, lane = threadIdx.x & 63;
  const int half = lane >> 5, sl = lane & 31;
  const int row = blockIdx.x * 4 + w;
  const unsigned b = offd[row], e = offd[row + 1];
  float ha[8];
#pragma unroll
  for (int j = 0; j < 8; ++j) ha[j] = 0.f;
  unsigned i = b;
  for (; i + 4 <= e; i += 4) {
    int2 e0 = se2[i + half];
    int2 e1 = se2[i + 2 + half];
    short8 h0v = *(const short8*)&hb[(long)e0.x * 512 + sl * 8];
    short8 h1v = *(const short8*)&hb[(long)e1.x * 512 + sl * 8];
#pragma unroll
    for (int j = 0; j < 8; ++j) ha[j] += b2f(h0v[j]) + b2f(h1v[j]);
  }
  for (; i < e; i += 2) {
    if (i + half < e) {
      int2 e0 = se2[i + half];
      short8 hv = *(const short8*)&hb[(long)e0.x * 512 + sl * 8];
#pragma unroll
      for (int j = 0; j < 8; ++j) ha[j] += b2f(hv[j]);
    }
  }
#pragma unroll
  for (int j = 0; j < 8; ++j) ha[j] += __shfl_xor(ha[j], 32, 64);
  if (half == 0) {
    short8 rs = *(const short8*)&rsum[(long)row * 256 + sl * 8];
    const float nm = 1.f / fmaxf((float)(e - b), 1.f);
    short8 o;
#pragma unroll
    for (int j = 0; j < 8; ++j) o[j] = f2b((ha[j] + b2f(rs[j])) * nm);
    *(short8*)&acat[(long)row * 512 + sl * 8] = o;
  }
}

// ---------------- deg==0 fixup: row = rrelu(hc @ evolve_w) (+l2norm if final) ----
template<int FINAL>
__global__ __launch_bounds__(256)
void fixup_k(const unsigned* __restrict__ nz, const unsigned* __restrict__ zl,
             const short* __restrict__ hbc, const short* __restrict__ evt,
             short* __restrict__ hbn, float* __restrict__ outF)
{
  __shared__ float x[H];
  __shared__ float red[4];
  const unsigned n = *nz;
  const short* wrow = evt + (long)threadIdx.x * 256;
  for (unsigned zi = blockIdx.x; zi < n; zi += gridDim.x) {
    const int row = zl[zi];
    __syncthreads();
    x[threadIdx.x] = b2f(hbc[(long)row * 512 + threadIdx.x]);
    __syncthreads();
    float acc = 0.f;
#pragma unroll
    for (int k0 = 0; k0 < H; k0 += 8) {
      short8 wv = *(const short8*)&wrow[k0];
      acc += x[k0]     * b2f(wv[0]) + x[k0 + 1] * b2f(wv[1])
           + x[k0 + 2] * b2f(wv[2]) + x[k0 + 3] * b2f(wv[3])
           + x[k0 + 4] * b2f(wv[4]) + x[k0 + 5] * b2f(wv[5])
           + x[k0 + 6] * b2f(wv[6]) + x[k0 + 7] * b2f(wv[7]);
    }
    float v = acc >= 0.f ? acc : acc * SLOPE;
    if (FINAL) {
      float s = v * v;
      s += __shfl_xor(s, 1, 64);  s += __shfl_xor(s, 2, 64);
      s += __shfl_xor(s, 4, 64);  s += __shfl_xor(s, 8, 64);
      s += __shfl_xor(s, 16, 64); s += __shfl_xor(s, 32, 64);
      const int w = threadIdx.x >> 6;
      if ((threadIdx.x & 63) == 0) red[w] = s;
      __syncthreads();
      float tot = (red[0] + red[1]) + (red[2] + red[3]);
      float sc = 1.f / fmaxf(sqrtf(tot), 1e-12f);
      v *= sc;
      outF[(long)row * H + threadIdx.x] = v;
    }
    if (hbn) hbn[(long)row * 512 + threadIdx.x] = f2b(v);
  }
}

// =================================================================================
extern "C" void kernel_launch(void* const* d_in, const int* in_sizes, int n_in,
                              void* d_out, int out_size, void* d_ws, size_t ws_size,
                              hipStream_t stream)
{
  (void)in_sizes; (void)n_in; (void)out_size; (void)ws_size;
  const int* src = (const int*)d_in[0];
  const int* dst = (const int*)d_in[1];
  const int* ety = (const int*)d_in[2];
  const int* r2e_ent = (const int*)d_in[3];
  const int* r2e_rel = (const int*)d_in[4];
  const float* dyn = (const float*)d_in[5];
  const float* erel = (const float*)d_in[6];
  const float* wn = (const float*)d_in[7];
  const float* lw = (const float*)d_in[8];
  const float* ew = (const float*)d_in[9];
  const float* wih = (const float*)d_in[10];
  const float* whh = (const float*)d_in[11];
  const float* bih = (const float*)d_in[12];
  const float* bhh = (const float*)d_in[13];

  float* out = (float*)d_out;
  float* hist = out;
  float* rels = out + (long)TSTEPS * N_ENTS * H;

  char* p = (char*)d_ws;
  auto alloc = [&](size_t n) { char* r = p; p += (n + 255) & ~(size_t)255; return r; };
  short*    AcatA  = (short*)alloc((size_t)N_ENTS * 512 * 2);
  short*    AcatB  = (short*)alloc((size_t)N_ENTS * 512 * 2);
  short*    rsum   = (short*)alloc((size_t)N_ENTS * 256 * 2);
  unsigned* deg    = (unsigned*)alloc((size_t)TSTEPS * N_ENTS * 4);
  unsigned* offd   = (unsigned*)alloc((size_t)TSTEPS * (N_ENTS + 1) * 4);
  unsigned* curd   = (unsigned*)alloc((size_t)TSTEPS * N_ENTS * 4);
  unsigned* flags  = (unsigned*)alloc((size_t)TSTEPS * SCAN_NB * 4);
  int2*     se2    = (int2*)alloc((size_t)TSTEPS * NE * 8);
  unsigned* zl     = (unsigned*)alloc((size_t)TSTEPS * N_ENTS * 4);
  unsigned* nz     = (unsigned*)alloc((size_t)TSTEPS * CPAD * 4);
  unsigned* cnt    = (unsigned*)alloc((size_t)TSTEPS * R2 * CPAD * 4);
  unsigned* off    = (unsigned*)alloc((size_t)TSTEPS * (R2 + 1) * 4);
  unsigned* cur    = (unsigned*)alloc((size_t)TSTEPS * R2 * CPAD * 4);
  int*      se     = (int*)alloc((size_t)TSTEPS * NM * 4);
  float*    xinf   = (float*)alloc((size_t)4 * R2 * 256 * 4);
  short*    x_inb  = (short*)alloc((size_t)R2 * H * 2);
  float*    gxbase = (float*)alloc((size_t)R2 * 768 * 4);
  float*    gx     = (float*)alloc((size_t)R2 * 768 * 4);
  float*    gh     = (float*)alloc((size_t)R2 * 768 * 4);
  float*    h0     = (float*)alloc((size_t)R2 * H * 4);
  short*    h0b    = (short*)alloc((size_t)R2 * H * 2);
  short*    erelb  = (short*)alloc((size_t)R2 * H * 2);
  short*    wcatb  = (short*)alloc((size_t)NL * 256 * 512 * 2);
  short*    evt    = (short*)alloc((size_t)NL * H * H * 2);
  short*    wihb   = (short*)alloc((size_t)768 * 512 * 2);
  short*    whhb   = (short*)alloc((size_t)768 * 256 * 2);

  prep_k<<<(int)((PREP_N + 255) / 256), 256, 0, stream>>>(
      wn, lw, ew, wih, whh, erel, wcatb, evt, wihb, whhb, erelb, h0, h0b);
  l2init_k<<<N_ENTS / 4, 256, 0, stream>>>(dyn, AcatA + 256);

  // gx_base = emb_rel @ W_ih[:, :256]^T + b_ih   (step-invariant)
  gemm_k<<<dim3(8, 3), 256, 0, stream>>>(erelb, 256, wihb, 512, R2, 256,
                                         gxbase, 768, bih);

  // ---- batched CSR build for ALL steps (depends only on int inputs) -------------
  zero_all_k<<<dim3(SCAN_NB, TSTEPS), 256, 0, stream>>>(deg, curd, cnt, cur, nz, flags);
  count_all_k<<<dim3(512, TSTEPS), 256, 0, stream>>>(r2e_rel, dst, cnt, deg);
  scan_all_k<<<dim3(SCAN_NB + 1, TSTEPS), 256, 0, stream>>>(deg, offd, flags, zl, nz, cnt, off);
  scatter_all_k<<<dim3(768, TSTEPS), 256, 0, stream>>>(r2e_rel, r2e_ent, off, cur, se,
                                                       src, dst, ety, offd, curd, se2);

  short* Acur = AcatA;
  short* Anxt = AcatB;

  for (int t = 0; t < TSTEPS; ++t) {
    float* hist_t = hist + (long)t * N_ENTS * H;
    float* rels_t = rels + (long)t * R2 * H;
    const unsigned* off_t  = off + t * (R2 + 1);
    const int*      se_t   = se + (long)t * NM;
    const unsigned* offd_t = offd + (long)t * (N_ENTS + 1);
    const int2*     se2_t  = se2 + (long)t * NE;
    const unsigned* cnt_t  = cnt + (long)t * R2 * CPAD;
    const unsigned* nz_t   = nz + t * CPAD;
    const unsigned* zl_t   = zl + (long)t * N_ENTS;

    // relation mean (split x4) + GRU
    segpart_k<<<R2 * 4, 256, 0, stream>>>(off_t, se_t, Acur + 256, xinf);
    segfin_k<<<R2, 256, 0, stream>>>(xinf, cnt_t, x_inb);
    gru2_k<<<dim3(8, 3, 2), 256, 0, stream>>>(x_inb, h0b, wihb, whhb, gxbase, bhh, gx, gh);
    gate_k<<<R2, 256, 0, stream>>>(gx, gh, h0, h0b, rels_t);

    // layer 0
    agg_first_k<<<N_ENTS / 4, 256, 0, stream>>>(se2_t, offd_t, Acur + 256, h0b, rsum, Acur);
    gemm_big<1><<<391, 256, 0, stream>>>(Acur, 512, wcatb, 512,
                                         N_ENTS, 512, nullptr, 0, Anxt + 256, 512);
    fixup_k<0><<<512, 256, 0, stream>>>(nz_t, zl_t, Acur + 256, evt, Anxt + 256, nullptr);
    { short* tmp = Acur; Acur = Anxt; Anxt = tmp; }

    // layer 1
    agg_second_k<<<N_ENTS / 4, 256, 0, stream>>>(se2_t, offd_t, Acur + 256, rsum, Acur);
    const bool last = (t == TSTEPS - 1);
    gemm_big<2><<<391, 256, 0, stream>>>(Acur, 512, wcatb + 256 * 512, 512,
                                         N_ENTS, 512, hist_t, 256,
                                         last ? nullptr : (Anxt + 256), 512);
    fixup_k<1><<<512, 256, 0, stream>>>(nz_t, zl_t, Acur + 256, evt + (long)H * H,
                                        last ? nullptr : (Anxt + 256), hist_t);
    { short* tmp = Acur; Acur = Anxt; Anxt = tmp; }
  }
}